// Round 2
// baseline (3270.176 us; speedup 1.0000x reference)
//
#include <hip/hip_runtime.h>
#include <math.h>

#define BB 8
#define HH 128
#define WW 128
#define HW (HH*WW)          // 16384
#define NPIX (BB*HW)        // 131072
#define CEMB 192
#define PD 96
#define C3 288
#define NHEAD 8
#define CPH 12
#define HIDC 256

static __device__ __forceinline__ float gelu_exact(float x){
    return 0.5f*x*(1.0f+erff(x*0.70710678118654752440f));
}

// ---------- pos depthwise 3x3 conv + bias + residual (NHWC, float4 over C), full tensor ----------
__global__ __launch_bounds__(256) void pos_conv_k(const float* __restrict__ x,
    const float* __restrict__ w, const float* __restrict__ bias, float* __restrict__ out)
{
    int idx = blockIdx.x*256 + threadIdx.x;          // over NPIX*48
    int c4 = idx % 48; int pix = idx / 48;
    int wx = pix % WW; int rest = pix / WW; int hy = rest % HH; int b = rest / HH;
    const float4* x4 = (const float4*)x;
    int c0 = c4*4;
    float4 acc;
    acc.x = bias[c0]; acc.y = bias[c0+1]; acc.z = bias[c0+2]; acc.w = bias[c0+3];
    for (int ky=0; ky<3; ky++){
        int hh = hy + ky - 1; if (hh < 0 || hh >= HH) continue;
        for (int kx=0; kx<3; kx++){
            int ww2 = wx + kx - 1; if (ww2 < 0 || ww2 >= WW) continue;
            float4 v = x4[((size_t)(b*HH+hh)*WW+ww2)*48 + c4];
            int tap = ky*3+kx;
            acc.x += w[(c0+0)*9+tap]*v.x;
            acc.y += w[(c0+1)*9+tap]*v.y;
            acc.z += w[(c0+2)*9+tap]*v.z;
            acc.w += w[(c0+3)*9+tap]*v.w;
        }
    }
    float4 xs = x4[idx];
    acc.x += xs.x; acc.y += xs.y; acc.z += xs.z; acc.w += xs.w;
    ((float4*)out)[idx] = acc;
}

// ---------- LayerNorm over C=192, wave per pixel (per-batch slice: grid HW/4) ----------
__global__ __launch_bounds__(256) void ln_k(const float* __restrict__ in,
    const float* __restrict__ g, const float* __restrict__ bta, float* __restrict__ out)
{
    int wid = threadIdx.x >> 6, lane = threadIdx.x & 63;
    size_t pix = (size_t)blockIdx.x*4 + wid;
    const float* row = in + pix*192;
    float x0 = row[lane], x1 = row[lane+64], x2 = row[lane+128];
    float s = x0+x1+x2;
    float q = x0*x0 + x1*x1 + x2*x2;
    #pragma unroll
    for (int off=32; off; off>>=1){ s += __shfl_xor(s,off,64); q += __shfl_xor(q,off,64); }
    float mean = s*(1.f/192.f);
    float var  = q*(1.f/192.f) - mean*mean;
    float inv  = rsqrtf(var + 1e-6f);
    float* orow = out + pix*192;
    orow[lane]     = (x0-mean)*inv*g[lane]     + bta[lane];
    orow[lane+64]  = (x1-mean)*inv*g[lane+64]  + bta[lane+64];
    orow[lane+128] = (x2-mean)*inv*g[lane+128] + bta[lane+128];
}

// ---------- generic tiled fp32 GEMM: C[M,N] = epi(A[M,K] @ W[N,K]^T), M multiple of 64 ----------
#define GM_NONE 0
#define GM_RES 1
#define GM_GELU_BN 2
#define GM_BN_RES 3
#define GM_BIAS_RELU 4

template<int MODE>
__global__ __launch_bounds__(256) void gemm_k(
    const float* __restrict__ A, int lda,
    const float* __restrict__ W,
    float* __restrict__ C, int ldc,
    const float* __restrict__ R, int ldr,
    const float* __restrict__ bg, const float* __restrict__ bb,
    const float* __restrict__ bm_, const float* __restrict__ bv,
    int N, int K)
{
    __shared__ float As[16][72];
    __shared__ float Ws[16][72];
    int t = threadIdx.x;
    int tx = t & 15, ty = t >> 4;
    int bm = blockIdx.x * 64;
    int bn = blockIdx.y * 64;
    int lrow = t >> 2;
    int lk   = (t & 3) * 4;
    const float* Ap = A + (size_t)(bm + lrow)*lda + lk;
    bool wv = (bn + lrow) < N;
    const float* Wp = wv ? (W + (size_t)(bn + lrow)*K + lk) : W;
    float acc[4][4] = {{0.f}};
    for (int k0 = 0; k0 < K; k0 += 16){
        float4 av = *(const float4*)(Ap + k0);
        float4 wvv = *(const float4*)(Wp + k0);
        if (!wv){ wvv.x=0.f; wvv.y=0.f; wvv.z=0.f; wvv.w=0.f; }
        __syncthreads();
        As[lk+0][lrow]=av.x;  As[lk+1][lrow]=av.y;  As[lk+2][lrow]=av.z;  As[lk+3][lrow]=av.w;
        Ws[lk+0][lrow]=wvv.x; Ws[lk+1][lrow]=wvv.y; Ws[lk+2][lrow]=wvv.z; Ws[lk+3][lrow]=wvv.w;
        __syncthreads();
        #pragma unroll
        for (int kk=0; kk<16; kk++){
            float4 a4 = *(const float4*)&As[kk][ty*4];
            float4 b4 = *(const float4*)&Ws[kk][tx*4];
            float aa[4] = {a4.x,a4.y,a4.z,a4.w};
            float bbv[4] = {b4.x,b4.y,b4.z,b4.w};
            #pragma unroll
            for (int i=0;i<4;i++)
                #pragma unroll
                for (int j=0;j<4;j++)
                    acc[i][j] = fmaf(aa[i], bbv[j], acc[i][j]);
        }
    }
    int row0 = bm + ty*4;
    int col0 = bn + tx*4;
    #pragma unroll
    for (int i=0;i<4;i++){
        #pragma unroll
        for (int j=0;j<4;j++){
            int col = col0 + j;
            if (col >= N) continue;
            size_t off = (size_t)(row0+i)*ldc + col;
            float v = acc[i][j];
            if (MODE == GM_RES){
                v += R[(size_t)(row0+i)*ldr + col];
            } else if (MODE == GM_GELU_BN){
                float gl = gelu_exact(v);
                v = (gl - bm_[col])*rsqrtf(bv[col]+1e-5f)*bg[col] + bb[col];
            } else if (MODE == GM_BN_RES){
                float bnv = (v - bm_[col])*rsqrtf(bv[col]+1e-5f)*bg[col] + bb[col];
                v = bnv + R[(size_t)(row0+i)*ldr + col];
            } else if (MODE == GM_BIAS_RELU){
                v = fmaxf(v + bg[col], 0.f);
            }
            C[off] = v;
        }
    }
}

// ---------- gate stage 2: sigmoid(G1 @ w2 + b2) per pixel ----------
__global__ __launch_bounds__(256) void gate2_k(const float* __restrict__ G1,
    const float* __restrict__ w2, const float* __restrict__ b2, float* __restrict__ gpix)
{
    int pix = blockIdx.x*256 + threadIdx.x;      // over HW
    const float4* g4 = (const float4*)(G1 + (size_t)pix*96);
    const float4* w4 = (const float4*)w2;
    float s = b2[0];
    #pragma unroll
    for (int j=0;j<24;j++){
        float4 g = g4[j]; float4 w = w4[j];
        s += g.x*w.x + g.y*w.y + g.z*w.z + g.w*w.w;
    }
    gpix[pix] = 1.f/(1.f+expf(-s));
}

// ---------- deterministic mean of gpix -> dyn_k ----------
__global__ __launch_bounds__(1024) void gate_reduce_k(const float* __restrict__ gpix,
                                                      float* __restrict__ dynk)
{
    __shared__ float sm[16];
    float s = 0.f;
    for (int i=threadIdx.x; i<NPIX; i+=1024) s += gpix[i];
    #pragma unroll
    for (int off=32; off; off>>=1) s += __shfl_xor(s,off,64);
    int wid = threadIdx.x>>6, lane = threadIdx.x&63;
    if (lane==0) sm[wid]=s;
    __syncthreads();
    if (threadIdx.x==0){
        float tot=0.f; for (int i=0;i<16;i++) tot+=sm[i];
        float mean = tot/(float)NPIX;
        *dynk = floorf((float)CPH * mean);
    }
}

// ---------- qkv depthwise 3x3 (288 ch, no bias), single batch image ----------
__global__ __launch_bounds__(256) void qkv_dw_k(const float* __restrict__ in,
    const float* __restrict__ w, float* __restrict__ out)
{
    int idx = blockIdx.x*256 + threadIdx.x;          // over HW*72
    int c4 = idx % 72; int pix = idx / 72;
    int wx = pix % WW; int hy = pix / WW;
    const float4* x4 = (const float4*)in;
    int c0 = c4*4;
    float4 acc; acc.x=0.f; acc.y=0.f; acc.z=0.f; acc.w=0.f;
    for (int ky=0; ky<3; ky++){
        int hh = hy + ky - 1; if (hh < 0 || hh >= HH) continue;
        for (int kx=0; kx<3; kx++){
            int ww2 = wx + kx - 1; if (ww2 < 0 || ww2 >= WW) continue;
            float4 v = x4[((size_t)hh*WW+ww2)*72 + c4];
            int tap = ky*3+kx;
            acc.x += w[(c0+0)*9+tap]*v.x;
            acc.y += w[(c0+1)*9+tap]*v.y;
            acc.z += w[(c0+2)*9+tap]*v.z;
            acc.w += w[(c0+3)*9+tap]*v.w;
        }
    }
    ((float4*)out)[idx] = acc;
}

// ---------- Gram partials per (head, slice): G[12][12], |q|^2[12], |k|^2[12] ----------
__global__ __launch_bounds__(256) void gram_k(const float* __restrict__ QKVd,
                                              float* __restrict__ part)
{
    int h = blockIdx.x;         // 8
    int slice = blockIdx.y;     // 16 (1024 pixels each)
    int qbase = h*12, kbase = 96 + h*12;
    __shared__ float qs[64][12];
    __shared__ float ks[64][12];
    int t = threadIdx.x;
    float acc = 0.f;
    int c = (t<144) ? t/12 : (t<156 ? t-144 : t-156);
    int d = (t<144) ? t%12 : 0;
    for (int st=0; st<16; st++){
        int pix0 = slice*1024 + st*64;
        __syncthreads();
        for (int i=t; i<64*24; i+=256){
            int p = i/24, cc = i%24;
            float v = QKVd[(size_t)(pix0 + p)*288 + (cc<12 ? qbase+cc : kbase+cc-12)];
            if (cc<12) qs[p][cc]=v; else ks[p][cc-12]=v;
        }
        __syncthreads();
        if (t<144){        for (int p=0;p<64;p++) acc = fmaf(qs[p][c], ks[p][d], acc); }
        else if (t<156){   for (int p=0;p<64;p++) acc = fmaf(qs[p][c], qs[p][c], acc); }
        else if (t<168){   for (int p=0;p<64;p++) acc = fmaf(ks[p][c], ks[p][c], acc); }
    }
    if (t<168) part[((size_t)h*16 + slice)*168 + t] = acc;
}

__global__ __launch_bounds__(256) void gram_combine_k(const float* __restrict__ part,
                                                      float* __restrict__ gram)
{
    int i = blockIdx.x*256 + threadIdx.x;
    if (i >= 8*168) return;
    int h = i/168, t = i%168;
    float s = 0.f;
    for (int sl=0; sl<16; sl++) s += part[((size_t)h*16+sl)*168 + t];
    gram[i] = s;
}

// ---------- attn 12x12: normalize, temperature, top-k mask, softmax, *(a1+a2+a3+a4) ----------
__global__ __launch_bounds__(256) void attn_k(const float* __restrict__ gram,
    const float* __restrict__ temp, const float* __restrict__ dynk_p,
    const float* __restrict__ a1, const float* __restrict__ a2,
    const float* __restrict__ a3, const float* __restrict__ a4,
    float* __restrict__ attnW)
{
    int h = blockIdx.x;    // 8 heads
    __shared__ float av[12][12];
    __shared__ float mv[12][12];
    __shared__ float nq[12], nk[12];
    int t = threadIdx.x;
    if (t < 12) nq[t] = fmaxf(sqrtf(gram[h*168+144+t]), 1e-12f);
    else if (t < 24) nk[t-12] = fmaxf(sqrtf(gram[h*168+156+(t-12)]), 1e-12f);
    __syncthreads();
    if (t < 144){
        int c=t/12, d=t%12;
        av[c][d] = gram[h*168+t] / (nq[c]*nk[d]) * temp[h];
    }
    __syncthreads();
    float dk = *dynk_p;
    if (t < 144){
        int c=t/12, d=t%12; float v = av[c][d];
        int r = 0;
        #pragma unroll
        for (int j=0;j<12;j++){
            float o = av[c][j];
            r += (o > v) ? 1 : ((o == v && j < d) ? 1 : 0);
        }
        mv[c][d] = ((float)r < dk) ? v : -INFINITY;
    }
    __syncthreads();
    if (t < 12){
        float mx = -INFINITY;
        for (int d2=0; d2<12; d2++) mx = fmaxf(mx, mv[t][d2]);
        float e[12]; float s = 0.f;
        for (int d2=0; d2<12; d2++){ e[d2] = expf(mv[t][d2]-mx); s += e[d2]; }
        float sc = (a1[0]+a2[0]+a3[0]+a4[0]) / s;
        for (int d2=0; d2<12; d2++) attnW[(size_t)h*144 + t*12 + d2] = e[d2]*sc;
    }
}

// ---------- attn apply + concat x2 -> P (stride 192), single batch ----------
__global__ __launch_bounds__(256) void attn_apply_k(const float* __restrict__ QKVd,
    const float* __restrict__ Y, const float* __restrict__ attnW, float* __restrict__ P)
{
    int idx = blockIdx.x*256 + threadIdx.x;          // HW*192
    int c = idx % 192; size_t pix = (size_t)(idx / 192);
    float outv;
    if (c < 96){
        int h = c/12, cc = c%12;
        const float* vr = QKVd + pix*288 + 192 + h*12;
        const float* aw = attnW + (size_t)h*144 + cc*12;
        float s = 0.f;
        #pragma unroll
        for (int d=0; d<12; d++) s += aw[d]*vr[d];
        outv = s;
    } else {
        outv = Y[pix*192 + c];
    }
    P[pix*192 + c] = outv;
}

// ---------- FFN multi-scale depthwise + residual + gelu + bn2 + mul v0, single batch ----------
__global__ __launch_bounds__(256) void ffn_dw_k(const float* __restrict__ V0,
    const float* __restrict__ w0, const float* __restrict__ bb0,
    const float* __restrict__ w1, const float* __restrict__ bb1,
    const float* __restrict__ w2, const float* __restrict__ bb2,
    const float* __restrict__ w3, const float* __restrict__ bb3,
    const float* __restrict__ bn2g, const float* __restrict__ bn2b,
    const float* __restrict__ bn2m, const float* __restrict__ bn2v,
    float* __restrict__ U)
{
    int ch = threadIdx.x;            // 0..255, wave-uniform group
    size_t pix = blockIdx.x;         // HW
    int wx = (int)(pix % WW);
    int hy = (int)(pix / WW);
    int g = ch >> 6; int cc = ch & 63;
    const float* wt; const float* bp;
    switch(g){
        case 0: wt=w0; bp=bb0; break;
        case 1: wt=w1; bp=bb1; break;
        case 2: wt=w2; bp=bb2; break;
        default: wt=w3; bp=bb3; break;
    }
    int ks = 2*g+1, pad = g;
    wt += cc*ks*ks;
    float acc = bp[cc];
    for (int ky=0; ky<ks; ky++){
        int hh = hy+ky-pad; if (hh<0||hh>=HH) continue;
        for (int kx=0; kx<ks; kx++){
            int ww2 = wx+kx-pad; if (ww2<0||ww2>=WW) continue;
            acc += wt[ky*ks+kx]*V0[((size_t)hh*WW+ww2)*256 + ch];
        }
    }
    float v0 = V0[pix*256+ch];
    float u1 = acc + v0;
    float gl = gelu_exact(u1);
    float bn = (gl - bn2m[ch])*rsqrtf(bn2v[ch]+1e-5f)*bn2g[ch] + bn2b[ch];
    U[pix*256+ch] = bn*v0;
}

extern "C" void kernel_launch(void* const* d_in, const int* in_sizes, int n_in,
                              void* d_out, int out_size, void* d_ws, size_t ws_size,
                              hipStream_t stream)
{
    const float* x     = (const float*)d_in[0];
    const float* pos_w = (const float*)d_in[1];
    const float* pos_b = (const float*)d_in[2];
    const float* ln1g  = (const float*)d_in[3];
    const float* ln1b  = (const float*)d_in[4];
    const float* temp  = (const float*)d_in[5];
    const float* qkvw  = (const float*)d_in[6];
    const float* qkvdw = (const float*)d_in[7];
    const float* projw = (const float*)d_in[8];
    const float* gw1   = (const float*)d_in[9];
    const float* gb1   = (const float*)d_in[10];
    const float* gw2   = (const float*)d_in[11];
    const float* gb2   = (const float*)d_in[12];
    const float* a1    = (const float*)d_in[13];
    const float* a2    = (const float*)d_in[14];
    const float* a3    = (const float*)d_in[15];
    const float* a4    = (const float*)d_in[16];
    const float* ln2g  = (const float*)d_in[17];
    const float* ln2b  = (const float*)d_in[18];
    const float* fc1w  = (const float*)d_in[19];
    const float* bn1g  = (const float*)d_in[20];
    const float* bn1b  = (const float*)d_in[21];
    const float* bn1m  = (const float*)d_in[22];
    const float* bn1v  = (const float*)d_in[23];
    const float* bn2g  = (const float*)d_in[24];
    const float* bn2b  = (const float*)d_in[25];
    const float* bn2m  = (const float*)d_in[26];
    const float* bn2v  = (const float*)d_in[27];
    const float* fc2w  = (const float*)d_in[28];
    const float* bn3g  = (const float*)d_in[29];
    const float* bn3b  = (const float*)d_in[30];
    const float* bn3m  = (const float*)d_in[31];
    const float* bn3v  = (const float*)d_in[32];
    const float* dw0w  = (const float*)d_in[33];
    const float* dw0b  = (const float*)d_in[34];
    const float* dw1w  = (const float*)d_in[35];
    const float* dw1b  = (const float*)d_in[36];
    const float* dw2w  = (const float*)d_in[37];
    const float* dw2b  = (const float*)d_in[38];
    const float* dw3w  = (const float*)d_in[39];
    const float* dw3b  = (const float*)d_in[40];

    float* OUT = (float*)d_out;      // residual stream lives here (A)

    // workspace layout (floats), peak ~63.5 MB
    float* ws = (float*)d_ws;
    float* gpix  = ws;                         // NPIX
    float* dynk  = gpix + NPIX;                // 1 (+63 pad)
    float* gpart = dynk + 64;                  // 8*16*168 = 21504
    float* gram  = gpart + 8*16*168;           // 8*168 = 1344
    float* attnW = gram + 8*168;               // 8*144 = 1152
    float* Yb    = attnW + 2048;               // HW*192
    float* QKVb  = Yb   + (size_t)HW*192;      // HW*288 (also G1b, V0b)
    float* QKVdb = QKVb + (size_t)HW*288;      // HW*288 (also Ub)
    float* Pb    = QKVdb+ (size_t)HW*288;      // HW*192
    float* G1b   = QKVb;                       // HW*96  (loop A reuse)
    float* V0b   = QKVb;                       // HW*256 (phase-2 reuse)
    float* Ub    = QKVdb;                      // HW*256 (phase-2 reuse)

    // 1. pos depthwise conv + bias + residual (full tensor) -> OUT (=A)
    pos_conv_k<<<NPIX*48/256, 256, 0, stream>>>(x, pos_w, pos_b, OUT);

    // 2. gate over all batches: LN1 -> G1 = relu(Y@w1^T+b1) -> gpix
    for (int b=0; b<BB; b++){
        const float* Ab = OUT + (size_t)b*HW*192;
        ln_k<<<HW/4, 256, 0, stream>>>(Ab, ln1g, ln1b, Yb);
        dim3 g(HW/64, 2);
        gemm_k<GM_BIAS_RELU><<<g, 256, 0, stream>>>(Yb, 192, gw1, G1b, 96, nullptr, 0,
                                                    gb1, nullptr, nullptr, nullptr, 96, 192);
        gate2_k<<<HW/256, 256, 0, stream>>>(G1b, gw2, gb2, gpix + (size_t)b*HW);
    }
    gate_reduce_k<<<1, 1024, 0, stream>>>(gpix, dynk);

    // 3. per-batch main pipeline
    for (int b=0; b<BB; b++){
        float* Ab = OUT + (size_t)b*HW*192;
        // LN1 -> Yb
        ln_k<<<HW/4, 256, 0, stream>>>(Ab, ln1g, ln1b, Yb);
        // qkv 1x1: QKVb = Yb[:, :96] @ qkvw^T  (M=HW, K=96, N=288)
        {
            dim3 g(HW/64, 5);
            gemm_k<GM_NONE><<<g, 256, 0, stream>>>(Yb, 192, qkvw, QKVb, 288, nullptr, 0,
                                                   nullptr,nullptr,nullptr,nullptr, 288, 96);
        }
        // qkv depthwise 3x3
        qkv_dw_k<<<HW*72/256, 256, 0, stream>>>(QKVb, qkvdw, QKVdb);
        // Gram partials + combine
        { dim3 g(8, 16); gram_k<<<g, 256, 0, stream>>>(QKVdb, gpart); }
        gram_combine_k<<<(8*168+255)/256, 256, 0, stream>>>(gpart, gram);
        // attention 12x12 softmax/top-k
        attn_k<<<8, 256, 0, stream>>>(gram, temp, dynk, a1,a2,a3,a4, attnW);
        // attn apply + concat x2 -> Pb
        attn_apply_k<<<HW*192/256, 256, 0, stream>>>(QKVdb, Yb, attnW, Pb);
        // proj + residual in-place: Ab += Pb @ projw^T
        {
            dim3 g(HW/64, 3);
            gemm_k<GM_RES><<<g, 256, 0, stream>>>(Pb, 192, projw, Ab, 192, Ab, 192,
                                                  nullptr,nullptr,nullptr,nullptr, 192, 192);
        }
        // LN2 -> Zb (reuse Yb)
        ln_k<<<HW/4, 256, 0, stream>>>(Ab, ln2g, ln2b, Yb);
        // fc1 + gelu + bn1 -> V0b
        {
            dim3 g(HW/64, 4);
            gemm_k<GM_GELU_BN><<<g, 256, 0, stream>>>(Yb, 192, fc1w, V0b, 256, nullptr, 0,
                                                      bn1g,bn1b,bn1m,bn1v, 256, 192);
        }
        // multi-scale depthwise + residual + gelu + bn2 + *v0 -> Ub
        ffn_dw_k<<<HW, 256, 0, stream>>>(V0b, dw0w,dw0b,dw1w,dw1b,dw2w,dw2b,dw3w,dw3b,
                                         bn2g,bn2b,bn2m,bn2v, Ub);
        // fc2 + bn3 + residual -> OUT (in place over Ab)
        {
            dim3 g(HW/64, 3);
            gemm_k<GM_BN_RES><<<g, 256, 0, stream>>>(Ub, 256, fc2w, Ab, 192, Ab, 192,
                                                     bn3g,bn3b,bn3m,bn3v, 192, 256);
        }
    }
}

// Round 3
// 2739.822 us; speedup vs baseline: 1.1936x; 1.1936x over previous
//
#include <hip/hip_runtime.h>
#include <hip/hip_bf16.h>
#include <math.h>

#define BB 8
#define HH 128
#define WW 128
#define HW (HH*WW)          // 16384
#define NPIX (BB*HW)        // 131072
#define CEMB 192
#define PD 96
#define C3 288
#define NHEAD 8
#define CPH 12
#define HIDC 256

typedef __attribute__((ext_vector_type(4))) float  floatx4;
typedef __attribute__((ext_vector_type(4))) short  short4v;
typedef __attribute__((ext_vector_type(8))) short  short8v;

static __device__ __forceinline__ float gelu_exact(float x){
    return 0.5f*x*(1.0f+erff(x*0.70710678118654752440f));
}
static __device__ __forceinline__ unsigned int pack_bf16(float a, float b){
    __hip_bfloat162 h2 = __float22bfloat162_rn(make_float2(a,b));
    return *(unsigned int*)&h2;
}

// ---------- pos depthwise 3x3 + bias + residual, sliding-window over W ----------
// thread = (b, hy, c4-group of 4 channels); block 64 threads (1 wave)
__global__ __launch_bounds__(64) void pos_conv_k(const float* __restrict__ x,
    const float* __restrict__ w, const float* __restrict__ bias, float* __restrict__ out)
{
    int idx = blockIdx.x*64 + threadIdx.x;           // (b*HH + hy)*48 + c4
    int c4 = idx % 48; int rest = idx / 48; int hy = rest % HH; int b = rest / HH;
    int c0 = c4*4;
    float wr[3][3][4];
    #pragma unroll
    for (int j=0;j<4;j++)
        #pragma unroll
        for (int ky=0;ky<3;ky++)
            #pragma unroll
            for (int kx=0;kx<3;kx++)
                wr[ky][kx][j] = w[(c0+j)*9 + ky*3 + kx];
    float4 bias4 = *(const float4*)(bias + c0);
    const float4* x4 = (const float4*)x;
    const float4* r0 = x4 + ((size_t)(b*HH + hy-1)*WW)*48 + c4;
    const float4* r1 = x4 + ((size_t)(b*HH + hy  )*WW)*48 + c4;
    const float4* r2 = x4 + ((size_t)(b*HH + hy+1)*WW)*48 + c4;
    bool v0 = hy > 0, v2 = hy < HH-1;
    float4 z4 = make_float4(0.f,0.f,0.f,0.f);
    float4 cA[3], cB[3], cC[3], cN[3];
    cA[0]=z4; cA[1]=z4; cA[2]=z4;
    cB[0] = v0 ? r0[0] : z4;  cB[1] = r1[0];  cB[2] = v2 ? r2[0] : z4;
    cC[0] = v0 ? r0[48] : z4; cC[1] = r1[48]; cC[2] = v2 ? r2[48] : z4;
    float4* o4 = (float4*)out + ((size_t)(b*HH + hy)*WW)*48 + c4;
    for (int wx=0; wx<WW; wx++){
        // prefetch column wx+2 (consumed next iteration)
        bool okc = (wx+2) < WW;
        size_t noff = (size_t)(wx+2)*48;
        cN[0] = (v0 && okc) ? r0[noff] : z4;
        cN[1] = okc ? r1[noff] : z4;
        cN[2] = (v2 && okc) ? r2[noff] : z4;
        float4 acc = bias4;
        #pragma unroll
        for (int i=0;i<3;i++){
            acc.x = fmaf(wr[i][0][0], cA[i].x, acc.x);
            acc.y = fmaf(wr[i][0][1], cA[i].y, acc.y);
            acc.z = fmaf(wr[i][0][2], cA[i].z, acc.z);
            acc.w = fmaf(wr[i][0][3], cA[i].w, acc.w);
            acc.x = fmaf(wr[i][1][0], cB[i].x, acc.x);
            acc.y = fmaf(wr[i][1][1], cB[i].y, acc.y);
            acc.z = fmaf(wr[i][1][2], cB[i].z, acc.z);
            acc.w = fmaf(wr[i][1][3], cB[i].w, acc.w);
            acc.x = fmaf(wr[i][2][0], cC[i].x, acc.x);
            acc.y = fmaf(wr[i][2][1], cC[i].y, acc.y);
            acc.z = fmaf(wr[i][2][2], cC[i].z, acc.z);
            acc.w = fmaf(wr[i][2][3], cC[i].w, acc.w);
        }
        acc.x += cB[1].x; acc.y += cB[1].y; acc.z += cB[1].z; acc.w += cB[1].w;
        o4[(size_t)wx*48] = acc;
        #pragma unroll
        for (int i=0;i<3;i++){ cA[i]=cB[i]; cB[i]=cC[i]; cC[i]=cN[i]; }
    }
}

// ---------- LayerNorm over C=192, wave per pixel ----------
__global__ __launch_bounds__(256) void ln_k(const float* __restrict__ in,
    const float* __restrict__ g, const float* __restrict__ bta, float* __restrict__ out)
{
    int wid = threadIdx.x >> 6, lane = threadIdx.x & 63;
    size_t pix = (size_t)blockIdx.x*4 + wid;
    const float* row = in + pix*192;
    float x0 = row[lane], x1 = row[lane+64], x2 = row[lane+128];
    float s = x0+x1+x2;
    float q = x0*x0 + x1*x1 + x2*x2;
    #pragma unroll
    for (int off=32; off; off>>=1){ s += __shfl_xor(s,off,64); q += __shfl_xor(q,off,64); }
    float mean = s*(1.f/192.f);
    float var  = q*(1.f/192.f) - mean*mean;
    float inv  = rsqrtf(var + 1e-6f);
    float* orow = out + pix*192;
    orow[lane]     = (x0-mean)*inv*g[lane]     + bta[lane];
    orow[lane+64]  = (x1-mean)*inv*g[lane+64]  + bta[lane+64];
    orow[lane+128] = (x2-mean)*inv*g[lane+128] + bta[lane+128];
}

// ---------- bf16 MFMA GEMM: C[M,N] = epi(A[M,K] @ W[N,K]^T) ----------
// tile 128x64, BK=64, 4 waves (2x2), per wave 64x32 = 4x2 fragments of 16x16
#define GM_NONE 0
#define GM_RES 1
#define GM_GELU_BN 2
#define GM_BN_RES 3
#define GM_BIAS_RELU 4

template<int MODE>
__global__ __launch_bounds__(256) void gemm_bf16_k(
    const float* __restrict__ A, int lda,
    const float* __restrict__ W,
    float* __restrict__ C, int ldc,
    const float* __restrict__ R, int ldr,
    const float* __restrict__ bg, const float* __restrict__ bb,
    const float* __restrict__ bm_, const float* __restrict__ bv,
    int N, int K)
{
    __shared__ short As[128*68];   // row stride 68 bf16 (136 B) -> conflict-free b64 reads
    __shared__ short Ws[64*68];
    int t = threadIdx.x;
    int bm = blockIdx.x * 128;
    int bn = blockIdx.y * 64;
    int wave = t >> 6, lane = t & 63;
    int wm = (wave >> 1)*64, wn = (wave & 1)*32;
    int lr = lane & 15, lk = lane >> 4;
    floatx4 acc[4][2] = {};

    int arow = t >> 1, ahalf = t & 1;   // A staging: 2 threads/row, 32 k each
    int brow = t >> 2, bq   = t & 3;    // B staging: 4 threads/row, 16 k each

    for (int k0 = 0; k0 < K; k0 += 64){
        __syncthreads();
        {   // stage A tile (128 x 64 fp32 -> bf16)
            const float* src = A + (size_t)(bm + arow)*lda + k0 + ahalf*32;
            #pragma unroll
            for (int j=0;j<8;j++){
                int kk = k0 + ahalf*32 + 4*j;
                float4 v = (kk < K) ? *(const float4*)(src + 4*j) : make_float4(0,0,0,0);
                uint2 p = make_uint2(pack_bf16(v.x,v.y), pack_bf16(v.z,v.w));
                *(uint2*)&As[arow*68 + ahalf*32 + 4*j] = p;
            }
        }
        {   // stage W tile (64 x 64 fp32 -> bf16), guard n < N
            int n = bn + brow;
            bool nv = n < N;
            const float* src = W + (size_t)n*K + k0 + bq*16;
            #pragma unroll
            for (int j=0;j<4;j++){
                int kk = k0 + bq*16 + 4*j;
                float4 v = (nv && kk < K) ? *(const float4*)(src + 4*j) : make_float4(0,0,0,0);
                uint2 p = make_uint2(pack_bf16(v.x,v.y), pack_bf16(v.z,v.w));
                *(uint2*)&Ws[brow*68 + bq*16 + 4*j] = p;
            }
        }
        __syncthreads();
        #pragma unroll
        for (int s=0; s<2; s++){
            int kb = s*32 + lk*8;
            short8v bfr[2];
            #pragma unroll
            for (int n=0;n<2;n++){
                const short4v* p = (const short4v*)&Ws[(wn + n*16 + lr)*68 + kb];
                short4v lo = p[0], hi = p[1];
                bfr[n] = __builtin_shufflevector(lo, hi, 0,1,2,3,4,5,6,7);
            }
            #pragma unroll
            for (int m=0;m<4;m++){
                const short4v* p = (const short4v*)&As[(wm + m*16 + lr)*68 + kb];
                short4v lo = p[0], hi = p[1];
                short8v afr = __builtin_shufflevector(lo, hi, 0,1,2,3,4,5,6,7);
                acc[m][0] = __builtin_amdgcn_mfma_f32_16x16x32_bf16(afr, bfr[0], acc[m][0], 0,0,0);
                acc[m][1] = __builtin_amdgcn_mfma_f32_16x16x32_bf16(afr, bfr[1], acc[m][1], 0,0,0);
            }
        }
    }
    // epilogue: C/D frag layout col=lane&15, row=(lane>>4)*4+reg
    #pragma unroll
    for (int m=0;m<4;m++){
        #pragma unroll
        for (int n=0;n<2;n++){
            #pragma unroll
            for (int rg=0; rg<4; rg++){
                int gcol = bn + wn + n*16 + lr;
                if (gcol >= N) continue;
                int grow = bm + wm + m*16 + lk*4 + rg;
                float v = acc[m][n][rg];
                if (MODE == GM_RES){
                    v += R[(size_t)grow*ldr + gcol];
                } else if (MODE == GM_GELU_BN){
                    float gl = gelu_exact(v);
                    v = (gl - bm_[gcol])*rsqrtf(bv[gcol]+1e-5f)*bg[gcol] + bb[gcol];
                } else if (MODE == GM_BN_RES){
                    float bnv = (v - bm_[gcol])*rsqrtf(bv[gcol]+1e-5f)*bg[gcol] + bb[gcol];
                    v = bnv + R[(size_t)grow*ldr + gcol];
                } else if (MODE == GM_BIAS_RELU){
                    v = fmaxf(v + bg[gcol], 0.f);
                }
                C[(size_t)grow*ldc + gcol] = v;
            }
        }
    }
}

// ---------- gate stage 2: sigmoid(G1 @ w2 + b2) per pixel ----------
__global__ __launch_bounds__(256) void gate2_k(const float* __restrict__ G1,
    const float* __restrict__ w2, const float* __restrict__ b2, float* __restrict__ gpix)
{
    int pix = blockIdx.x*256 + threadIdx.x;      // over HW
    const float4* g4 = (const float4*)(G1 + (size_t)pix*96);
    const float4* w4 = (const float4*)w2;
    float s = b2[0];
    #pragma unroll
    for (int j=0;j<24;j++){
        float4 g = g4[j]; float4 w = w4[j];
        s += g.x*w.x + g.y*w.y + g.z*w.z + g.w*w.w;
    }
    gpix[pix] = 1.f/(1.f+expf(-s));
}

// ---------- deterministic mean of gpix -> dyn_k ----------
__global__ __launch_bounds__(1024) void gate_reduce_k(const float* __restrict__ gpix,
                                                      float* __restrict__ dynk)
{
    __shared__ float sm[16];
    float s = 0.f;
    for (int i=threadIdx.x; i<NPIX; i+=1024) s += gpix[i];
    #pragma unroll
    for (int off=32; off; off>>=1) s += __shfl_xor(s,off,64);
    int wid = threadIdx.x>>6, lane = threadIdx.x&63;
    if (lane==0) sm[wid]=s;
    __syncthreads();
    if (threadIdx.x==0){
        float tot=0.f; for (int i=0;i<16;i++) tot+=sm[i];
        float mean = tot/(float)NPIX;
        *dynk = floorf((float)CPH * mean);
    }
}

// ---------- qkv depthwise 3x3 (288 ch, no bias), single batch image ----------
__global__ __launch_bounds__(256) void qkv_dw_k(const float* __restrict__ in,
    const float* __restrict__ w, float* __restrict__ out)
{
    int idx = blockIdx.x*256 + threadIdx.x;          // over HW*72
    int c4 = idx % 72; int pix = idx / 72;
    int wx = pix % WW; int hy = pix / WW;
    const float4* x4 = (const float4*)in;
    int c0 = c4*4;
    float4 acc; acc.x=0.f; acc.y=0.f; acc.z=0.f; acc.w=0.f;
    for (int ky=0; ky<3; ky++){
        int hh = hy + ky - 1; if (hh < 0 || hh >= HH) continue;
        for (int kx=0; kx<3; kx++){
            int ww2 = wx + kx - 1; if (ww2 < 0 || ww2 >= WW) continue;
            float4 v = x4[((size_t)hh*WW+ww2)*72 + c4];
            int tap = ky*3+kx;
            acc.x += w[(c0+0)*9+tap]*v.x;
            acc.y += w[(c0+1)*9+tap]*v.y;
            acc.z += w[(c0+2)*9+tap]*v.z;
            acc.w += w[(c0+3)*9+tap]*v.w;
        }
    }
    ((float4*)out)[idx] = acc;
}

// ---------- Gram partials per (head, slice): G[12][12], |q|^2[12], |k|^2[12] ----------
__global__ __launch_bounds__(256) void gram_k(const float* __restrict__ QKVd,
                                              float* __restrict__ part)
{
    int h = blockIdx.x;         // 8
    int slice = blockIdx.y;     // 16 (1024 pixels each)
    int qbase = h*12, kbase = 96 + h*12;
    __shared__ float qs[64][12];
    __shared__ float ks[64][12];
    int t = threadIdx.x;
    float acc = 0.f;
    int c = (t<144) ? t/12 : (t<156 ? t-144 : t-156);
    int d = (t<144) ? t%12 : 0;
    for (int st=0; st<16; st++){
        int pix0 = slice*1024 + st*64;
        __syncthreads();
        for (int i=t; i<64*24; i+=256){
            int p = i/24, cc = i%24;
            float v = QKVd[(size_t)(pix0 + p)*288 + (cc<12 ? qbase+cc : kbase+cc-12)];
            if (cc<12) qs[p][cc]=v; else ks[p][cc-12]=v;
        }
        __syncthreads();
        if (t<144){        for (int p=0;p<64;p++) acc = fmaf(qs[p][c], ks[p][d], acc); }
        else if (t<156){   for (int p=0;p<64;p++) acc = fmaf(qs[p][c], qs[p][c], acc); }
        else if (t<168){   for (int p=0;p<64;p++) acc = fmaf(ks[p][c], ks[p][c], acc); }
    }
    if (t<168) part[((size_t)h*16 + slice)*168 + t] = acc;
}

__global__ __launch_bounds__(256) void gram_combine_k(const float* __restrict__ part,
                                                      float* __restrict__ gram)
{
    int i = blockIdx.x*256 + threadIdx.x;
    if (i >= 8*168) return;
    int h = i/168, t = i%168;
    float s = 0.f;
    for (int sl=0; sl<16; sl++) s += part[((size_t)h*16+sl)*168 + t];
    gram[i] = s;
}

// ---------- attn 12x12: normalize, temperature, top-k mask, softmax, *(a1+a2+a3+a4) ----------
__global__ __launch_bounds__(256) void attn_k(const float* __restrict__ gram,
    const float* __restrict__ temp, const float* __restrict__ dynk_p,
    const float* __restrict__ a1, const float* __restrict__ a2,
    const float* __restrict__ a3, const float* __restrict__ a4,
    float* __restrict__ attnW)
{
    int h = blockIdx.x;    // 8 heads
    __shared__ float av[12][12];
    __shared__ float mv[12][12];
    __shared__ float nq[12], nk[12];
    int t = threadIdx.x;
    if (t < 12) nq[t] = fmaxf(sqrtf(gram[h*168+144+t]), 1e-12f);
    else if (t < 24) nk[t-12] = fmaxf(sqrtf(gram[h*168+156+(t-12)]), 1e-12f);
    __syncthreads();
    if (t < 144){
        int c=t/12, d=t%12;
        av[c][d] = gram[h*168+t] / (nq[c]*nk[d]) * temp[h];
    }
    __syncthreads();
    float dk = *dynk_p;
    if (t < 144){
        int c=t/12, d=t%12; float v = av[c][d];
        int r = 0;
        #pragma unroll
        for (int j=0;j<12;j++){
            float o = av[c][j];
            r += (o > v) ? 1 : ((o == v && j < d) ? 1 : 0);
        }
        mv[c][d] = ((float)r < dk) ? v : -INFINITY;
    }
    __syncthreads();
    if (t < 12){
        float mx = -INFINITY;
        for (int d2=0; d2<12; d2++) mx = fmaxf(mx, mv[t][d2]);
        float e[12]; float s = 0.f;
        for (int d2=0; d2<12; d2++){ e[d2] = expf(mv[t][d2]-mx); s += e[d2]; }
        float sc = (a1[0]+a2[0]+a3[0]+a4[0]) / s;
        for (int d2=0; d2<12; d2++) attnW[(size_t)h*144 + t*12 + d2] = e[d2]*sc;
    }
}

// ---------- attn apply + concat x2 -> P (stride 192), single batch ----------
__global__ __launch_bounds__(256) void attn_apply_k(const float* __restrict__ QKVd,
    const float* __restrict__ Y, const float* __restrict__ attnW, float* __restrict__ P)
{
    int idx = blockIdx.x*256 + threadIdx.x;          // HW*192
    int c = idx % 192; size_t pix = (size_t)(idx / 192);
    float outv;
    if (c < 96){
        int h = c/12, cc = c%12;
        const float* vr = QKVd + pix*288 + 192 + h*12;
        const float* aw = attnW + (size_t)h*144 + cc*12;
        float s = 0.f;
        #pragma unroll
        for (int d=0; d<12; d++) s += aw[d]*vr[d];
        outv = s;
    } else {
        outv = Y[pix*192 + c];
    }
    P[pix*192 + c] = outv;
}

// ---------- FFN multi-scale depthwise + residual + gelu + bn2 + mul v0, single batch ----------
__global__ __launch_bounds__(256) void ffn_dw_k(const float* __restrict__ V0,
    const float* __restrict__ w0, const float* __restrict__ bb0,
    const float* __restrict__ w1, const float* __restrict__ bb1,
    const float* __restrict__ w2, const float* __restrict__ bb2,
    const float* __restrict__ w3, const float* __restrict__ bb3,
    const float* __restrict__ bn2g, const float* __restrict__ bn2b,
    const float* __restrict__ bn2m, const float* __restrict__ bn2v,
    float* __restrict__ U)
{
    int ch = threadIdx.x;            // 0..255, wave-uniform group
    size_t pix = blockIdx.x;         // HW
    int wx = (int)(pix % WW);
    int hy = (int)(pix / WW);
    int g = ch >> 6; int cc = ch & 63;
    const float* wt; const float* bp;
    switch(g){
        case 0: wt=w0; bp=bb0; break;
        case 1: wt=w1; bp=bb1; break;
        case 2: wt=w2; bp=bb2; break;
        default: wt=w3; bp=bb3; break;
    }
    int ks = 2*g+1, pad = g;
    wt += cc*ks*ks;
    float acc = bp[cc];
    for (int ky=0; ky<ks; ky++){
        int hh = hy+ky-pad; if (hh<0||hh>=HH) continue;
        for (int kx=0; kx<ks; kx++){
            int ww2 = wx+kx-pad; if (ww2<0||ww2>=WW) continue;
            acc += wt[ky*ks+kx]*V0[((size_t)hh*WW+ww2)*256 + ch];
        }
    }
    float v0 = V0[pix*256+ch];
    float u1 = acc + v0;
    float gl = gelu_exact(u1);
    float bn = (gl - bn2m[ch])*rsqrtf(bn2v[ch]+1e-5f)*bn2g[ch] + bn2b[ch];
    U[pix*256+ch] = bn*v0;
}

extern "C" void kernel_launch(void* const* d_in, const int* in_sizes, int n_in,
                              void* d_out, int out_size, void* d_ws, size_t ws_size,
                              hipStream_t stream)
{
    const float* x     = (const float*)d_in[0];
    const float* pos_w = (const float*)d_in[1];
    const float* pos_b = (const float*)d_in[2];
    const float* ln1g  = (const float*)d_in[3];
    const float* ln1b  = (const float*)d_in[4];
    const float* temp  = (const float*)d_in[5];
    const float* qkvw  = (const float*)d_in[6];
    const float* qkvdw = (const float*)d_in[7];
    const float* projw = (const float*)d_in[8];
    const float* gw1   = (const float*)d_in[9];
    const float* gb1   = (const float*)d_in[10];
    const float* gw2   = (const float*)d_in[11];
    const float* gb2   = (const float*)d_in[12];
    const float* a1    = (const float*)d_in[13];
    const float* a2    = (const float*)d_in[14];
    const float* a3    = (const float*)d_in[15];
    const float* a4    = (const float*)d_in[16];
    const float* ln2g  = (const float*)d_in[17];
    const float* ln2b  = (const float*)d_in[18];
    const float* fc1w  = (const float*)d_in[19];
    const float* bn1g  = (const float*)d_in[20];
    const float* bn1b  = (const float*)d_in[21];
    const float* bn1m  = (const float*)d_in[22];
    const float* bn1v  = (const float*)d_in[23];
    const float* bn2g  = (const float*)d_in[24];
    const float* bn2b  = (const float*)d_in[25];
    const float* bn2m  = (const float*)d_in[26];
    const float* bn2v  = (const float*)d_in[27];
    const float* fc2w  = (const float*)d_in[28];
    const float* bn3g  = (const float*)d_in[29];
    const float* bn3b  = (const float*)d_in[30];
    const float* bn3m  = (const float*)d_in[31];
    const float* bn3v  = (const float*)d_in[32];
    const float* dw0w  = (const float*)d_in[33];
    const float* dw0b  = (const float*)d_in[34];
    const float* dw1w  = (const float*)d_in[35];
    const float* dw1b  = (const float*)d_in[36];
    const float* dw2w  = (const float*)d_in[37];
    const float* dw2b  = (const float*)d_in[38];
    const float* dw3w  = (const float*)d_in[39];
    const float* dw3b  = (const float*)d_in[40];

    float* OUT = (float*)d_out;      // residual stream lives here (A)

    // workspace layout (floats), peak ~63.5 MB
    float* ws = (float*)d_ws;
    float* gpix  = ws;                         // NPIX
    float* dynk  = gpix + NPIX;                // 1 (+63 pad)
    float* gpart = dynk + 64;                  // 8*16*168 = 21504
    float* gram  = gpart + 8*16*168;           // 8*168 = 1344
    float* attnW = gram + 8*168;               // 8*144 = 1152
    float* Yb    = attnW + 2048;               // HW*192
    float* QKVb  = Yb   + (size_t)HW*192;      // HW*288 (also G1b, V0b)
    float* QKVdb = QKVb + (size_t)HW*288;      // HW*288 (also Ub)
    float* Pb    = QKVdb+ (size_t)HW*288;      // HW*192
    float* G1b   = QKVb;                       // HW*96  (gate loop reuse)
    float* V0b   = QKVb;                       // HW*256 (phase-2 reuse)
    float* Ub    = QKVdb;                      // HW*256 (phase-2 reuse)

    // 1. pos depthwise conv + bias + residual (full tensor) -> OUT (=A)
    pos_conv_k<<<BB*HH*48/64, 64, 0, stream>>>(x, pos_w, pos_b, OUT);

    // 2. gate over all batches: LN1 -> G1 = relu(Y@w1^T+b1) -> gpix
    for (int b=0; b<BB; b++){
        const float* Ab = OUT + (size_t)b*HW*192;
        ln_k<<<HW/4, 256, 0, stream>>>(Ab, ln1g, ln1b, Yb);
        dim3 g(HW/128, 2);
        gemm_bf16_k<GM_BIAS_RELU><<<g, 256, 0, stream>>>(Yb, 192, gw1, G1b, 96, nullptr, 0,
                                                         gb1, nullptr, nullptr, nullptr, 96, 192);
        gate2_k<<<HW/256, 256, 0, stream>>>(G1b, gw2, gb2, gpix + (size_t)b*HW);
    }
    gate_reduce_k<<<1, 1024, 0, stream>>>(gpix, dynk);

    // 3. per-batch main pipeline
    for (int b=0; b<BB; b++){
        float* Ab = OUT + (size_t)b*HW*192;
        // LN1 -> Yb
        ln_k<<<HW/4, 256, 0, stream>>>(Ab, ln1g, ln1b, Yb);
        // qkv 1x1: QKVb = Yb[:, :96] @ qkvw^T  (M=HW, K=96, N=288)
        {
            dim3 g(HW/128, 5);
            gemm_bf16_k<GM_NONE><<<g, 256, 0, stream>>>(Yb, 192, qkvw, QKVb, 288, nullptr, 0,
                                                        nullptr,nullptr,nullptr,nullptr, 288, 96);
        }
        // qkv depthwise 3x3
        qkv_dw_k<<<HW*72/256, 256, 0, stream>>>(QKVb, qkvdw, QKVdb);
        // Gram partials + combine
        { dim3 g(8, 16); gram_k<<<g, 256, 0, stream>>>(QKVdb, gpart); }
        gram_combine_k<<<(8*168+255)/256, 256, 0, stream>>>(gpart, gram);
        // attention 12x12 softmax/top-k
        attn_k<<<8, 256, 0, stream>>>(gram, temp, dynk, a1,a2,a3,a4, attnW);
        // attn apply + concat x2 -> Pb
        attn_apply_k<<<HW*192/256, 256, 0, stream>>>(QKVdb, Yb, attnW, Pb);
        // proj + residual in-place: Ab += Pb @ projw^T
        {
            dim3 g(HW/128, 3);
            gemm_bf16_k<GM_RES><<<g, 256, 0, stream>>>(Pb, 192, projw, Ab, 192, Ab, 192,
                                                       nullptr,nullptr,nullptr,nullptr, 192, 192);
        }
        // LN2 -> Zb (reuse Yb)
        ln_k<<<HW/4, 256, 0, stream>>>(Ab, ln2g, ln2b, Yb);
        // fc1 + gelu + bn1 -> V0b
        {
            dim3 g(HW/128, 4);
            gemm_bf16_k<GM_GELU_BN><<<g, 256, 0, stream>>>(Yb, 192, fc1w, V0b, 256, nullptr, 0,
                                                           bn1g,bn1b,bn1m,bn1v, 256, 192);
        }
        // multi-scale depthwise + residual + gelu + bn2 + *v0 -> Ub
        ffn_dw_k<<<HW, 256, 0, stream>>>(V0b, dw0w,dw0b,dw1w,dw1b,dw2w,dw2b,dw3w,dw3b,
                                         bn2g,bn2b,bn2m,bn2v, Ub);
        // fc2 + bn3 + residual -> OUT (in place over Ab)
        {
            dim3 g(HW/128, 3);
            gemm_bf16_k<GM_BN_RES><<<g, 256, 0, stream>>>(Ub, 256, fc2w, Ab, 192, Ab, 192,
                                                          bn3g,bn3b,bn3m,bn3v, 192, 256);
        }
    }
}

// Round 4
// 1954.494 us; speedup vs baseline: 1.6732x; 1.4018x over previous
//
#include <hip/hip_runtime.h>
#include <hip/hip_bf16.h>
#include <math.h>

#define BB 8
#define HH 128
#define WW 128
#define HW (HH*WW)          // 16384
#define NPIX (BB*HW)        // 131072
#define CB 2                // images per chunk
#define CHW (CB*HW)         // 32768
#define NCHUNK (BB/CB)

typedef unsigned short u16;
typedef __attribute__((ext_vector_type(4))) float  floatx4;
typedef __attribute__((ext_vector_type(4))) short  short4v;
typedef __attribute__((ext_vector_type(8))) short  short8v;

static __device__ __forceinline__ float gelu_exact(float x){
    return 0.5f*x*(1.0f+erff(x*0.70710678118654752440f));
}
static __device__ __forceinline__ float b2f(u16 v){
    union { unsigned u; float f; } x; x.u = ((unsigned)v)<<16; return x.f;
}
static __device__ __forceinline__ u16 f2b(float f){
    __hip_bfloat16 h = __float2bfloat16(f);
    return *(u16*)&h;
}

// ---------- weight prep: fp32 -> bf16 for the five GEMM weight matrices ----------
#define WQ 27648
#define WP 36864
#define WG 18432
#define WF1 49152
#define WF2 49152
#define WTOT (WQ+WP+WG+WF1+WF2)   // 181248
__global__ __launch_bounds__(256) void wprep_k(const float* __restrict__ a,
    const float* __restrict__ b, const float* __restrict__ c,
    const float* __restrict__ d, const float* __restrict__ e, u16* __restrict__ o)
{
    int i = blockIdx.x*256 + threadIdx.x;
    if (i >= WTOT) return;
    float v;
    if (i < WQ) v = a[i];
    else if (i < WQ+WP) v = b[i-WQ];
    else if (i < WQ+WP+WG) v = c[i-WQ-WP];
    else if (i < WQ+WP+WG+WF1) v = d[i-WQ-WP-WG];
    else v = e[i-WQ-WP-WG-WF1];
    o[i] = f2b(v);
}

// ---------- pos depthwise 3x3 + bias + residual, 32-col segments ----------
__global__ __launch_bounds__(256) void pos_conv_k(const float* __restrict__ x,
    const float* __restrict__ w, const float* __restrict__ bias, float* __restrict__ out)
{
    int gid = blockIdx.x*256 + threadIdx.x;     // ((b*HH+hy)*4 + seg)*48 + c4
    int c4 = gid % 48; int rest = gid / 48;
    int seg = rest & 3; rest >>= 2;
    int hy = rest % HH; int b = rest / HH;
    int c0 = c4*4;
    float wr[3][3][4];
    #pragma unroll
    for (int j=0;j<4;j++)
        #pragma unroll
        for (int ky=0;ky<3;ky++)
            #pragma unroll
            for (int kx=0;kx<3;kx++)
                wr[ky][kx][j] = w[(c0+j)*9 + ky*3 + kx];
    float4 bias4 = *(const float4*)(bias + c0);
    const float4* x4 = (const float4*)x;
    const float4* r0 = x4 + ((size_t)(b*HH + hy-1)*WW)*48 + c4;
    const float4* r1 = x4 + ((size_t)(b*HH + hy  )*WW)*48 + c4;
    const float4* r2 = x4 + ((size_t)(b*HH + hy+1)*WW)*48 + c4;
    bool v0 = hy > 0, v2 = hy < HH-1;
    float4 z4 = make_float4(0.f,0.f,0.f,0.f);
    int s0 = seg*32;
    float4 cA[3], cB[3], cC[3], cN[3];
    bool la = s0 > 0;
    cA[0] = (v0&&la) ? r0[(size_t)(s0-1)*48] : z4;
    cA[1] = la ? r1[(size_t)(s0-1)*48] : z4;
    cA[2] = (v2&&la) ? r2[(size_t)(s0-1)*48] : z4;
    cB[0] = v0 ? r0[(size_t)s0*48] : z4;  cB[1] = r1[(size_t)s0*48];  cB[2] = v2 ? r2[(size_t)s0*48] : z4;
    cC[0] = v0 ? r0[(size_t)(s0+1)*48] : z4; cC[1] = r1[(size_t)(s0+1)*48]; cC[2] = v2 ? r2[(size_t)(s0+1)*48] : z4;
    float4* o4 = (float4*)out + ((size_t)(b*HH + hy)*WW)*48 + c4;
    for (int i2=0; i2<32; i2++){
        int wx = s0 + i2;
        bool okc = (wx+2) < WW;
        size_t noff = (size_t)(wx+2)*48;
        cN[0] = (v0 && okc) ? r0[noff] : z4;
        cN[1] = okc ? r1[noff] : z4;
        cN[2] = (v2 && okc) ? r2[noff] : z4;
        float4 acc = bias4;
        #pragma unroll
        for (int i=0;i<3;i++){
            acc.x = fmaf(wr[i][0][0], cA[i].x, acc.x);
            acc.y = fmaf(wr[i][0][1], cA[i].y, acc.y);
            acc.z = fmaf(wr[i][0][2], cA[i].z, acc.z);
            acc.w = fmaf(wr[i][0][3], cA[i].w, acc.w);
            acc.x = fmaf(wr[i][1][0], cB[i].x, acc.x);
            acc.y = fmaf(wr[i][1][1], cB[i].y, acc.y);
            acc.z = fmaf(wr[i][1][2], cB[i].z, acc.z);
            acc.w = fmaf(wr[i][1][3], cB[i].w, acc.w);
            acc.x = fmaf(wr[i][2][0], cC[i].x, acc.x);
            acc.y = fmaf(wr[i][2][1], cC[i].y, acc.y);
            acc.z = fmaf(wr[i][2][2], cC[i].z, acc.z);
            acc.w = fmaf(wr[i][2][3], cC[i].w, acc.w);
        }
        acc.x += cB[1].x; acc.y += cB[1].y; acc.z += cB[1].z; acc.w += cB[1].w;
        o4[(size_t)wx*48] = acc;
        #pragma unroll
        for (int i=0;i<3;i++){ cA[i]=cB[i]; cB[i]=cC[i]; cC[i]=cN[i]; }
    }
}

// ---------- LayerNorm over C=192 fp32 in -> bf16 out, wave per pixel ----------
__global__ __launch_bounds__(256) void ln_k(const float* __restrict__ in,
    const float* __restrict__ g, const float* __restrict__ bta, u16* __restrict__ out)
{
    int wid = threadIdx.x >> 6, lane = threadIdx.x & 63;
    size_t pix = (size_t)blockIdx.x*4 + wid;
    const float* row = in + pix*192;
    float x0 = row[lane], x1 = row[lane+64], x2 = row[lane+128];
    float s = x0+x1+x2;
    float q = x0*x0 + x1*x1 + x2*x2;
    #pragma unroll
    for (int off=32; off; off>>=1){ s += __shfl_xor(s,off,64); q += __shfl_xor(q,off,64); }
    float mean = s*(1.f/192.f);
    float var  = q*(1.f/192.f) - mean*mean;
    float inv  = rsqrtf(var + 1e-6f);
    u16* orow = out + pix*192;
    orow[lane]     = f2b((x0-mean)*inv*g[lane]     + bta[lane]);
    orow[lane+64]  = f2b((x1-mean)*inv*g[lane+64]  + bta[lane+64]);
    orow[lane+128] = f2b((x2-mean)*inv*g[lane+128] + bta[lane+128]);
}

// ---------- bf16 MFMA GEMM: C[M,N] = epi(A[M,K] @ W[N,K]^T), A,W bf16 ----------
// tile 128x64, BK=64, 4 waves (2x2), per wave 64x32 = 4x2 fragments of 16x16
#define GM_NONE 0
#define GM_RES 1
#define GM_GELU_BN 2
#define GM_BN_RES 3
#define GM_BIAS_RELU 4

template<int MODE>
__global__ __launch_bounds__(256) void gemm_bf16_k(
    const u16* __restrict__ A, int lda,
    const u16* __restrict__ W,
    void* __restrict__ Cv, int ldc,
    const float* __restrict__ R, int ldr,
    const float* __restrict__ bg, const float* __restrict__ bb,
    const float* __restrict__ bm_, const float* __restrict__ bv,
    int N, int K)
{
    __shared__ u16 As[128*72];   // row stride 72 shorts (144 B): 16B-aligned b128 ops
    __shared__ u16 Ws[64*72];
    int t = threadIdx.x;
    int bm = blockIdx.x * 128;
    int bn = blockIdx.y * 64;
    int wave = t >> 6, lane = t & 63;
    int wm = (wave >> 1)*64, wn = (wave & 1)*32;
    int lr = lane & 15, lk = lane >> 4;
    floatx4 acc[4][2] = {};
    int arow = t >> 1, ahalf = t & 1;
    int brow = t >> 2, bq   = t & 3;

    for (int k0 = 0; k0 < K; k0 += 64){
        __syncthreads();
        {   // stage A tile 128x64 bf16
            const u16* src = A + (size_t)(bm + arow)*lda + k0 + ahalf*32;
            #pragma unroll
            for (int j=0;j<4;j++){
                int kk = k0 + ahalf*32 + 8*j;
                short8v v = {};
                if (kk < K) v = *(const short8v*)(src + 8*j);
                *(short8v*)&As[arow*72 + ahalf*32 + 8*j] = v;
            }
        }
        {   // stage W tile 64x64 bf16
            int n = bn + brow;
            bool nv = n < N;
            const u16* src = W + (size_t)n*K + k0 + bq*16;
            #pragma unroll
            for (int j=0;j<2;j++){
                int kk = k0 + bq*16 + 8*j;
                short8v v = {};
                if (nv && kk < K) v = *(const short8v*)(src + 8*j);
                *(short8v*)&Ws[brow*72 + bq*16 + 8*j] = v;
            }
        }
        __syncthreads();
        #pragma unroll
        for (int s=0; s<2; s++){
            int kb = s*32 + lk*8;
            short8v bfr0 = *(const short8v*)&Ws[(wn + lr)*72 + kb];
            short8v bfr1 = *(const short8v*)&Ws[(wn + 16 + lr)*72 + kb];
            #pragma unroll
            for (int m=0;m<4;m++){
                short8v afr = *(const short8v*)&As[(wm + m*16 + lr)*72 + kb];
                acc[m][0] = __builtin_amdgcn_mfma_f32_16x16x32_bf16(afr, bfr0, acc[m][0], 0,0,0);
                acc[m][1] = __builtin_amdgcn_mfma_f32_16x16x32_bf16(afr, bfr1, acc[m][1], 0,0,0);
            }
        }
    }
    // epilogue: C/D frag layout col=lane&15, row=(lane>>4)*4+reg
    #pragma unroll
    for (int m=0;m<4;m++){
        #pragma unroll
        for (int n2=0;n2<2;n2++){
            int gcol = bn + wn + n2*16 + lr;
            if (gcol >= N) continue;
            #pragma unroll
            for (int rg=0; rg<4; rg++){
                int grow = bm + wm + m*16 + lk*4 + rg;
                float v = acc[m][n2][rg];
                if (MODE == GM_RES){
                    v += R[(size_t)grow*ldr + gcol];
                    ((float*)Cv)[(size_t)grow*ldc + gcol] = v;
                } else if (MODE == GM_BN_RES){
                    float bnv = (v - bm_[gcol])*rsqrtf(bv[gcol]+1e-5f)*bg[gcol] + bb[gcol];
                    ((float*)Cv)[(size_t)grow*ldc + gcol] = bnv + R[(size_t)grow*ldr + gcol];
                } else if (MODE == GM_GELU_BN){
                    float gl = gelu_exact(v);
                    v = (gl - bm_[gcol])*rsqrtf(bv[gcol]+1e-5f)*bg[gcol] + bb[gcol];
                    ((u16*)Cv)[(size_t)grow*ldc + gcol] = f2b(v);
                } else if (MODE == GM_BIAS_RELU){
                    ((u16*)Cv)[(size_t)grow*ldc + gcol] = f2b(fmaxf(v + bg[gcol], 0.f));
                } else {
                    ((u16*)Cv)[(size_t)grow*ldc + gcol] = f2b(v);
                }
            }
        }
    }
}

// ---------- gate stage 2: sigmoid(G1 @ w2 + b2) per pixel, G1 bf16 ----------
__global__ __launch_bounds__(256) void gate2_k(const u16* __restrict__ G1,
    const float* __restrict__ w2, const float* __restrict__ b2, float* __restrict__ gpix)
{
    int pix = blockIdx.x*256 + threadIdx.x;      // over CHW
    const short4v* g4 = (const short4v*)(G1 + (size_t)pix*96);
    const float4* w4 = (const float4*)w2;
    float s = b2[0];
    #pragma unroll
    for (int j=0;j<24;j++){
        short4v g = g4[j]; float4 w = w4[j];
        s += b2f((u16)g.x)*w.x + b2f((u16)g.y)*w.y + b2f((u16)g.z)*w.z + b2f((u16)g.w)*w.w;
    }
    gpix[pix] = 1.f/(1.f+expf(-s));
}

// ---------- deterministic mean of gpix -> dyn_k ----------
__global__ __launch_bounds__(1024) void gate_reduce_k(const float* __restrict__ gpix,
                                                      float* __restrict__ dynk)
{
    __shared__ float sm[16];
    float s = 0.f;
    for (int i=threadIdx.x; i<NPIX; i+=1024) s += gpix[i];
    #pragma unroll
    for (int off=32; off; off>>=1) s += __shfl_xor(s,off,64);
    int wid = threadIdx.x>>6, lane = threadIdx.x&63;
    if (lane==0) sm[wid]=s;
    __syncthreads();
    if (threadIdx.x==0){
        float tot=0.f; for (int i=0;i<16;i++) tot+=sm[i];
        *dynk = floorf(12.0f * (tot/(float)NPIX));
    }
}

// ---------- qkv depthwise 3x3 (288 ch), bf16 in/out, chunk of CB images ----------
__global__ __launch_bounds__(256) void qkv_dw_k(const u16* __restrict__ in,
    const float* __restrict__ w, u16* __restrict__ out)
{
    int idx = blockIdx.x*256 + threadIdx.x;          // over CHW*72
    int c4 = idx % 72; int pix = idx / 72;
    int wx = pix % WW; int hy = (pix / WW) % HH; int img = pix / HW;
    int c0 = c4*4;
    float4 acc; acc.x=0.f; acc.y=0.f; acc.z=0.f; acc.w=0.f;
    for (int ky=0; ky<3; ky++){
        int hh = hy + ky - 1; if (hh < 0 || hh >= HH) continue;
        for (int kx=0; kx<3; kx++){
            int ww2 = wx + kx - 1; if (ww2 < 0 || ww2 >= WW) continue;
            short4v v = *(const short4v*)(in + ((size_t)(img*HH+hh)*WW+ww2)*288 + c0);
            int tap = ky*3+kx;
            acc.x = fmaf(w[(c0+0)*9+tap], b2f((u16)v.x), acc.x);
            acc.y = fmaf(w[(c0+1)*9+tap], b2f((u16)v.y), acc.y);
            acc.z = fmaf(w[(c0+2)*9+tap], b2f((u16)v.z), acc.z);
            acc.w = fmaf(w[(c0+3)*9+tap], b2f((u16)v.w), acc.w);
        }
    }
    short4v o; o.x = (short)f2b(acc.x); o.y = (short)f2b(acc.y);
    o.z = (short)f2b(acc.z); o.w = (short)f2b(acc.w);
    *(short4v*)(out + (size_t)pix*288 + c0) = o;
}

// ---------- Gram partials per (img,head,slice): G[12][12], |q|^2, |k|^2 ----------
__global__ __launch_bounds__(256) void gram_k(const u16* __restrict__ QKVd,
                                              float* __restrict__ part)
{
    int bh = blockIdx.x;        // CB*8: img*8+h
    int slice = blockIdx.y;     // 16 (1024 pixels each)
    int img = bh >> 3, h = bh & 7;
    int qbase = h*12, kbase = 96 + h*12;
    const u16* base = QKVd + (size_t)img*HW*288;
    __shared__ float qs[64][12];
    __shared__ float ks[64][12];
    int t = threadIdx.x;
    float acc = 0.f;
    int c = (t<144) ? t/12 : (t<156 ? t-144 : t-156);
    int d = (t<144) ? t%12 : 0;
    for (int st=0; st<16; st++){
        int pix0 = slice*1024 + st*64;
        __syncthreads();
        for (int i=t; i<64*24; i+=256){
            int p = i/24, cc = i%24;
            float v = b2f(base[(size_t)(pix0 + p)*288 + (cc<12 ? qbase+cc : kbase+cc-12)]);
            if (cc<12) qs[p][cc]=v; else ks[p][cc-12]=v;
        }
        __syncthreads();
        if (t<144){        for (int p=0;p<64;p++) acc = fmaf(qs[p][c], ks[p][d], acc); }
        else if (t<156){   for (int p=0;p<64;p++) acc = fmaf(qs[p][c], qs[p][c], acc); }
        else if (t<168){   for (int p=0;p<64;p++) acc = fmaf(ks[p][c], ks[p][c], acc); }
    }
    if (t<168) part[((size_t)bh*16 + slice)*168 + t] = acc;
}

__global__ __launch_bounds__(256) void gram_combine_k(const float* __restrict__ part,
                                                      float* __restrict__ gram)
{
    int i = blockIdx.x*256 + threadIdx.x;
    if (i >= CB*8*168) return;
    int bh = i/168, t = i%168;
    float s = 0.f;
    for (int sl=0; sl<16; sl++) s += part[((size_t)bh*16+sl)*168 + t];
    gram[i] = s;
}

// ---------- attn 12x12: normalize, temperature, top-k mask, softmax ----------
__global__ __launch_bounds__(256) void attn_k(const float* __restrict__ gram,
    const float* __restrict__ temp, const float* __restrict__ dynk_p,
    const float* __restrict__ a1, const float* __restrict__ a2,
    const float* __restrict__ a3, const float* __restrict__ a4,
    float* __restrict__ attnW)
{
    int bh = blockIdx.x;   // CB*8: img*8+h
    int h = bh & 7;
    __shared__ float av[12][12];
    __shared__ float mv[12][12];
    __shared__ float nq[12], nk[12];
    int t = threadIdx.x;
    if (t < 12) nq[t] = fmaxf(sqrtf(gram[bh*168+144+t]), 1e-12f);
    else if (t < 24) nk[t-12] = fmaxf(sqrtf(gram[bh*168+156+(t-12)]), 1e-12f);
    __syncthreads();
    if (t < 144){
        int c=t/12, d=t%12;
        av[c][d] = gram[bh*168+t] / (nq[c]*nk[d]) * temp[h];
    }
    __syncthreads();
    float dk = *dynk_p;
    if (t < 144){
        int c=t/12, d=t%12; float v = av[c][d];
        int r = 0;
        #pragma unroll
        for (int j=0;j<12;j++){
            float o = av[c][j];
            r += (o > v) ? 1 : ((o == v && j < d) ? 1 : 0);
        }
        mv[c][d] = ((float)r < dk) ? v : -INFINITY;
    }
    __syncthreads();
    if (t < 12){
        float mx = -INFINITY;
        for (int d2=0; d2<12; d2++) mx = fmaxf(mx, mv[t][d2]);
        float e[12]; float s = 0.f;
        for (int d2=0; d2<12; d2++){ e[d2] = expf(mv[t][d2]-mx); s += e[d2]; }
        float sc = (a1[0]+a2[0]+a3[0]+a4[0]) / s;
        for (int d2=0; d2<12; d2++) attnW[(size_t)bh*144 + t*12 + d2] = e[d2]*sc;
    }
}

// ---------- attn apply + concat x2 -> P bf16, chunk ----------
__global__ __launch_bounds__(256) void attn_apply_k(const u16* __restrict__ QKVd,
    const u16* __restrict__ Y, const float* __restrict__ attnW, u16* __restrict__ P)
{
    int idx = blockIdx.x*256 + threadIdx.x;          // CHW*192
    int c = idx % 192; size_t pix = (size_t)(idx / 192);
    int img = (int)(pix >> 14);
    u16 outv;
    if (c < 96){
        int h = c/12, cc = c%12;
        const u16* vr = QKVd + pix*288 + 192 + h*12;
        const float* aw = attnW + ((size_t)(img*8+h))*144 + cc*12;
        float s = 0.f;
        #pragma unroll
        for (int d=0; d<12; d++) s += aw[d]*b2f(vr[d]);
        outv = f2b(s);
    } else {
        outv = Y[pix*192 + c];
    }
    P[idx] = outv;
}

// ---------- FFN multi-scale depthwise + residual + gelu + bn2 + mul v0, bf16 ----------
__global__ __launch_bounds__(256) void ffn_dw_k(const u16* __restrict__ V0,
    const float* __restrict__ w0, const float* __restrict__ bb0,
    const float* __restrict__ w1, const float* __restrict__ bb1,
    const float* __restrict__ w2, const float* __restrict__ bb2,
    const float* __restrict__ w3, const float* __restrict__ bb3,
    const float* __restrict__ bn2g, const float* __restrict__ bn2b,
    const float* __restrict__ bn2m, const float* __restrict__ bn2v,
    u16* __restrict__ U)
{
    int ch = threadIdx.x;            // 0..255
    size_t pix = blockIdx.x;         // CHW
    int wx = (int)(pix % WW);
    int hy = (int)((pix / WW) % HH);
    int img = (int)(pix / HW);
    int g = ch >> 6; int cc = ch & 63;
    const float* wt; const float* bp;
    switch(g){
        case 0: wt=w0; bp=bb0; break;
        case 1: wt=w1; bp=bb1; break;
        case 2: wt=w2; bp=bb2; break;
        default: wt=w3; bp=bb3; break;
    }
    int ks = 2*g+1, pad = g;
    wt += cc*ks*ks;
    float acc = bp[cc];
    for (int ky=0; ky<ks; ky++){
        int hh = hy+ky-pad; if (hh<0||hh>=HH) continue;
        for (int kx=0; kx<ks; kx++){
            int ww2 = wx+kx-pad; if (ww2<0||ww2>=WW) continue;
            acc = fmaf(wt[ky*ks+kx], b2f(V0[((size_t)(img*HH+hh)*WW+ww2)*256 + ch]), acc);
        }
    }
    float v0 = b2f(V0[pix*256+ch]);
    float u1 = acc + v0;
    float gl = gelu_exact(u1);
    float bn = (gl - bn2m[ch])*rsqrtf(bn2v[ch]+1e-5f)*bn2g[ch] + bn2b[ch];
    U[pix*256+ch] = f2b(bn*v0);
}

extern "C" void kernel_launch(void* const* d_in, const int* in_sizes, int n_in,
                              void* d_out, int out_size, void* d_ws, size_t ws_size,
                              hipStream_t stream)
{
    const float* x     = (const float*)d_in[0];
    const float* pos_w = (const float*)d_in[1];
    const float* pos_b = (const float*)d_in[2];
    const float* ln1g  = (const float*)d_in[3];
    const float* ln1b  = (const float*)d_in[4];
    const float* temp  = (const float*)d_in[5];
    const float* qkvw  = (const float*)d_in[6];
    const float* qkvdw = (const float*)d_in[7];
    const float* projw = (const float*)d_in[8];
    const float* gw1   = (const float*)d_in[9];
    const float* gb1   = (const float*)d_in[10];
    const float* gw2   = (const float*)d_in[11];
    const float* gb2   = (const float*)d_in[12];
    const float* a1    = (const float*)d_in[13];
    const float* a2    = (const float*)d_in[14];
    const float* a3    = (const float*)d_in[15];
    const float* a4    = (const float*)d_in[16];
    const float* ln2g  = (const float*)d_in[17];
    const float* ln2b  = (const float*)d_in[18];
    const float* fc1w  = (const float*)d_in[19];
    const float* bn1g  = (const float*)d_in[20];
    const float* bn1b  = (const float*)d_in[21];
    const float* bn1m  = (const float*)d_in[22];
    const float* bn1v  = (const float*)d_in[23];
    const float* bn2g  = (const float*)d_in[24];
    const float* bn2b  = (const float*)d_in[25];
    const float* bn2m  = (const float*)d_in[26];
    const float* bn2v  = (const float*)d_in[27];
    const float* fc2w  = (const float*)d_in[28];
    const float* bn3g  = (const float*)d_in[29];
    const float* bn3b  = (const float*)d_in[30];
    const float* bn3m  = (const float*)d_in[31];
    const float* bn3v  = (const float*)d_in[32];
    const float* dw0w  = (const float*)d_in[33];
    const float* dw0b  = (const float*)d_in[34];
    const float* dw1w  = (const float*)d_in[35];
    const float* dw1b  = (const float*)d_in[36];
    const float* dw2w  = (const float*)d_in[37];
    const float* dw2b  = (const float*)d_in[38];
    const float* dw3w  = (const float*)d_in[39];
    const float* dw3b  = (const float*)d_in[40];

    float* OUT = (float*)d_out;      // residual stream (fp32)

    // ---- workspace layout (bytes), peak ~64.3 MB ----
    char* p = (char*)d_ws;
    float* gpix  = (float*)p;                 p += (size_t)NPIX*4;      // 524288
    float* dynk  = (float*)p;                 p += 256;
    float* gpart = (float*)p;                 p += 262144;              // CB*8*16*168*4 = 172032
    float* gram  = (float*)p;                 p += 16384;               // CB*8*168*4
    float* attnW = (float*)p;                 p += 16384;               // CB*8*144*4
    u16*   wbf   = (u16*)p;                   p += 524288;              // 181248*2
    u16*   Ybf   = (u16*)p;                   p += (size_t)CHW*192*2;   // 12.58 MB
    u16*   QKVbf = (u16*)p;                   p += (size_t)CHW*288*2;   // 18.87 MB
    u16*   QKVdbf= (u16*)p;                   p += (size_t)CHW*288*2;   // 18.87 MB
    u16*   Pbf   = (u16*)p;                   p += (size_t)CHW*192*2;   // 12.58 MB
    u16* qkvwb = wbf;
    u16* projwb= wbf + WQ;
    u16* gw1b  = wbf + WQ + WP;
    u16* fc1b  = wbf + WQ + WP + WG;
    u16* fc2b  = wbf + WQ + WP + WG + WF1;
    u16* G1bf  = QKVbf;    // gate phase reuse
    u16* Zbf   = Pbf;      // after proj, P dead
    u16* V0bf  = QKVdbf;   // after attn_apply, QKVd dead
    u16* Ubf   = QKVbf;    // after qkv_dw, QKV dead

    // 0. weight prep
    wprep_k<<<(WTOT+255)/256, 256, 0, stream>>>(qkvw, projw, gw1, fc1w, fc2w, wbf);
    // 1. pos depthwise conv + bias + residual -> OUT
    pos_conv_k<<<BB*HH*4*48/256, 256, 0, stream>>>(x, pos_w, pos_b, OUT);

    // 2. gate phase (all chunks) -> gpix, then dyn_k
    for (int c=0; c<NCHUNK; c++){
        const float* Ab = OUT + (size_t)c*CHW*192;
        ln_k<<<CHW/4, 256, 0, stream>>>(Ab, ln1g, ln1b, Ybf);
        dim3 g(CHW/128, 2);
        gemm_bf16_k<GM_BIAS_RELU><<<g, 256, 0, stream>>>(Ybf, 192, gw1b, G1bf, 96,
            nullptr, 0, gb1, nullptr, nullptr, nullptr, 96, 192);
        gate2_k<<<CHW/256, 256, 0, stream>>>(G1bf, gw2, gb2, gpix + (size_t)c*CHW);
    }
    gate_reduce_k<<<1, 1024, 0, stream>>>(gpix, dynk);

    // 3. main pipeline per chunk
    for (int c=0; c<NCHUNK; c++){
        float* Ab = OUT + (size_t)c*CHW*192;
        ln_k<<<CHW/4, 256, 0, stream>>>(Ab, ln1g, ln1b, Ybf);
        {   // qkv 1x1 (M=CHW, K=96, N=288)
            dim3 g(CHW/128, 5);
            gemm_bf16_k<GM_NONE><<<g, 256, 0, stream>>>(Ybf, 192, qkvwb, QKVbf, 288,
                nullptr, 0, nullptr,nullptr,nullptr,nullptr, 288, 96);
        }
        qkv_dw_k<<<CHW*72/256, 256, 0, stream>>>(QKVbf, qkvdw, QKVdbf);
        { dim3 g(CB*8, 16); gram_k<<<g, 256, 0, stream>>>(QKVdbf, gpart); }
        gram_combine_k<<<(CB*8*168+255)/256, 256, 0, stream>>>(gpart, gram);
        attn_k<<<CB*8, 256, 0, stream>>>(gram, temp, dynk, a1,a2,a3,a4, attnW);
        attn_apply_k<<<CHW*192/256, 256, 0, stream>>>(QKVdbf, Ybf, attnW, Pbf);
        {   // proj + residual (fp32 in-place)
            dim3 g(CHW/128, 3);
            gemm_bf16_k<GM_RES><<<g, 256, 0, stream>>>(Pbf, 192, projwb, Ab, 192,
                Ab, 192, nullptr,nullptr,nullptr,nullptr, 192, 192);
        }
        ln_k<<<CHW/4, 256, 0, stream>>>(Ab, ln2g, ln2b, Zbf);
        {   // fc1 + gelu + bn1 -> V0 bf16
            dim3 g(CHW/128, 4);
            gemm_bf16_k<GM_GELU_BN><<<g, 256, 0, stream>>>(Zbf, 192, fc1b, V0bf, 256,
                nullptr, 0, bn1g,bn1b,bn1m,bn1v, 256, 192);
        }
        ffn_dw_k<<<CHW, 256, 0, stream>>>(V0bf, dw0w,dw0b,dw1w,dw1b,dw2w,dw2b,dw3w,dw3b,
                                          bn2g,bn2b,bn2m,bn2v, Ubf);
        {   // fc2 + bn3 + residual -> OUT fp32
            dim3 g(CHW/128, 3);
            gemm_bf16_k<GM_BN_RES><<<g, 256, 0, stream>>>(Ubf, 256, fc2b, Ab, 192,
                Ab, 192, bn3g,bn3b,bn3m,bn3v, 192, 256);
        }
    }
}

// Round 5
// 1230.597 us; speedup vs baseline: 2.6574x; 1.5882x over previous
//
#include <hip/hip_runtime.h>
#include <hip/hip_bf16.h>
#include <math.h>

#define BB 8
#define HH 128
#define WW 128
#define HW (HH*WW)          // 16384
#define NPIX (BB*HW)        // 131072
#define CB 2                // images per chunk
#define CHW (CB*HW)         // 32768
#define NCHUNK (BB/CB)

typedef unsigned short u16;
typedef __attribute__((ext_vector_type(4))) float  floatx4;
typedef __attribute__((ext_vector_type(4))) short  short4v;
typedef __attribute__((ext_vector_type(8))) short  short8v;

static __device__ __forceinline__ float gelu_exact(float x){
    return 0.5f*x*(1.0f+erff(x*0.70710678118654752440f));
}
static __device__ __forceinline__ float b2f(u16 v){
    union { unsigned u; float f; } x; x.u = ((unsigned)v)<<16; return x.f;
}
static __device__ __forceinline__ u16 f2b(float f){
    __hip_bfloat16 h = __float2bfloat16(f);
    return *(u16*)&h;
}

// ---------- weight prep: fp32 -> bf16 for the five GEMM weight matrices ----------
#define WQ 27648
#define WP 36864
#define WG 18432
#define WF1 49152
#define WF2 49152
#define WTOT (WQ+WP+WG+WF1+WF2)   // 181248
__global__ __launch_bounds__(256) void wprep_k(const float* __restrict__ a,
    const float* __restrict__ b, const float* __restrict__ c,
    const float* __restrict__ d, const float* __restrict__ e, u16* __restrict__ o)
{
    int i = blockIdx.x*256 + threadIdx.x;
    if (i >= WTOT) return;
    float v;
    if (i < WQ) v = a[i];
    else if (i < WQ+WP) v = b[i-WQ];
    else if (i < WQ+WP+WG) v = c[i-WQ-WP];
    else if (i < WQ+WP+WG+WF1) v = d[i-WQ-WP-WG];
    else v = e[i-WQ-WP-WG-WF1];
    o[i] = f2b(v);
}

// ---------- pos depthwise 3x3 + bias + residual, 32-col segments ----------
__global__ __launch_bounds__(256) void pos_conv_k(const float* __restrict__ x,
    const float* __restrict__ w, const float* __restrict__ bias, float* __restrict__ out)
{
    int gid = blockIdx.x*256 + threadIdx.x;     // ((b*HH+hy)*4 + seg)*48 + c4
    int c4 = gid % 48; int rest = gid / 48;
    int seg = rest & 3; rest >>= 2;
    int hy = rest % HH; int b = rest / HH;
    int c0 = c4*4;
    float wr[3][3][4];
    #pragma unroll
    for (int j=0;j<4;j++)
        #pragma unroll
        for (int ky=0;ky<3;ky++)
            #pragma unroll
            for (int kx=0;kx<3;kx++)
                wr[ky][kx][j] = w[(c0+j)*9 + ky*3 + kx];
    float4 bias4 = *(const float4*)(bias + c0);
    const float4* x4 = (const float4*)x;
    const float4* r0 = x4 + ((size_t)(b*HH + hy-1)*WW)*48 + c4;
    const float4* r1 = x4 + ((size_t)(b*HH + hy  )*WW)*48 + c4;
    const float4* r2 = x4 + ((size_t)(b*HH + hy+1)*WW)*48 + c4;
    bool v0 = hy > 0, v2 = hy < HH-1;
    float4 z4 = make_float4(0.f,0.f,0.f,0.f);
    int s0 = seg*32;
    float4 cA[3], cB[3], cC[3], cN[3];
    bool la = s0 > 0;
    cA[0] = (v0&&la) ? r0[(size_t)(s0-1)*48] : z4;
    cA[1] = la ? r1[(size_t)(s0-1)*48] : z4;
    cA[2] = (v2&&la) ? r2[(size_t)(s0-1)*48] : z4;
    cB[0] = v0 ? r0[(size_t)s0*48] : z4;  cB[1] = r1[(size_t)s0*48];  cB[2] = v2 ? r2[(size_t)s0*48] : z4;
    cC[0] = v0 ? r0[(size_t)(s0+1)*48] : z4; cC[1] = r1[(size_t)(s0+1)*48]; cC[2] = v2 ? r2[(size_t)(s0+1)*48] : z4;
    float4* o4 = (float4*)out + ((size_t)(b*HH + hy)*WW)*48 + c4;
    for (int i2=0; i2<32; i2++){
        int wx = s0 + i2;
        bool okc = (wx+2) < WW;
        size_t noff = (size_t)(wx+2)*48;
        cN[0] = (v0 && okc) ? r0[noff] : z4;
        cN[1] = okc ? r1[noff] : z4;
        cN[2] = (v2 && okc) ? r2[noff] : z4;
        float4 acc = bias4;
        #pragma unroll
        for (int i=0;i<3;i++){
            acc.x = fmaf(wr[i][0][0], cA[i].x, acc.x);
            acc.y = fmaf(wr[i][0][1], cA[i].y, acc.y);
            acc.z = fmaf(wr[i][0][2], cA[i].z, acc.z);
            acc.w = fmaf(wr[i][0][3], cA[i].w, acc.w);
            acc.x = fmaf(wr[i][1][0], cB[i].x, acc.x);
            acc.y = fmaf(wr[i][1][1], cB[i].y, acc.y);
            acc.z = fmaf(wr[i][1][2], cB[i].z, acc.z);
            acc.w = fmaf(wr[i][1][3], cB[i].w, acc.w);
            acc.x = fmaf(wr[i][2][0], cC[i].x, acc.x);
            acc.y = fmaf(wr[i][2][1], cC[i].y, acc.y);
            acc.z = fmaf(wr[i][2][2], cC[i].z, acc.z);
            acc.w = fmaf(wr[i][2][3], cC[i].w, acc.w);
        }
        acc.x += cB[1].x; acc.y += cB[1].y; acc.z += cB[1].z; acc.w += cB[1].w;
        o4[(size_t)wx*48] = acc;
        #pragma unroll
        for (int i=0;i<3;i++){ cA[i]=cB[i]; cB[i]=cC[i]; cC[i]=cN[i]; }
    }
}

// ---------- LayerNorm over C=192 fp32 in -> bf16 out, wave per pixel ----------
__global__ __launch_bounds__(256) void ln_k(const float* __restrict__ in,
    const float* __restrict__ g, const float* __restrict__ bta, u16* __restrict__ out)
{
    int wid = threadIdx.x >> 6, lane = threadIdx.x & 63;
    size_t pix = (size_t)blockIdx.x*4 + wid;
    const float* row = in + pix*192;
    float x0 = row[lane], x1 = row[lane+64], x2 = row[lane+128];
    float s = x0+x1+x2;
    float q = x0*x0 + x1*x1 + x2*x2;
    #pragma unroll
    for (int off=32; off; off>>=1){ s += __shfl_xor(s,off,64); q += __shfl_xor(q,off,64); }
    float mean = s*(1.f/192.f);
    float var  = q*(1.f/192.f) - mean*mean;
    float inv  = rsqrtf(var + 1e-6f);
    u16* orow = out + pix*192;
    orow[lane]     = f2b((x0-mean)*inv*g[lane]     + bta[lane]);
    orow[lane+64]  = f2b((x1-mean)*inv*g[lane+64]  + bta[lane+64]);
    orow[lane+128] = f2b((x2-mean)*inv*g[lane+128] + bta[lane+128]);
}

// ---------- bf16 MFMA GEMM: C[M,N] = epi(A[M,K] @ W[N,K]^T), A,W bf16 ----------
#define GM_NONE 0
#define GM_RES 1
#define GM_GELU_BN 2
#define GM_BN_RES 3
#define GM_BIAS_RELU 4

template<int MODE>
__global__ __launch_bounds__(256) void gemm_bf16_k(
    const u16* __restrict__ A, int lda,
    const u16* __restrict__ W,
    void* __restrict__ Cv, int ldc,
    const float* __restrict__ R, int ldr,
    const float* __restrict__ bg, const float* __restrict__ bb,
    const float* __restrict__ bm_, const float* __restrict__ bv,
    int N, int K)
{
    __shared__ u16 As[128*72];   // row stride 72 shorts (144 B): 16B-aligned b128 ops
    __shared__ u16 Ws[64*72];
    int t = threadIdx.x;
    int bm = blockIdx.x * 128;
    int bn = blockIdx.y * 64;
    int wave = t >> 6, lane = t & 63;
    int wm = (wave >> 1)*64, wn = (wave & 1)*32;
    int lr = lane & 15, lk = lane >> 4;
    floatx4 acc[4][2] = {};
    int arow = t >> 1, ahalf = t & 1;
    int brow = t >> 2, bq   = t & 3;

    for (int k0 = 0; k0 < K; k0 += 64){
        __syncthreads();
        {
            const u16* src = A + (size_t)(bm + arow)*lda + k0 + ahalf*32;
            #pragma unroll
            for (int j=0;j<4;j++){
                int kk = k0 + ahalf*32 + 8*j;
                short8v v = {};
                if (kk < K) v = *(const short8v*)(src + 8*j);
                *(short8v*)&As[arow*72 + ahalf*32 + 8*j] = v;
            }
        }
        {
            int n = bn + brow;
            bool nv = n < N;
            const u16* src = W + (size_t)n*K + k0 + bq*16;
            #pragma unroll
            for (int j=0;j<2;j++){
                int kk = k0 + bq*16 + 8*j;
                short8v v = {};
                if (nv && kk < K) v = *(const short8v*)(src + 8*j);
                *(short8v*)&Ws[brow*72 + bq*16 + 8*j] = v;
            }
        }
        __syncthreads();
        #pragma unroll
        for (int s=0; s<2; s++){
            int kb = s*32 + lk*8;
            short8v bfr0 = *(const short8v*)&Ws[(wn + lr)*72 + kb];
            short8v bfr1 = *(const short8v*)&Ws[(wn + 16 + lr)*72 + kb];
            #pragma unroll
            for (int m=0;m<4;m++){
                short8v afr = *(const short8v*)&As[(wm + m*16 + lr)*72 + kb];
                acc[m][0] = __builtin_amdgcn_mfma_f32_16x16x32_bf16(afr, bfr0, acc[m][0], 0,0,0);
                acc[m][1] = __builtin_amdgcn_mfma_f32_16x16x32_bf16(afr, bfr1, acc[m][1], 0,0,0);
            }
        }
    }
    #pragma unroll
    for (int m=0;m<4;m++){
        #pragma unroll
        for (int n2=0;n2<2;n2++){
            int gcol = bn + wn + n2*16 + lr;
            if (gcol >= N) continue;
            #pragma unroll
            for (int rg=0; rg<4; rg++){
                int grow = bm + wm + m*16 + lk*4 + rg;
                float v = acc[m][n2][rg];
                if (MODE == GM_RES){
                    v += R[(size_t)grow*ldr + gcol];
                    ((float*)Cv)[(size_t)grow*ldc + gcol] = v;
                } else if (MODE == GM_BN_RES){
                    float bnv = (v - bm_[gcol])*rsqrtf(bv[gcol]+1e-5f)*bg[gcol] + bb[gcol];
                    ((float*)Cv)[(size_t)grow*ldc + gcol] = bnv + R[(size_t)grow*ldr + gcol];
                } else if (MODE == GM_GELU_BN){
                    float gl = gelu_exact(v);
                    v = (gl - bm_[gcol])*rsqrtf(bv[gcol]+1e-5f)*bg[gcol] + bb[gcol];
                    ((u16*)Cv)[(size_t)grow*ldc + gcol] = f2b(v);
                } else if (MODE == GM_BIAS_RELU){
                    ((u16*)Cv)[(size_t)grow*ldc + gcol] = f2b(fmaxf(v + bg[gcol], 0.f));
                } else {
                    ((u16*)Cv)[(size_t)grow*ldc + gcol] = f2b(v);
                }
            }
        }
    }
}

// ---------- gate stage 2: sigmoid(G1 @ w2 + b2) per pixel, G1 bf16 ----------
__global__ __launch_bounds__(256) void gate2_k(const u16* __restrict__ G1,
    const float* __restrict__ w2, const float* __restrict__ b2, float* __restrict__ gpix)
{
    int pix = blockIdx.x*256 + threadIdx.x;      // over CHW
    const short4v* g4 = (const short4v*)(G1 + (size_t)pix*96);
    const float4* w4 = (const float4*)w2;
    float s = b2[0];
    #pragma unroll
    for (int j=0;j<24;j++){
        short4v g = g4[j]; float4 w = w4[j];
        s += b2f((u16)g.x)*w.x + b2f((u16)g.y)*w.y + b2f((u16)g.z)*w.z + b2f((u16)g.w)*w.w;
    }
    gpix[pix] = 1.f/(1.f+expf(-s));
}

// ---------- deterministic mean of gpix -> dyn_k ----------
__global__ __launch_bounds__(1024) void gate_reduce_k(const float* __restrict__ gpix,
                                                      float* __restrict__ dynk)
{
    __shared__ float sm[16];
    float s = 0.f;
    for (int i=threadIdx.x; i<NPIX; i+=1024) s += gpix[i];
    #pragma unroll
    for (int off=32; off; off>>=1) s += __shfl_xor(s,off,64);
    int wid = threadIdx.x>>6, lane = threadIdx.x&63;
    if (lane==0) sm[wid]=s;
    __syncthreads();
    if (threadIdx.x==0){
        float tot=0.f; for (int i=0;i<16;i++) tot+=sm[i];
        *dynk = floorf(12.0f * (tot/(float)NPIX));
    }
}

// ---------- qkv depthwise 3x3 (288 ch), bf16, 8-ch vectorized + LDS weights ----------
// LDS: w transposed [tap][288 ch] with +4-float pad per 32 ch to spread banks
#define QPOS(c8) ((c8)*8 + ((c8)>>2)*4)
#define QTAPSTRIDE 324
__global__ __launch_bounds__(256) void qkv_dw_k(const u16* __restrict__ in,
    const float* __restrict__ w, u16* __restrict__ out)
{
    __shared__ float wlds[9*QTAPSTRIDE];
    int t = threadIdx.x;
    for (int i=t; i<2592; i+=256){
        int tap = i/288, cc = i%288;
        wlds[tap*QTAPSTRIDE + QPOS(cc>>3) + (cc&7)] = w[cc*9+tap];
    }
    __syncthreads();
    int idx = blockIdx.x*256 + t;          // over CHW*36
    int c8 = idx % 36; int pix = idx / 36;
    int wx = pix % WW; int hy = (pix / WW) % HH; int img = pix / HW;
    int c0 = c8*8;
    int wofs = QPOS(c8);
    float acc[8] = {};
    #pragma unroll
    for (int ky=0; ky<3; ky++){
        int hh = hy + ky - 1; if ((unsigned)hh >= HH) continue;
        #pragma unroll
        for (int kx=0; kx<3; kx++){
            int ww2 = wx + kx - 1; if ((unsigned)ww2 >= WW) continue;
            int tap = ky*3+kx;
            short8v v = *(const short8v*)(in + ((size_t)(img*HH+hh)*WW+ww2)*288 + c0);
            floatx4 wa = *(const floatx4*)&wlds[tap*QTAPSTRIDE + wofs];
            floatx4 wb = *(const floatx4*)&wlds[tap*QTAPSTRIDE + wofs + 4];
            #pragma unroll
            for (int j=0;j<4;j++) acc[j]   = fmaf(wa[j], b2f((u16)v[j]),   acc[j]);
            #pragma unroll
            for (int j=0;j<4;j++) acc[4+j] = fmaf(wb[j], b2f((u16)v[4+j]), acc[4+j]);
        }
    }
    short8v o;
    #pragma unroll
    for (int j=0;j<8;j++) o[j] = (short)f2b(acc[j]);
    *(short8v*)(out + (size_t)pix*288 + c0) = o;
}

// ---------- Gram partials per (img,head,slice): G[12][12], |q|^2, |k|^2 ----------
__global__ __launch_bounds__(256) void gram_k(const u16* __restrict__ QKVd,
                                              float* __restrict__ part)
{
    int bh = blockIdx.x;        // CB*8: img*8+h
    int slice = blockIdx.y;     // 16 (1024 pixels each)
    int img = bh >> 3, h = bh & 7;
    int qbase = h*12, kbase = 96 + h*12;
    const u16* base = QKVd + (size_t)img*HW*288;
    __shared__ float qs[64][12];
    __shared__ float ks[64][12];
    int t = threadIdx.x;
    float acc = 0.f;
    int c = (t<144) ? t/12 : (t<156 ? t-144 : t-156);
    int d = (t<144) ? t%12 : 0;
    for (int st=0; st<16; st++){
        int pix0 = slice*1024 + st*64;
        __syncthreads();
        for (int i=t; i<64*24; i+=256){
            int p = i/24, cc = i%24;
            float v = b2f(base[(size_t)(pix0 + p)*288 + (cc<12 ? qbase+cc : kbase+cc-12)]);
            if (cc<12) qs[p][cc]=v; else ks[p][cc-12]=v;
        }
        __syncthreads();
        if (t<144){        for (int p=0;p<64;p++) acc = fmaf(qs[p][c], ks[p][d], acc); }
        else if (t<156){   for (int p=0;p<64;p++) acc = fmaf(qs[p][c], qs[p][c], acc); }
        else if (t<168){   for (int p=0;p<64;p++) acc = fmaf(ks[p][c], ks[p][c], acc); }
    }
    if (t<168) part[((size_t)bh*16 + slice)*168 + t] = acc;
}

__global__ __launch_bounds__(256) void gram_combine_k(const float* __restrict__ part,
                                                      float* __restrict__ gram)
{
    int i = blockIdx.x*256 + threadIdx.x;
    if (i >= CB*8*168) return;
    int bh = i/168, t = i%168;
    float s = 0.f;
    for (int sl=0; sl<16; sl++) s += part[((size_t)bh*16+sl)*168 + t];
    gram[i] = s;
}

// ---------- attn 12x12: normalize, temperature, top-k mask, softmax ----------
__global__ __launch_bounds__(256) void attn_k(const float* __restrict__ gram,
    const float* __restrict__ temp, const float* __restrict__ dynk_p,
    const float* __restrict__ a1, const float* __restrict__ a2,
    const float* __restrict__ a3, const float* __restrict__ a4,
    float* __restrict__ attnW)
{
    int bh = blockIdx.x;   // CB*8: img*8+h
    int h = bh & 7;
    __shared__ float av[12][12];
    __shared__ float mv[12][12];
    __shared__ float nq[12], nk[12];
    int t = threadIdx.x;
    if (t < 12) nq[t] = fmaxf(sqrtf(gram[bh*168+144+t]), 1e-12f);
    else if (t < 24) nk[t-12] = fmaxf(sqrtf(gram[bh*168+156+(t-12)]), 1e-12f);
    __syncthreads();
    if (t < 144){
        int c=t/12, d=t%12;
        av[c][d] = gram[bh*168+t] / (nq[c]*nk[d]) * temp[h];
    }
    __syncthreads();
    float dk = *dynk_p;
    if (t < 144){
        int c=t/12, d=t%12; float v = av[c][d];
        int r = 0;
        #pragma unroll
        for (int j=0;j<12;j++){
            float o = av[c][j];
            r += (o > v) ? 1 : ((o == v && j < d) ? 1 : 0);
        }
        mv[c][d] = ((float)r < dk) ? v : -INFINITY;
    }
    __syncthreads();
    if (t < 12){
        float mx = -INFINITY;
        for (int d2=0; d2<12; d2++) mx = fmaxf(mx, mv[t][d2]);
        float e[12]; float s = 0.f;
        for (int d2=0; d2<12; d2++){ e[d2] = expf(mv[t][d2]-mx); s += e[d2]; }
        float sc = (a1[0]+a2[0]+a3[0]+a4[0]) / s;
        for (int d2=0; d2<12; d2++) attnW[(size_t)bh*144 + t*12 + d2] = e[d2]*sc;
    }
}

// ---------- attn apply + concat x2 -> P bf16, chunk ----------
__global__ __launch_bounds__(256) void attn_apply_k(const u16* __restrict__ QKVd,
    const u16* __restrict__ Y, const float* __restrict__ attnW, u16* __restrict__ P)
{
    int idx = blockIdx.x*256 + threadIdx.x;          // CHW*192
    int c = idx % 192; size_t pix = (size_t)(idx / 192);
    int img = (int)(pix >> 14);
    u16 outv;
    if (c < 96){
        int h = c/12, cc = c%12;
        const u16* vr = QKVd + pix*288 + 192 + h*12;
        const float* aw = attnW + ((size_t)(img*8+h))*144 + cc*12;
        float s = 0.f;
        #pragma unroll
        for (int d=0; d<12; d++) s += aw[d]*b2f(vr[d]);
        outv = f2b(s);
    } else {
        outv = Y[pix*192 + c];
    }
    P[idx] = outv;
}

// ---------- FFN multi-scale depthwise: 8 px/block, wave = scale group, 8 ch/lane ----------
// LDS weights transposed [tap][64 ch] per group; lane reads are 2-way aliased (free)
__global__ __launch_bounds__(256) void ffn_dw_k(const u16* __restrict__ V0,
    const float* __restrict__ w0, const float* __restrict__ bb0,
    const float* __restrict__ w1, const float* __restrict__ bb1,
    const float* __restrict__ w2, const float* __restrict__ bb2,
    const float* __restrict__ w3, const float* __restrict__ bb3,
    const float* __restrict__ bn2g, const float* __restrict__ bn2b,
    const float* __restrict__ bn2m, const float* __restrict__ bn2v,
    u16* __restrict__ U)
{
    __shared__ float wlds[5376];  // g0:[0,64) g1:[64,640) g2:[640,2240) g3:[2240,5376)
    int t = threadIdx.x;
    for (int i=t; i<64;   i+=256)  wlds[i] = w0[i];
    for (int i=t; i<576;  i+=256){ int tap=i>>6, cc=i&63; wlds[64+i]   = w1[cc*9+tap]; }
    for (int i=t; i<1600; i+=256){ int tap=i>>6, cc=i&63; wlds[640+i]  = w2[cc*25+tap]; }
    for (int i=t; i<3136; i+=256){ int tap=i>>6, cc=i&63; wlds[2240+i] = w3[cc*49+tap]; }
    __syncthreads();
    int g = t >> 6, lane = t & 63;
    int p8 = lane >> 3, ci = lane & 7;
    size_t pix = (size_t)blockIdx.x*8 + p8;
    int wx = (int)(pix % WW);
    int hy = (int)((pix / WW) % HH);
    int img = (int)(pix / HW);
    int c0 = g*64 + ci*8;
    int ks = 2*g+1, pad = g;
    const int gb[4] = {0,64,640,2240};
    const float* wg = &wlds[gb[g]];
    float acc[8];
    {
        const float* bp = (g==0)?bb0:(g==1)?bb1:(g==2)?bb2:bb3;
        floatx4 b0 = *(const floatx4*)(bp + ci*8);
        floatx4 b1 = *(const floatx4*)(bp + ci*8 + 4);
        #pragma unroll
        for (int j=0;j<4;j++){ acc[j]=b0[j]; acc[4+j]=b1[j]; }
    }
    for (int ky=0; ky<ks; ky++){
        int hh = hy+ky-pad; if ((unsigned)hh >= HH) continue;
        const u16* rowp = V0 + ((size_t)(img*HH+hh)*WW)*256 + c0;
        for (int kx=0; kx<ks; kx++){
            int ww2 = wx+kx-pad; if ((unsigned)ww2 >= WW) continue;
            int tap = ky*ks+kx;
            short8v v = *(const short8v*)(rowp + (size_t)ww2*256);
            floatx4 wa = *(const floatx4*)&wg[tap*64 + ci*8];
            floatx4 wb = *(const floatx4*)&wg[tap*64 + ci*8 + 4];
            #pragma unroll
            for (int j=0;j<4;j++) acc[j]   = fmaf(wa[j], b2f((u16)v[j]),   acc[j]);
            #pragma unroll
            for (int j=0;j<4;j++) acc[4+j] = fmaf(wb[j], b2f((u16)v[4+j]), acc[4+j]);
        }
    }
    short8v vc = *(const short8v*)(V0 + pix*256 + c0);
    floatx4 g0v = *(const floatx4*)(bn2g + c0), g1v = *(const floatx4*)(bn2g + c0 + 4);
    floatx4 b0v = *(const floatx4*)(bn2b + c0), b1v = *(const floatx4*)(bn2b + c0 + 4);
    floatx4 m0v = *(const floatx4*)(bn2m + c0), m1v = *(const floatx4*)(bn2m + c0 + 4);
    floatx4 v0v = *(const floatx4*)(bn2v + c0), v1v = *(const floatx4*)(bn2v + c0 + 4);
    short8v o;
    #pragma unroll
    for (int j=0;j<8;j++){
        float v0c = b2f((u16)vc[j]);
        float u1 = acc[j] + v0c;
        float gl = gelu_exact(u1);
        float gg = (j<4) ? g0v[j] : g1v[j-4];
        float bbv= (j<4) ? b0v[j] : b1v[j-4];
        float mm = (j<4) ? m0v[j] : m1v[j-4];
        float vv = (j<4) ? v0v[j] : v1v[j-4];
        float bn = (gl - mm)*rsqrtf(vv+1e-5f)*gg + bbv;
        o[j] = (short)f2b(bn*v0c);
    }
    *(short8v*)(U + pix*256 + c0) = o;
}

extern "C" void kernel_launch(void* const* d_in, const int* in_sizes, int n_in,
                              void* d_out, int out_size, void* d_ws, size_t ws_size,
                              hipStream_t stream)
{
    const float* x     = (const float*)d_in[0];
    const float* pos_w = (const float*)d_in[1];
    const float* pos_b = (const float*)d_in[2];
    const float* ln1g  = (const float*)d_in[3];
    const float* ln1b  = (const float*)d_in[4];
    const float* temp  = (const float*)d_in[5];
    const float* qkvw  = (const float*)d_in[6];
    const float* qkvdw = (const float*)d_in[7];
    const float* projw = (const float*)d_in[8];
    const float* gw1   = (const float*)d_in[9];
    const float* gb1   = (const float*)d_in[10];
    const float* gw2   = (const float*)d_in[11];
    const float* gb2   = (const float*)d_in[12];
    const float* a1    = (const float*)d_in[13];
    const float* a2    = (const float*)d_in[14];
    const float* a3    = (const float*)d_in[15];
    const float* a4    = (const float*)d_in[16];
    const float* ln2g  = (const float*)d_in[17];
    const float* ln2b  = (const float*)d_in[18];
    const float* fc1w  = (const float*)d_in[19];
    const float* bn1g  = (const float*)d_in[20];
    const float* bn1b  = (const float*)d_in[21];
    const float* bn1m  = (const float*)d_in[22];
    const float* bn1v  = (const float*)d_in[23];
    const float* bn2g  = (const float*)d_in[24];
    const float* bn2b  = (const float*)d_in[25];
    const float* bn2m  = (const float*)d_in[26];
    const float* bn2v  = (const float*)d_in[27];
    const float* fc2w  = (const float*)d_in[28];
    const float* bn3g  = (const float*)d_in[29];
    const float* bn3b  = (const float*)d_in[30];
    const float* bn3m  = (const float*)d_in[31];
    const float* bn3v  = (const float*)d_in[32];
    const float* dw0w  = (const float*)d_in[33];
    const float* dw0b  = (const float*)d_in[34];
    const float* dw1w  = (const float*)d_in[35];
    const float* dw1b  = (const float*)d_in[36];
    const float* dw2w  = (const float*)d_in[37];
    const float* dw2b  = (const float*)d_in[38];
    const float* dw3w  = (const float*)d_in[39];
    const float* dw3b  = (const float*)d_in[40];

    float* OUT = (float*)d_out;      // residual stream (fp32)

    // ---- workspace layout (bytes), peak ~64.3 MB ----
    char* p = (char*)d_ws;
    float* gpix  = (float*)p;                 p += (size_t)NPIX*4;
    float* dynk  = (float*)p;                 p += 256;
    float* gpart = (float*)p;                 p += 262144;
    float* gram  = (float*)p;                 p += 16384;
    float* attnW = (float*)p;                 p += 16384;
    u16*   wbf   = (u16*)p;                   p += 524288;
    u16*   Ybf   = (u16*)p;                   p += (size_t)CHW*192*2;
    u16*   QKVbf = (u16*)p;                   p += (size_t)CHW*288*2;
    u16*   QKVdbf= (u16*)p;                   p += (size_t)CHW*288*2;
    u16*   Pbf   = (u16*)p;                   p += (size_t)CHW*192*2;
    u16* qkvwb = wbf;
    u16* projwb= wbf + WQ;
    u16* gw1b  = wbf + WQ + WP;
    u16* fc1b  = wbf + WQ + WP + WG;
    u16* fc2b  = wbf + WQ + WP + WG + WF1;
    u16* G1bf  = QKVbf;
    u16* Zbf   = Pbf;
    u16* V0bf  = QKVdbf;
    u16* Ubf   = QKVbf;

    wprep_k<<<(WTOT+255)/256, 256, 0, stream>>>(qkvw, projw, gw1, fc1w, fc2w, wbf);
    pos_conv_k<<<BB*HH*4*48/256, 256, 0, stream>>>(x, pos_w, pos_b, OUT);

    for (int c=0; c<NCHUNK; c++){
        const float* Ab = OUT + (size_t)c*CHW*192;
        ln_k<<<CHW/4, 256, 0, stream>>>(Ab, ln1g, ln1b, Ybf);
        dim3 g(CHW/128, 2);
        gemm_bf16_k<GM_BIAS_RELU><<<g, 256, 0, stream>>>(Ybf, 192, gw1b, G1bf, 96,
            nullptr, 0, gb1, nullptr, nullptr, nullptr, 96, 192);
        gate2_k<<<CHW/256, 256, 0, stream>>>(G1bf, gw2, gb2, gpix + (size_t)c*CHW);
    }
    gate_reduce_k<<<1, 1024, 0, stream>>>(gpix, dynk);

    for (int c=0; c<NCHUNK; c++){
        float* Ab = OUT + (size_t)c*CHW*192;
        ln_k<<<CHW/4, 256, 0, stream>>>(Ab, ln1g, ln1b, Ybf);
        {
            dim3 g(CHW/128, 5);
            gemm_bf16_k<GM_NONE><<<g, 256, 0, stream>>>(Ybf, 192, qkvwb, QKVbf, 288,
                nullptr, 0, nullptr,nullptr,nullptr,nullptr, 288, 96);
        }
        qkv_dw_k<<<CHW*36/256, 256, 0, stream>>>(QKVbf, qkvdw, QKVdbf);
        { dim3 g(CB*8, 16); gram_k<<<g, 256, 0, stream>>>(QKVdbf, gpart); }
        gram_combine_k<<<(CB*8*168+255)/256, 256, 0, stream>>>(gpart, gram);
        attn_k<<<CB*8, 256, 0, stream>>>(gram, temp, dynk, a1,a2,a3,a4, attnW);
        attn_apply_k<<<CHW*192/256, 256, 0, stream>>>(QKVdbf, Ybf, attnW, Pbf);
        {
            dim3 g(CHW/128, 3);
            gemm_bf16_k<GM_RES><<<g, 256, 0, stream>>>(Pbf, 192, projwb, Ab, 192,
                Ab, 192, nullptr,nullptr,nullptr,nullptr, 192, 192);
        }
        ln_k<<<CHW/4, 256, 0, stream>>>(Ab, ln2g, ln2b, Zbf);
        {
            dim3 g(CHW/128, 4);
            gemm_bf16_k<GM_GELU_BN><<<g, 256, 0, stream>>>(Zbf, 192, fc1b, V0bf, 256,
                nullptr, 0, bn1g,bn1b,bn1m,bn1v, 256, 192);
        }
        ffn_dw_k<<<CHW/8, 256, 0, stream>>>(V0bf, dw0w,dw0b,dw1w,dw1b,dw2w,dw2b,dw3w,dw3b,
                                            bn2g,bn2b,bn2m,bn2v, Ubf);
        {
            dim3 g(CHW/128, 3);
            gemm_bf16_k<GM_BN_RES><<<g, 256, 0, stream>>>(Ubf, 256, fc2b, Ab, 192,
                Ab, 192, bn3g,bn3b,bn3m,bn3v, 192, 256);
        }
    }
}

// Round 6
// 944.540 us; speedup vs baseline: 3.4622x; 1.3029x over previous
//
#include <hip/hip_runtime.h>
#include <hip/hip_bf16.h>
#include <math.h>

#define BB 8
#define HH 128
#define WW 128
#define HW (HH*WW)          // 16384
#define NPIX (BB*HW)        // 131072

typedef unsigned short u16;
typedef __attribute__((ext_vector_type(4))) float  floatx4;
typedef __attribute__((ext_vector_type(4))) short  short4v;
typedef __attribute__((ext_vector_type(8))) short  short8v;

static __device__ __forceinline__ float gelu_exact(float x){
    return 0.5f*x*(1.0f+erff(x*0.70710678118654752440f));
}
static __device__ __forceinline__ float b2f(u16 v){
    union { unsigned u; float f; } x; x.u = ((unsigned)v)<<16; return x.f;
}
static __device__ __forceinline__ u16 f2b(float f){
    __hip_bfloat16 h = __float2bfloat16(f);
    return *(u16*)&h;
}

// ---------- weight prep: fp32 -> bf16 for the five GEMM weight matrices ----------
#define WQ 27648
#define WP 36864
#define WG 18432
#define WF1 49152
#define WF2 49152
#define WTOT (WQ+WP+WG+WF1+WF2)   // 181248
__global__ __launch_bounds__(256) void wprep_k(const float* __restrict__ a,
    const float* __restrict__ b, const float* __restrict__ c,
    const float* __restrict__ d, const float* __restrict__ e, u16* __restrict__ o)
{
    int i = blockIdx.x*256 + threadIdx.x;
    if (i >= WTOT) return;
    float v;
    if (i < WQ) v = a[i];
    else if (i < WQ+WP) v = b[i-WQ];
    else if (i < WQ+WP+WG) v = c[i-WQ-WP];
    else if (i < WQ+WP+WG+WF1) v = d[i-WQ-WP-WG];
    else v = e[i-WQ-WP-WG-WF1];
    o[i] = f2b(v);
}

// ---------- pos depthwise 3x3 + bias + residual, 16-col segments (8/row) ----------
__global__ __launch_bounds__(256) void pos_conv_k(const float* __restrict__ x,
    const float* __restrict__ w, const float* __restrict__ bias, float* __restrict__ out)
{
    int gid = blockIdx.x*256 + threadIdx.x;     // ((b*HH+hy)*8 + seg)*48 + c4
    int c4 = gid % 48; int rest = gid / 48;
    int seg = rest & 7; rest >>= 3;
    int hy = rest % HH; int b = rest / HH;
    int c0 = c4*4;
    float wr[3][3][4];
    #pragma unroll
    for (int j=0;j<4;j++)
        #pragma unroll
        for (int ky=0;ky<3;ky++)
            #pragma unroll
            for (int kx=0;kx<3;kx++)
                wr[ky][kx][j] = w[(c0+j)*9 + ky*3 + kx];
    float4 bias4 = *(const float4*)(bias + c0);
    const float4* x4 = (const float4*)x;
    const float4* r0 = x4 + ((size_t)(b*HH + hy-1)*WW)*48 + c4;
    const float4* r1 = x4 + ((size_t)(b*HH + hy  )*WW)*48 + c4;
    const float4* r2 = x4 + ((size_t)(b*HH + hy+1)*WW)*48 + c4;
    bool v0 = hy > 0, v2 = hy < HH-1;
    float4 z4 = make_float4(0.f,0.f,0.f,0.f);
    int s0 = seg*16;
    float4 cA[3], cB[3], cC[3], cN[3];
    bool la = s0 > 0;
    cA[0] = (v0&&la) ? r0[(size_t)(s0-1)*48] : z4;
    cA[1] = la ? r1[(size_t)(s0-1)*48] : z4;
    cA[2] = (v2&&la) ? r2[(size_t)(s0-1)*48] : z4;
    cB[0] = v0 ? r0[(size_t)s0*48] : z4;  cB[1] = r1[(size_t)s0*48];  cB[2] = v2 ? r2[(size_t)s0*48] : z4;
    cC[0] = v0 ? r0[(size_t)(s0+1)*48] : z4; cC[1] = r1[(size_t)(s0+1)*48]; cC[2] = v2 ? r2[(size_t)(s0+1)*48] : z4;
    float4* o4 = (float4*)out + ((size_t)(b*HH + hy)*WW)*48 + c4;
    for (int i2=0; i2<16; i2++){
        int wx = s0 + i2;
        bool okc = (wx+2) < WW;
        size_t noff = (size_t)(wx+2)*48;
        cN[0] = (v0 && okc) ? r0[noff] : z4;
        cN[1] = okc ? r1[noff] : z4;
        cN[2] = (v2 && okc) ? r2[noff] : z4;
        float4 acc = bias4;
        #pragma unroll
        for (int i=0;i<3;i++){
            acc.x = fmaf(wr[i][0][0], cA[i].x, acc.x);
            acc.y = fmaf(wr[i][0][1], cA[i].y, acc.y);
            acc.z = fmaf(wr[i][0][2], cA[i].z, acc.z);
            acc.w = fmaf(wr[i][0][3], cA[i].w, acc.w);
            acc.x = fmaf(wr[i][1][0], cB[i].x, acc.x);
            acc.y = fmaf(wr[i][1][1], cB[i].y, acc.y);
            acc.z = fmaf(wr[i][1][2], cB[i].z, acc.z);
            acc.w = fmaf(wr[i][1][3], cB[i].w, acc.w);
            acc.x = fmaf(wr[i][2][0], cC[i].x, acc.x);
            acc.y = fmaf(wr[i][2][1], cC[i].y, acc.y);
            acc.z = fmaf(wr[i][2][2], cC[i].z, acc.z);
            acc.w = fmaf(wr[i][2][3], cC[i].w, acc.w);
        }
        acc.x += cB[1].x; acc.y += cB[1].y; acc.z += cB[1].z; acc.w += cB[1].w;
        o4[(size_t)wx*48] = acc;
        #pragma unroll
        for (int i=0;i<3;i++){ cA[i]=cB[i]; cB[i]=cC[i]; cC[i]=cN[i]; }
    }
}

// ---------- LayerNorm over C=192 fp32 in -> bf16 out, wave per pixel ----------
__global__ __launch_bounds__(256) void ln_k(const float* __restrict__ in,
    const float* __restrict__ g, const float* __restrict__ bta, u16* __restrict__ out)
{
    int wid = threadIdx.x >> 6, lane = threadIdx.x & 63;
    size_t pix = (size_t)blockIdx.x*4 + wid;
    const float* row = in + pix*192;
    float x0 = row[lane], x1 = row[lane+64], x2 = row[lane+128];
    float s = x0+x1+x2;
    float q = x0*x0 + x1*x1 + x2*x2;
    #pragma unroll
    for (int off=32; off; off>>=1){ s += __shfl_xor(s,off,64); q += __shfl_xor(q,off,64); }
    float mean = s*(1.f/192.f);
    float var  = q*(1.f/192.f) - mean*mean;
    float inv  = rsqrtf(var + 1e-6f);
    u16* orow = out + pix*192;
    orow[lane]     = f2b((x0-mean)*inv*g[lane]     + bta[lane]);
    orow[lane+64]  = f2b((x1-mean)*inv*g[lane+64]  + bta[lane+64]);
    orow[lane+128] = f2b((x2-mean)*inv*g[lane+128] + bta[lane+128]);
}

// ---------- bf16 MFMA GEMM: C[M,N] = epi(A[M,K] @ W[N,K]^T), A,W bf16 ----------
#define GM_NONE 0
#define GM_RES 1
#define GM_GELU_BN 2
#define GM_BN_RES 3
#define GM_BIAS_RELU 4

template<int MODE>
__global__ __launch_bounds__(256) void gemm_bf16_k(
    const u16* __restrict__ A, int lda,
    const u16* __restrict__ W,
    void* __restrict__ Cv, int ldc,
    const float* __restrict__ R, int ldr,
    const float* __restrict__ bg, const float* __restrict__ bb,
    const float* __restrict__ bm_, const float* __restrict__ bv,
    int N, int K)
{
    __shared__ u16 As[128*72];   // row stride 72 shorts (144 B): 16B-aligned b128 ops
    __shared__ u16 Ws[64*72];
    int t = threadIdx.x;
    int bm = blockIdx.x * 128;
    int bn = blockIdx.y * 64;
    int wave = t >> 6, lane = t & 63;
    int wm = (wave >> 1)*64, wn = (wave & 1)*32;
    int lr = lane & 15, lk = lane >> 4;
    floatx4 acc[4][2] = {};
    int arow = t >> 1, ahalf = t & 1;
    int brow = t >> 2, bq   = t & 3;

    for (int k0 = 0; k0 < K; k0 += 64){
        __syncthreads();
        {
            const u16* src = A + (size_t)(bm + arow)*lda + k0 + ahalf*32;
            #pragma unroll
            for (int j=0;j<4;j++){
                int kk = k0 + ahalf*32 + 8*j;
                short8v v = {};
                if (kk < K) v = *(const short8v*)(src + 8*j);
                *(short8v*)&As[arow*72 + ahalf*32 + 8*j] = v;
            }
        }
        {
            int n = bn + brow;
            bool nv = n < N;
            const u16* src = W + (size_t)n*K + k0 + bq*16;
            #pragma unroll
            for (int j=0;j<2;j++){
                int kk = k0 + bq*16 + 8*j;
                short8v v = {};
                if (nv && kk < K) v = *(const short8v*)(src + 8*j);
                *(short8v*)&Ws[brow*72 + bq*16 + 8*j] = v;
            }
        }
        __syncthreads();
        #pragma unroll
        for (int s=0; s<2; s++){
            int kb = s*32 + lk*8;
            short8v bfr0 = *(const short8v*)&Ws[(wn + lr)*72 + kb];
            short8v bfr1 = *(const short8v*)&Ws[(wn + 16 + lr)*72 + kb];
            #pragma unroll
            for (int m=0;m<4;m++){
                short8v afr = *(const short8v*)&As[(wm + m*16 + lr)*72 + kb];
                acc[m][0] = __builtin_amdgcn_mfma_f32_16x16x32_bf16(afr, bfr0, acc[m][0], 0,0,0);
                acc[m][1] = __builtin_amdgcn_mfma_f32_16x16x32_bf16(afr, bfr1, acc[m][1], 0,0,0);
            }
        }
    }
    #pragma unroll
    for (int m=0;m<4;m++){
        #pragma unroll
        for (int n2=0;n2<2;n2++){
            int gcol = bn + wn + n2*16 + lr;
            if (gcol >= N) continue;
            #pragma unroll
            for (int rg=0; rg<4; rg++){
                int grow = bm + wm + m*16 + lk*4 + rg;
                float v = acc[m][n2][rg];
                if (MODE == GM_RES){
                    v += R[(size_t)grow*ldr + gcol];
                    ((float*)Cv)[(size_t)grow*ldc + gcol] = v;
                } else if (MODE == GM_BN_RES){
                    float bnv = (v - bm_[gcol])*rsqrtf(bv[gcol]+1e-5f)*bg[gcol] + bb[gcol];
                    ((float*)Cv)[(size_t)grow*ldc + gcol] = bnv + R[(size_t)grow*ldr + gcol];
                } else if (MODE == GM_GELU_BN){
                    float gl = gelu_exact(v);
                    v = (gl - bm_[gcol])*rsqrtf(bv[gcol]+1e-5f)*bg[gcol] + bb[gcol];
                    ((u16*)Cv)[(size_t)grow*ldc + gcol] = f2b(v);
                } else if (MODE == GM_BIAS_RELU){
                    ((u16*)Cv)[(size_t)grow*ldc + gcol] = f2b(fmaxf(v + bg[gcol], 0.f));
                } else {
                    ((u16*)Cv)[(size_t)grow*ldc + gcol] = f2b(v);
                }
            }
        }
    }
}

// ---------- gate stage 2: sigmoid(G1 @ w2 + b2) per pixel, G1 bf16 ----------
__global__ __launch_bounds__(256) void gate2_k(const u16* __restrict__ G1,
    const float* __restrict__ w2, const float* __restrict__ b2, float* __restrict__ gpix)
{
    int pix = blockIdx.x*256 + threadIdx.x;
    const short4v* g4 = (const short4v*)(G1 + (size_t)pix*96);
    const float4* w4 = (const float4*)w2;
    float s = b2[0];
    #pragma unroll
    for (int j=0;j<24;j++){
        short4v g = g4[j]; float4 w = w4[j];
        s += b2f((u16)g.x)*w.x + b2f((u16)g.y)*w.y + b2f((u16)g.z)*w.z + b2f((u16)g.w)*w.w;
    }
    gpix[pix] = 1.f/(1.f+expf(-s));
}

// ---------- deterministic mean of gpix -> dyn_k ----------
__global__ __launch_bounds__(1024) void gate_reduce_k(const float* __restrict__ gpix,
                                                      float* __restrict__ dynk)
{
    __shared__ float sm[16];
    float s = 0.f;
    for (int i=threadIdx.x; i<NPIX; i+=1024) s += gpix[i];
    #pragma unroll
    for (int off=32; off; off>>=1) s += __shfl_xor(s,off,64);
    int wid = threadIdx.x>>6, lane = threadIdx.x&63;
    if (lane==0) sm[wid]=s;
    __syncthreads();
    if (threadIdx.x==0){
        float tot=0.f; for (int i=0;i<16;i++) tot+=sm[i];
        *dynk = floorf(12.0f * (tot/(float)NPIX));
    }
}

// ---------- qkv depthwise 3x3 (288 ch), bf16, 8-ch vectorized + LDS weights ----------
#define QPOS(c8) ((c8)*8 + ((c8)>>2)*4)
#define QTAPSTRIDE 324
__global__ __launch_bounds__(256) void qkv_dw_k(const u16* __restrict__ in,
    const float* __restrict__ w, u16* __restrict__ out)
{
    __shared__ float wlds[9*QTAPSTRIDE];
    int t = threadIdx.x;
    for (int i=t; i<2592; i+=256){
        int tap = i/288, cc = i%288;
        wlds[tap*QTAPSTRIDE + QPOS(cc>>3) + (cc&7)] = w[cc*9+tap];
    }
    __syncthreads();
    int idx = blockIdx.x*256 + t;          // over NB*HW*36
    int c8 = idx % 36; int pix = idx / 36;
    int wx = pix % WW; int hy = (pix / WW) % HH; int img = pix / HW;
    int c0 = c8*8;
    int wofs = QPOS(c8);
    float acc[8] = {};
    #pragma unroll
    for (int ky=0; ky<3; ky++){
        int hh = hy + ky - 1; if ((unsigned)hh >= HH) continue;
        #pragma unroll
        for (int kx=0; kx<3; kx++){
            int ww2 = wx + kx - 1; if ((unsigned)ww2 >= WW) continue;
            int tap = ky*3+kx;
            short8v v = *(const short8v*)(in + ((size_t)(img*HH+hh)*WW+ww2)*288 + c0);
            floatx4 wa = *(const floatx4*)&wlds[tap*QTAPSTRIDE + wofs];
            floatx4 wb = *(const floatx4*)&wlds[tap*QTAPSTRIDE + wofs + 4];
            #pragma unroll
            for (int j=0;j<4;j++) acc[j]   = fmaf(wa[j], b2f((u16)v[j]),   acc[j]);
            #pragma unroll
            for (int j=0;j<4;j++) acc[4+j] = fmaf(wb[j], b2f((u16)v[4+j]), acc[4+j]);
        }
    }
    short8v o;
    #pragma unroll
    for (int j=0;j<8;j++) o[j] = (short)f2b(acc[j]);
    *(short8v*)(out + (size_t)pix*288 + c0) = o;
}

// ---------- Gram partials per (img,head,slice): G[12][12], |q|^2, |k|^2 ----------
__global__ __launch_bounds__(256) void gram_k(const u16* __restrict__ QKVd,
                                              float* __restrict__ part)
{
    int bh = blockIdx.x;        // NB*8: img*8+h
    int slice = blockIdx.y;     // 16 (1024 pixels each)
    int img = bh >> 3, h = bh & 7;
    int qbase = h*12, kbase = 96 + h*12;
    const u16* base = QKVd + (size_t)img*HW*288;
    __shared__ float qs[64][12];
    __shared__ float ks[64][12];
    int t = threadIdx.x;
    float acc = 0.f;
    int c = (t<144) ? t/12 : (t<156 ? t-144 : t-156);
    int d = (t<144) ? t%12 : 0;
    for (int st=0; st<16; st++){
        int pix0 = slice*1024 + st*64;
        __syncthreads();
        for (int i=t; i<64*24; i+=256){
            int p = i/24, cc = i%24;
            float v = b2f(base[(size_t)(pix0 + p)*288 + (cc<12 ? qbase+cc : kbase+cc-12)]);
            if (cc<12) qs[p][cc]=v; else ks[p][cc-12]=v;
        }
        __syncthreads();
        if (t<144){        for (int p=0;p<64;p++) acc = fmaf(qs[p][c], ks[p][d], acc); }
        else if (t<156){   for (int p=0;p<64;p++) acc = fmaf(qs[p][c], qs[p][c], acc); }
        else if (t<168){   for (int p=0;p<64;p++) acc = fmaf(ks[p][c], ks[p][c], acc); }
    }
    if (t<168) part[((size_t)bh*16 + slice)*168 + t] = acc;
}

__global__ __launch_bounds__(256) void gram_combine_k(const float* __restrict__ part,
                                                      float* __restrict__ gram, int n)
{
    int i = blockIdx.x*256 + threadIdx.x;
    if (i >= n) return;
    int bh = i/168, t = i%168;
    float s = 0.f;
    for (int sl=0; sl<16; sl++) s += part[((size_t)bh*16+sl)*168 + t];
    gram[i] = s;
}

// ---------- attn 12x12: normalize, temperature, top-k mask, softmax ----------
__global__ __launch_bounds__(256) void attn_k(const float* __restrict__ gram,
    const float* __restrict__ temp, const float* __restrict__ dynk_p,
    const float* __restrict__ a1, const float* __restrict__ a2,
    const float* __restrict__ a3, const float* __restrict__ a4,
    float* __restrict__ attnW)
{
    int bh = blockIdx.x;   // NB*8: img*8+h
    int h = bh & 7;
    __shared__ float av[12][12];
    __shared__ float mv[12][12];
    __shared__ float nq[12], nk[12];
    int t = threadIdx.x;
    if (t < 12) nq[t] = fmaxf(sqrtf(gram[bh*168+144+t]), 1e-12f);
    else if (t < 24) nk[t-12] = fmaxf(sqrtf(gram[bh*168+156+(t-12)]), 1e-12f);
    __syncthreads();
    if (t < 144){
        int c=t/12, d=t%12;
        av[c][d] = gram[bh*168+t] / (nq[c]*nk[d]) * temp[h];
    }
    __syncthreads();
    float dk = *dynk_p;
    if (t < 144){
        int c=t/12, d=t%12; float v = av[c][d];
        int r = 0;
        #pragma unroll
        for (int j=0;j<12;j++){
            float o = av[c][j];
            r += (o > v) ? 1 : ((o == v && j < d) ? 1 : 0);
        }
        mv[c][d] = ((float)r < dk) ? v : -INFINITY;
    }
    __syncthreads();
    if (t < 12){
        float mx = -INFINITY;
        for (int d2=0; d2<12; d2++) mx = fmaxf(mx, mv[t][d2]);
        float e[12]; float s = 0.f;
        for (int d2=0; d2<12; d2++){ e[d2] = expf(mv[t][d2]-mx); s += e[d2]; }
        float sc = (a1[0]+a2[0]+a3[0]+a4[0]) / s;
        for (int d2=0; d2<12; d2++) attnW[(size_t)bh*144 + t*12 + d2] = e[d2]*sc;
    }
}

// ---------- attn apply + concat x2 -> P bf16 ----------
__global__ __launch_bounds__(256) void attn_apply_k(const u16* __restrict__ QKVd,
    const u16* __restrict__ Y, const float* __restrict__ attnW, u16* __restrict__ P)
{
    int idx = blockIdx.x*256 + threadIdx.x;          // NB*HW*192
    int c = idx % 192; size_t pix = (size_t)(idx / 192);
    int img = (int)(pix >> 14);
    u16 outv;
    if (c < 96){
        int h = c/12, cc = c%12;
        const u16* vr = QKVd + pix*288 + 192 + h*12;
        const float* aw = attnW + ((size_t)(img*8+h))*144 + cc*12;
        float s = 0.f;
        #pragma unroll
        for (int d=0; d<12; d++) s += aw[d]*b2f(vr[d]);
        outv = f2b(s);
    } else {
        outv = Y[pix*192 + c];
    }
    P[idx] = outv;
}

// ---------- FFN multi-scale depthwise: 8 px/block, wave = scale group, 8 ch/lane ----------
__global__ __launch_bounds__(256) void ffn_dw_k(const u16* __restrict__ V0,
    const float* __restrict__ w0, const float* __restrict__ bb0,
    const float* __restrict__ w1, const float* __restrict__ bb1,
    const float* __restrict__ w2, const float* __restrict__ bb2,
    const float* __restrict__ w3, const float* __restrict__ bb3,
    const float* __restrict__ bn2g, const float* __restrict__ bn2b,
    const float* __restrict__ bn2m, const float* __restrict__ bn2v,
    u16* __restrict__ U)
{
    __shared__ float wlds[5376];
    int t = threadIdx.x;
    for (int i=t; i<64;   i+=256)  wlds[i] = w0[i];
    for (int i=t; i<576;  i+=256){ int tap=i>>6, cc=i&63; wlds[64+i]   = w1[cc*9+tap]; }
    for (int i=t; i<1600; i+=256){ int tap=i>>6, cc=i&63; wlds[640+i]  = w2[cc*25+tap]; }
    for (int i=t; i<3136; i+=256){ int tap=i>>6, cc=i&63; wlds[2240+i] = w3[cc*49+tap]; }
    __syncthreads();
    int g = t >> 6, lane = t & 63;
    int p8 = lane >> 3, ci = lane & 7;
    size_t pix = (size_t)blockIdx.x*8 + p8;
    int wx = (int)(pix % WW);
    int hy = (int)((pix / WW) % HH);
    int img = (int)(pix / HW);
    int c0 = g*64 + ci*8;
    int ks = 2*g+1, pad = g;
    const int gb[4] = {0,64,640,2240};
    const float* wg = &wlds[gb[g]];
    float acc[8];
    {
        const float* bp = (g==0)?bb0:(g==1)?bb1:(g==2)?bb2:bb3;
        floatx4 b0 = *(const floatx4*)(bp + ci*8);
        floatx4 b1 = *(const floatx4*)(bp + ci*8 + 4);
        #pragma unroll
        for (int j=0;j<4;j++){ acc[j]=b0[j]; acc[4+j]=b1[j]; }
    }
    for (int ky=0; ky<ks; ky++){
        int hh = hy+ky-pad; if ((unsigned)hh >= HH) continue;
        const u16* rowp = V0 + ((size_t)(img*HH+hh)*WW)*256 + c0;
        for (int kx=0; kx<ks; kx++){
            int ww2 = wx+kx-pad; if ((unsigned)ww2 >= WW) continue;
            int tap = ky*ks+kx;
            short8v v = *(const short8v*)(rowp + (size_t)ww2*256);
            floatx4 wa = *(const floatx4*)&wg[tap*64 + ci*8];
            floatx4 wb = *(const floatx4*)&wg[tap*64 + ci*8 + 4];
            #pragma unroll
            for (int j=0;j<4;j++) acc[j]   = fmaf(wa[j], b2f((u16)v[j]),   acc[j]);
            #pragma unroll
            for (int j=0;j<4;j++) acc[4+j] = fmaf(wb[j], b2f((u16)v[4+j]), acc[4+j]);
        }
    }
    short8v vc = *(const short8v*)(V0 + pix*256 + c0);
    floatx4 g0v = *(const floatx4*)(bn2g + c0), g1v = *(const floatx4*)(bn2g + c0 + 4);
    floatx4 b0v = *(const floatx4*)(bn2b + c0), b1v = *(const floatx4*)(bn2b + c0 + 4);
    floatx4 m0v = *(const floatx4*)(bn2m + c0), m1v = *(const floatx4*)(bn2m + c0 + 4);
    floatx4 v0v = *(const floatx4*)(bn2v + c0), v1v = *(const floatx4*)(bn2v + c0 + 4);
    short8v o;
    #pragma unroll
    for (int j=0;j<8;j++){
        float v0c = b2f((u16)vc[j]);
        float u1 = acc[j] + v0c;
        float gl = gelu_exact(u1);
        float gg = (j<4) ? g0v[j] : g1v[j-4];
        float bbv= (j<4) ? b0v[j] : b1v[j-4];
        float mm = (j<4) ? m0v[j] : m1v[j-4];
        float vv = (j<4) ? v0v[j] : v1v[j-4];
        float bn = (gl - mm)*rsqrtf(vv+1e-5f)*gg + bbv;
        o[j] = (short)f2b(bn*v0c);
    }
    *(short8v*)(U + pix*256 + c0) = o;
}

extern "C" void kernel_launch(void* const* d_in, const int* in_sizes, int n_in,
                              void* d_out, int out_size, void* d_ws, size_t ws_size,
                              hipStream_t stream)
{
    const float* x     = (const float*)d_in[0];
    const float* pos_w = (const float*)d_in[1];
    const float* pos_b = (const float*)d_in[2];
    const float* ln1g  = (const float*)d_in[3];
    const float* ln1b  = (const float*)d_in[4];
    const float* temp  = (const float*)d_in[5];
    const float* qkvw  = (const float*)d_in[6];
    const float* qkvdw = (const float*)d_in[7];
    const float* projw = (const float*)d_in[8];
    const float* gw1   = (const float*)d_in[9];
    const float* gb1   = (const float*)d_in[10];
    const float* gw2   = (const float*)d_in[11];
    const float* gb2   = (const float*)d_in[12];
    const float* a1    = (const float*)d_in[13];
    const float* a2    = (const float*)d_in[14];
    const float* a3    = (const float*)d_in[15];
    const float* a4    = (const float*)d_in[16];
    const float* ln2g  = (const float*)d_in[17];
    const float* ln2b  = (const float*)d_in[18];
    const float* fc1w  = (const float*)d_in[19];
    const float* bn1g  = (const float*)d_in[20];
    const float* bn1b  = (const float*)d_in[21];
    const float* bn1m  = (const float*)d_in[22];
    const float* bn1v  = (const float*)d_in[23];
    const float* bn2g  = (const float*)d_in[24];
    const float* bn2b  = (const float*)d_in[25];
    const float* bn2m  = (const float*)d_in[26];
    const float* bn2v  = (const float*)d_in[27];
    const float* fc2w  = (const float*)d_in[28];
    const float* bn3g  = (const float*)d_in[29];
    const float* bn3b  = (const float*)d_in[30];
    const float* bn3m  = (const float*)d_in[31];
    const float* bn3v  = (const float*)d_in[32];
    const float* dw0w  = (const float*)d_in[33];
    const float* dw0b  = (const float*)d_in[34];
    const float* dw1w  = (const float*)d_in[35];
    const float* dw1b  = (const float*)d_in[36];
    const float* dw2w  = (const float*)d_in[37];
    const float* dw2b  = (const float*)d_in[38];
    const float* dw3w  = (const float*)d_in[39];
    const float* dw3b  = (const float*)d_in[40];

    float* OUT = (float*)d_out;      // residual stream (fp32)

    // ---- fixed small buffers ----
    char* p = (char*)d_ws;
    float* gpix  = (float*)p;                 p += (size_t)NPIX*4;      // 524288
    float* dynk  = (float*)p;                 p += 256;
    float* gpart = (float*)p;                 p += 64*16*168*4;         // 688128
    float* gram  = (float*)p;                 p += 64*168*4;            // 43008
    float* attnW = (float*)p;                 p += 64*144*4;            // 36864
    u16*   wbf   = (u16*)p;                   p += (size_t)WTOT*2;      // 362496
    size_t fixedB = (size_t)(p - (char*)d_ws);

    // ---- choose chunk size from ws_size: per-image 31.5 MB ----
    size_t perImg = (size_t)HW*2*(192+288+288+192);   // 31457280
    int CBr = 2;
    if (ws_size >= fixedB + 8*perImg) CBr = 8;
    else if (ws_size >= fixedB + 4*perImg) CBr = 4;
    int NCHUNKr = BB/CBr;
    size_t CHWr = (size_t)CBr*HW;

    u16* Ybf   = (u16*)p;                   p += CHWr*192*2;
    u16* QKVbf = (u16*)p;                   p += CHWr*288*2;
    u16* QKVdbf= (u16*)p;                   p += CHWr*288*2;
    u16* Pbf   = (u16*)p;
    u16* qkvwb = wbf;
    u16* projwb= wbf + WQ;
    u16* gw1b  = wbf + WQ + WP;
    u16* fc1b  = wbf + WQ + WP + WG;
    u16* fc2b  = wbf + WQ + WP + WG + WF1;
    u16* G1bf  = QKVbf;
    u16* Zbf   = Pbf;
    u16* V0bf  = QKVdbf;
    u16* Ubf   = QKVbf;

    wprep_k<<<(WTOT+255)/256, 256, 0, stream>>>(qkvw, projw, gw1, fc1w, fc2w, wbf);
    pos_conv_k<<<BB*HH*8*48/256, 256, 0, stream>>>(x, pos_w, pos_b, OUT);

    // gate phase
    for (int c=0; c<NCHUNKr; c++){
        const float* Ab = OUT + (size_t)c*CHWr*192;
        ln_k<<<CHWr/4, 256, 0, stream>>>(Ab, ln1g, ln1b, Ybf);
        dim3 g(CHWr/128, 2);
        gemm_bf16_k<GM_BIAS_RELU><<<g, 256, 0, stream>>>(Ybf, 192, gw1b, G1bf, 96,
            nullptr, 0, gb1, nullptr, nullptr, nullptr, 96, 192);
        gate2_k<<<CHWr/256, 256, 0, stream>>>(G1bf, gw2, gb2, gpix + (size_t)c*CHWr);
    }
    gate_reduce_k<<<1, 1024, 0, stream>>>(gpix, dynk);

    // main phase
    for (int c=0; c<NCHUNKr; c++){
        float* Ab = OUT + (size_t)c*CHWr*192;
        if (NCHUNKr > 1)   // single-chunk mode: Ybf from gate phase is still valid
            ln_k<<<CHWr/4, 256, 0, stream>>>(Ab, ln1g, ln1b, Ybf);
        {
            dim3 g(CHWr/128, 5);
            gemm_bf16_k<GM_NONE><<<g, 256, 0, stream>>>(Ybf, 192, qkvwb, QKVbf, 288,
                nullptr, 0, nullptr,nullptr,nullptr,nullptr, 288, 96);
        }
        qkv_dw_k<<<CHWr*36/256, 256, 0, stream>>>(QKVbf, qkvdw, QKVdbf);
        { dim3 g(CBr*8, 16); gram_k<<<g, 256, 0, stream>>>(QKVdbf, gpart); }
        gram_combine_k<<<(CBr*8*168+255)/256, 256, 0, stream>>>(gpart, gram, CBr*8*168);
        attn_k<<<CBr*8, 256, 0, stream>>>(gram, temp, dynk, a1,a2,a3,a4, attnW);
        attn_apply_k<<<CHWr*192/256, 256, 0, stream>>>(QKVdbf, Ybf, attnW, Pbf);
        {
            dim3 g(CHWr/128, 3);
            gemm_bf16_k<GM_RES><<<g, 256, 0, stream>>>(Pbf, 192, projwb, Ab, 192,
                Ab, 192, nullptr,nullptr,nullptr,nullptr, 192, 192);
        }
        ln_k<<<CHWr/4, 256, 0, stream>>>(Ab, ln2g, ln2b, Zbf);
        {
            dim3 g(CHWr/128, 4);
            gemm_bf16_k<GM_GELU_BN><<<g, 256, 0, stream>>>(Zbf, 192, fc1b, V0bf, 256,
                nullptr, 0, bn1g,bn1b,bn1m,bn1v, 256, 192);
        }
        ffn_dw_k<<<CHWr/8, 256, 0, stream>>>(V0bf, dw0w,dw0b,dw1w,dw1b,dw2w,dw2b,dw3w,dw3b,
                                             bn2g,bn2b,bn2m,bn2v, Ubf);
        {
            dim3 g(CHWr/128, 3);
            gemm_bf16_k<GM_BN_RES><<<g, 256, 0, stream>>>(Ubf, 256, fc2b, Ab, 192,
                Ab, 192, bn3g,bn3b,bn3m,bn3v, 192, 256);
        }
    }
}

// Round 7
// 889.027 us; speedup vs baseline: 3.6784x; 1.0624x over previous
//
#include <hip/hip_runtime.h>
#include <hip/hip_bf16.h>
#include <math.h>

#define BB 8
#define HH 128
#define WW 128
#define HW (HH*WW)          // 16384
#define NPIX (BB*HW)        // 131072

typedef unsigned short u16;
typedef __attribute__((ext_vector_type(4))) float  floatx4;
typedef __attribute__((ext_vector_type(4))) short  short4v;
typedef __attribute__((ext_vector_type(8))) short  short8v;

static __device__ __forceinline__ float gelu_exact(float x){
    return 0.5f*x*(1.0f+erff(x*0.70710678118654752440f));
}
static __device__ __forceinline__ float b2f(u16 v){
    union { unsigned u; float f; } x; x.u = ((unsigned)v)<<16; return x.f;
}
static __device__ __forceinline__ u16 f2b(float f){
    __hip_bfloat16 h = __float2bfloat16(f);
    return *(u16*)&h;
}

// ---------- weight prep: fp32 -> bf16 for the five GEMM weight matrices ----------
#define WQ 27648
#define WP 36864
#define WG 18432
#define WF1 49152
#define WF2 49152
#define WTOT (WQ+WP+WG+WF1+WF2)   // 181248
__global__ __launch_bounds__(256) void wprep_k(const float* __restrict__ a,
    const float* __restrict__ b, const float* __restrict__ c,
    const float* __restrict__ d, const float* __restrict__ e, u16* __restrict__ o)
{
    int i = blockIdx.x*256 + threadIdx.x;
    if (i >= WTOT) return;
    float v;
    if (i < WQ) v = a[i];
    else if (i < WQ+WP) v = b[i-WQ];
    else if (i < WQ+WP+WG) v = c[i-WQ-WP];
    else if (i < WQ+WP+WG+WF1) v = d[i-WQ-WP-WG];
    else v = e[i-WQ-WP-WG-WF1];
    o[i] = f2b(v);
}

// ---------- pos depthwise 3x3 + bias + residual, 8-col segments (16/row) ----------
__global__ __launch_bounds__(256) void pos_conv_k(const float* __restrict__ x,
    const float* __restrict__ w, const float* __restrict__ bias, float* __restrict__ out)
{
    int gid = blockIdx.x*256 + threadIdx.x;     // ((b*HH+hy)*16 + seg)*48 + c4
    int c4 = gid % 48; int rest = gid / 48;
    int seg = rest & 15; rest >>= 4;
    int hy = rest % HH; int b = rest / HH;
    int c0 = c4*4;
    float wr[3][3][4];
    #pragma unroll
    for (int j=0;j<4;j++)
        #pragma unroll
        for (int ky=0;ky<3;ky++)
            #pragma unroll
            for (int kx=0;kx<3;kx++)
                wr[ky][kx][j] = w[(c0+j)*9 + ky*3 + kx];
    float4 bias4 = *(const float4*)(bias + c0);
    const float4* x4 = (const float4*)x;
    const float4* r0 = x4 + ((size_t)(b*HH + hy-1)*WW)*48 + c4;
    const float4* r1 = x4 + ((size_t)(b*HH + hy  )*WW)*48 + c4;
    const float4* r2 = x4 + ((size_t)(b*HH + hy+1)*WW)*48 + c4;
    bool v0 = hy > 0, v2 = hy < HH-1;
    float4 z4 = make_float4(0.f,0.f,0.f,0.f);
    int s0 = seg*8;
    float4 cA[3], cB[3], cC[3], cN[3];
    bool la = s0 > 0;
    cA[0] = (v0&&la) ? r0[(size_t)(s0-1)*48] : z4;
    cA[1] = la ? r1[(size_t)(s0-1)*48] : z4;
    cA[2] = (v2&&la) ? r2[(size_t)(s0-1)*48] : z4;
    cB[0] = v0 ? r0[(size_t)s0*48] : z4;  cB[1] = r1[(size_t)s0*48];  cB[2] = v2 ? r2[(size_t)s0*48] : z4;
    cC[0] = v0 ? r0[(size_t)(s0+1)*48] : z4; cC[1] = r1[(size_t)(s0+1)*48]; cC[2] = v2 ? r2[(size_t)(s0+1)*48] : z4;
    float4* o4 = (float4*)out + ((size_t)(b*HH + hy)*WW)*48 + c4;
    for (int i2=0; i2<8; i2++){
        int wx = s0 + i2;
        bool okc = (wx+2) < WW;
        size_t noff = (size_t)(wx+2)*48;
        cN[0] = (v0 && okc) ? r0[noff] : z4;
        cN[1] = okc ? r1[noff] : z4;
        cN[2] = (v2 && okc) ? r2[noff] : z4;
        float4 acc = bias4;
        #pragma unroll
        for (int i=0;i<3;i++){
            acc.x = fmaf(wr[i][0][0], cA[i].x, acc.x);
            acc.y = fmaf(wr[i][0][1], cA[i].y, acc.y);
            acc.z = fmaf(wr[i][0][2], cA[i].z, acc.z);
            acc.w = fmaf(wr[i][0][3], cA[i].w, acc.w);
            acc.x = fmaf(wr[i][1][0], cB[i].x, acc.x);
            acc.y = fmaf(wr[i][1][1], cB[i].y, acc.y);
            acc.z = fmaf(wr[i][1][2], cB[i].z, acc.z);
            acc.w = fmaf(wr[i][1][3], cB[i].w, acc.w);
            acc.x = fmaf(wr[i][2][0], cC[i].x, acc.x);
            acc.y = fmaf(wr[i][2][1], cC[i].y, acc.y);
            acc.z = fmaf(wr[i][2][2], cC[i].z, acc.z);
            acc.w = fmaf(wr[i][2][3], cC[i].w, acc.w);
        }
        acc.x += cB[1].x; acc.y += cB[1].y; acc.z += cB[1].z; acc.w += cB[1].w;
        o4[(size_t)wx*48] = acc;
        #pragma unroll
        for (int i=0;i<3;i++){ cA[i]=cB[i]; cB[i]=cC[i]; cC[i]=cN[i]; }
    }
}

// ---------- LayerNorm over C=192 fp32 in -> bf16 out, wave per pixel ----------
__global__ __launch_bounds__(256) void ln_k(const float* __restrict__ in,
    const float* __restrict__ g, const float* __restrict__ bta, u16* __restrict__ out)
{
    int wid = threadIdx.x >> 6, lane = threadIdx.x & 63;
    size_t pix = (size_t)blockIdx.x*4 + wid;
    const float* row = in + pix*192;
    float x0 = row[lane], x1 = row[lane+64], x2 = row[lane+128];
    float s = x0+x1+x2;
    float q = x0*x0 + x1*x1 + x2*x2;
    #pragma unroll
    for (int off=32; off; off>>=1){ s += __shfl_xor(s,off,64); q += __shfl_xor(q,off,64); }
    float mean = s*(1.f/192.f);
    float var  = q*(1.f/192.f) - mean*mean;
    float inv  = rsqrtf(var + 1e-6f);
    u16* orow = out + pix*192;
    orow[lane]     = f2b((x0-mean)*inv*g[lane]     + bta[lane]);
    orow[lane+64]  = f2b((x1-mean)*inv*g[lane+64]  + bta[lane+64]);
    orow[lane+128] = f2b((x2-mean)*inv*g[lane+128] + bta[lane+128]);
}

// ---------- bf16 MFMA GEMM: C[M,N] = epi(A[M,K] @ W[N,K]^T), A,W bf16 ----------
// tile 256x64, BK=64, 4 waves (2x2), per wave 128x32 = 8x2 fragments of 16x16
#define GM_NONE 0
#define GM_RES 1
#define GM_GELU_BN 2
#define GM_BN_RES 3
#define GM_BIAS_RELU 4

template<int MODE>
__global__ __launch_bounds__(256) void gemm_bf16_k(
    const u16* __restrict__ A, int lda,
    const u16* __restrict__ W,
    void* __restrict__ Cv, int ldc,
    const float* __restrict__ R, int ldr,
    const float* __restrict__ bg, const float* __restrict__ bb,
    const float* __restrict__ bm_, const float* __restrict__ bv,
    int N, int K)
{
    __shared__ u16 As[256*72];   // 36 KB; row stride 72 shorts keeps b128 16B-aligned
    __shared__ u16 Ws[64*72];    // 9.2 KB
    int t = threadIdx.x;
    int bm = blockIdx.x * 256;
    int bn = blockIdx.y * 64;
    int wave = t >> 6, lane = t & 63;
    int wm = (wave >> 1)*128, wn = (wave & 1)*32;
    int lr = lane & 15, lk = lane >> 4;
    floatx4 acc[8][2] = {};
    int brow = t >> 2, bq = t & 3;

    for (int k0 = 0; k0 < K; k0 += 64){
        __syncthreads();
        {   // stage A: thread t stages full row bm+t (64 k = 8 x short8v)
            const u16* src = A + (size_t)(bm + t)*lda + k0;
            #pragma unroll
            for (int j=0;j<8;j++){
                int kk = k0 + 8*j;
                short8v v = {};
                if (kk < K) v = *(const short8v*)(src + 8*j);
                *(short8v*)&As[t*72 + 8*j] = v;
            }
        }
        {   // stage W tile 64x64
            int n = bn + brow;
            bool nv = n < N;
            const u16* src = W + (size_t)n*K + k0 + bq*16;
            #pragma unroll
            for (int j=0;j<2;j++){
                int kk = k0 + bq*16 + 8*j;
                short8v v = {};
                if (nv && kk < K) v = *(const short8v*)(src + 8*j);
                *(short8v*)&Ws[brow*72 + bq*16 + 8*j] = v;
            }
        }
        __syncthreads();
        #pragma unroll
        for (int s=0; s<2; s++){
            int kb = s*32 + lk*8;
            short8v bfr0 = *(const short8v*)&Ws[(wn + lr)*72 + kb];
            short8v bfr1 = *(const short8v*)&Ws[(wn + 16 + lr)*72 + kb];
            #pragma unroll
            for (int m=0;m<8;m++){
                short8v afr = *(const short8v*)&As[(wm + m*16 + lr)*72 + kb];
                acc[m][0] = __builtin_amdgcn_mfma_f32_16x16x32_bf16(afr, bfr0, acc[m][0], 0,0,0);
                acc[m][1] = __builtin_amdgcn_mfma_f32_16x16x32_bf16(afr, bfr1, acc[m][1], 0,0,0);
            }
        }
    }
    #pragma unroll
    for (int m=0;m<8;m++){
        #pragma unroll
        for (int n2=0;n2<2;n2++){
            int gcol = bn + wn + n2*16 + lr;
            if (gcol >= N) continue;
            #pragma unroll
            for (int rg=0; rg<4; rg++){
                int grow = bm + wm + m*16 + lk*4 + rg;
                float v = acc[m][n2][rg];
                if (MODE == GM_RES){
                    v += R[(size_t)grow*ldr + gcol];
                    ((float*)Cv)[(size_t)grow*ldc + gcol] = v;
                } else if (MODE == GM_BN_RES){
                    float bnv = (v - bm_[gcol])*rsqrtf(bv[gcol]+1e-5f)*bg[gcol] + bb[gcol];
                    ((float*)Cv)[(size_t)grow*ldc + gcol] = bnv + R[(size_t)grow*ldr + gcol];
                } else if (MODE == GM_GELU_BN){
                    float gl = gelu_exact(v);
                    v = (gl - bm_[gcol])*rsqrtf(bv[gcol]+1e-5f)*bg[gcol] + bb[gcol];
                    ((u16*)Cv)[(size_t)grow*ldc + gcol] = f2b(v);
                } else if (MODE == GM_BIAS_RELU){
                    ((u16*)Cv)[(size_t)grow*ldc + gcol] = f2b(fmaxf(v + bg[gcol], 0.f));
                } else {
                    ((u16*)Cv)[(size_t)grow*ldc + gcol] = f2b(v);
                }
            }
        }
    }
}

// ---------- gate stage 2: sigmoid(G1 @ w2 + b2) per pixel, G1 bf16 ----------
__global__ __launch_bounds__(256) void gate2_k(const u16* __restrict__ G1,
    const float* __restrict__ w2, const float* __restrict__ b2, float* __restrict__ gpix)
{
    int pix = blockIdx.x*256 + threadIdx.x;
    const short4v* g4 = (const short4v*)(G1 + (size_t)pix*96);
    const float4* w4 = (const float4*)w2;
    float s = b2[0];
    #pragma unroll
    for (int j=0;j<24;j++){
        short4v g = g4[j]; float4 w = w4[j];
        s += b2f((u16)g.x)*w.x + b2f((u16)g.y)*w.y + b2f((u16)g.z)*w.z + b2f((u16)g.w)*w.w;
    }
    gpix[pix] = 1.f/(1.f+expf(-s));
}

// ---------- deterministic mean of gpix -> dyn_k ----------
__global__ __launch_bounds__(1024) void gate_reduce_k(const float* __restrict__ gpix,
                                                      float* __restrict__ dynk)
{
    __shared__ float sm[16];
    float s = 0.f;
    for (int i=threadIdx.x; i<NPIX; i+=1024) s += gpix[i];
    #pragma unroll
    for (int off=32; off; off>>=1) s += __shfl_xor(s,off,64);
    int wid = threadIdx.x>>6, lane = threadIdx.x&63;
    if (lane==0) sm[wid]=s;
    __syncthreads();
    if (threadIdx.x==0){
        float tot=0.f; for (int i=0;i<16;i++) tot+=sm[i];
        *dynk = floorf(12.0f * (tot/(float)NPIX));
    }
}

// ---------- qkv depthwise 3x3 (288 ch), bf16, 8-ch vectorized + LDS weights ----------
#define QPOS(c8) ((c8)*8 + ((c8)>>2)*4)
#define QTAPSTRIDE 324
__global__ __launch_bounds__(256) void qkv_dw_k(const u16* __restrict__ in,
    const float* __restrict__ w, u16* __restrict__ out)
{
    __shared__ float wlds[9*QTAPSTRIDE];
    int t = threadIdx.x;
    for (int i=t; i<2592; i+=256){
        int tap = i/288, cc = i%288;
        wlds[tap*QTAPSTRIDE + QPOS(cc>>3) + (cc&7)] = w[cc*9+tap];
    }
    __syncthreads();
    int idx = blockIdx.x*256 + t;          // over NB*HW*36
    int c8 = idx % 36; int pix = idx / 36;
    int wx = pix % WW; int hy = (pix / WW) % HH; int img = pix / HW;
    int c0 = c8*8;
    int wofs = QPOS(c8);
    float acc[8] = {};
    #pragma unroll
    for (int ky=0; ky<3; ky++){
        int hh = hy + ky - 1; if ((unsigned)hh >= HH) continue;
        #pragma unroll
        for (int kx=0; kx<3; kx++){
            int ww2 = wx + kx - 1; if ((unsigned)ww2 >= WW) continue;
            int tap = ky*3+kx;
            short8v v = *(const short8v*)(in + ((size_t)(img*HH+hh)*WW+ww2)*288 + c0);
            floatx4 wa = *(const floatx4*)&wlds[tap*QTAPSTRIDE + wofs];
            floatx4 wb = *(const floatx4*)&wlds[tap*QTAPSTRIDE + wofs + 4];
            #pragma unroll
            for (int j=0;j<4;j++) acc[j]   = fmaf(wa[j], b2f((u16)v[j]),   acc[j]);
            #pragma unroll
            for (int j=0;j<4;j++) acc[4+j] = fmaf(wb[j], b2f((u16)v[4+j]), acc[4+j]);
        }
    }
    short8v o;
    #pragma unroll
    for (int j=0;j<8;j++) o[j] = (short)f2b(acc[j]);
    *(short8v*)(out + (size_t)pix*288 + c0) = o;
}

// ---------- Gram partials per (img,head,slice): G[12][12], |q|^2, |k|^2 ----------
__global__ __launch_bounds__(256) void gram_k(const u16* __restrict__ QKVd,
                                              float* __restrict__ part)
{
    int bh = blockIdx.x;        // NB*8: img*8+h
    int slice = blockIdx.y;     // 16 (1024 pixels each)
    int img = bh >> 3, h = bh & 7;
    int qbase = h*12, kbase = 96 + h*12;
    const u16* base = QKVd + (size_t)img*HW*288;
    __shared__ float qs[64][12];
    __shared__ float ks[64][12];
    int t = threadIdx.x;
    float acc = 0.f;
    int c = (t<144) ? t/12 : (t<156 ? t-144 : t-156);
    int d = (t<144) ? t%12 : 0;
    for (int st=0; st<16; st++){
        int pix0 = slice*1024 + st*64;
        __syncthreads();
        for (int i=t; i<64*24; i+=256){
            int p = i/24, cc = i%24;
            float v = b2f(base[(size_t)(pix0 + p)*288 + (cc<12 ? qbase+cc : kbase+cc-12)]);
            if (cc<12) qs[p][cc]=v; else ks[p][cc-12]=v;
        }
        __syncthreads();
        if (t<144){        for (int p=0;p<64;p++) acc = fmaf(qs[p][c], ks[p][d], acc); }
        else if (t<156){   for (int p=0;p<64;p++) acc = fmaf(qs[p][c], qs[p][c], acc); }
        else if (t<168){   for (int p=0;p<64;p++) acc = fmaf(ks[p][c], ks[p][c], acc); }
    }
    if (t<168) part[((size_t)bh*16 + slice)*168 + t] = acc;
}

__global__ __launch_bounds__(256) void gram_combine_k(const float* __restrict__ part,
                                                      float* __restrict__ gram, int n)
{
    int i = blockIdx.x*256 + threadIdx.x;
    if (i >= n) return;
    int bh = i/168, t = i%168;
    float s = 0.f;
    for (int sl=0; sl<16; sl++) s += part[((size_t)bh*16+sl)*168 + t];
    gram[i] = s;
}

// ---------- attn 12x12: normalize, temperature, top-k mask, softmax ----------
__global__ __launch_bounds__(256) void attn_k(const float* __restrict__ gram,
    const float* __restrict__ temp, const float* __restrict__ dynk_p,
    const float* __restrict__ a1, const float* __restrict__ a2,
    const float* __restrict__ a3, const float* __restrict__ a4,
    float* __restrict__ attnW)
{
    int bh = blockIdx.x;   // NB*8: img*8+h
    int h = bh & 7;
    __shared__ float av[12][12];
    __shared__ float mv[12][12];
    __shared__ float nq[12], nk[12];
    int t = threadIdx.x;
    if (t < 12) nq[t] = fmaxf(sqrtf(gram[bh*168+144+t]), 1e-12f);
    else if (t < 24) nk[t-12] = fmaxf(sqrtf(gram[bh*168+156+(t-12)]), 1e-12f);
    __syncthreads();
    if (t < 144){
        int c=t/12, d=t%12;
        av[c][d] = gram[bh*168+t] / (nq[c]*nk[d]) * temp[h];
    }
    __syncthreads();
    float dk = *dynk_p;
    if (t < 144){
        int c=t/12, d=t%12; float v = av[c][d];
        int r = 0;
        #pragma unroll
        for (int j=0;j<12;j++){
            float o = av[c][j];
            r += (o > v) ? 1 : ((o == v && j < d) ? 1 : 0);
        }
        mv[c][d] = ((float)r < dk) ? v : -INFINITY;
    }
    __syncthreads();
    if (t < 12){
        float mx = -INFINITY;
        for (int d2=0; d2<12; d2++) mx = fmaxf(mx, mv[t][d2]);
        float e[12]; float s = 0.f;
        for (int d2=0; d2<12; d2++){ e[d2] = expf(mv[t][d2]-mx); s += e[d2]; }
        float sc = (a1[0]+a2[0]+a3[0]+a4[0]) / s;
        for (int d2=0; d2<12; d2++) attnW[(size_t)bh*144 + t*12 + d2] = e[d2]*sc;
    }
}

// ---------- attn apply + concat x2 -> P bf16 ----------
__global__ __launch_bounds__(256) void attn_apply_k(const u16* __restrict__ QKVd,
    const u16* __restrict__ Y, const float* __restrict__ attnW, u16* __restrict__ P)
{
    int idx = blockIdx.x*256 + threadIdx.x;          // NB*HW*192
    int c = idx % 192; size_t pix = (size_t)(idx / 192);
    int img = (int)(pix >> 14);
    u16 outv;
    if (c < 96){
        int h = c/12, cc = c%12;
        const u16* vr = QKVd + pix*288 + 192 + h*12;
        const float* aw = attnW + ((size_t)(img*8+h))*144 + cc*12;
        float s = 0.f;
        #pragma unroll
        for (int d=0; d<12; d++) s += aw[d]*b2f(vr[d]);
        outv = f2b(s);
    } else {
        outv = Y[pix*192 + c];
    }
    P[idx] = outv;
}

// ---------- FFN multi-scale depthwise, row-sweep, one kernel per scale group ----------
// block = one (row, 64-ch group); threads: ci = t&7 (8-ch slice), seg = t>>3 (4 cols each)
// each input column is loaded & converted ONCE and scatter-fma'd into all covered outputs
template<int KS>
__global__ __launch_bounds__(256) void ffn_dw_g(const u16* __restrict__ V0,
    const float* __restrict__ wsrc, const float* __restrict__ bsrc, int cbase,
    const float* __restrict__ bn2g, const float* __restrict__ bn2b,
    const float* __restrict__ bn2m, const float* __restrict__ bn2v,
    u16* __restrict__ U)
{
    constexpr int PAD = KS/2;
    __shared__ float wlds[KS*KS*64];
    __shared__ float bng[64], bnb[64], bnm[64], bnvr[64];
    int t = threadIdx.x;
    for (int i=t; i<KS*KS*64; i+=256){
        int tap = i >> 6, cc = i & 63;
        wlds[tap*64 + cc] = wsrc[cc*KS*KS + tap];
    }
    if (t < 64){
        bng[t] = bn2g[cbase+t]; bnb[t] = bn2b[cbase+t];
        bnm[t] = bn2m[cbase+t]; bnvr[t] = rsqrtf(bn2v[cbase+t]+1e-5f);
    }
    __syncthreads();
    int ci = t & 7, seg = t >> 3;
    int rowid = blockIdx.x;                 // rows in chunk
    int img = rowid >> 7, hy = rowid & 127;
    int c0r = ci*8;
    int c0 = cbase + c0r;
    int x0 = seg*4;
    float acc[4][8];
    {
        floatx4 b0 = *(const floatx4*)(bsrc + c0r);
        floatx4 b1 = *(const floatx4*)(bsrc + c0r + 4);
        #pragma unroll
        for (int dx=0;dx<4;dx++){
            #pragma unroll
            for (int j=0;j<4;j++){ acc[dx][j]=b0[j]; acc[dx][4+j]=b1[j]; }
        }
    }
    #pragma unroll
    for (int ky=0; ky<KS; ky++){
        int hh = hy + ky - PAD;
        if ((unsigned)hh >= HH) continue;
        float wr[KS][8];
        #pragma unroll
        for (int kx=0; kx<KS; kx++){
            floatx4 wa = *(const floatx4*)&wlds[(ky*KS+kx)*64 + c0r];
            floatx4 wb = *(const floatx4*)&wlds[(ky*KS+kx)*64 + c0r + 4];
            #pragma unroll
            for (int j=0;j<4;j++){ wr[kx][j]=wa[j]; wr[kx][4+j]=wb[j]; }
        }
        const u16* rowp = V0 + ((size_t)(img*HH+hh)*WW)*256 + c0;
        #pragma unroll
        for (int cc=0; cc<4+2*PAD; cc++){
            int cx = x0 - PAD + cc;
            if ((unsigned)cx >= WW) continue;
            short8v v = *(const short8v*)(rowp + (size_t)cx*256);
            float vf[8];
            #pragma unroll
            for (int j=0;j<8;j++) vf[j] = b2f((u16)v[j]);
            #pragma unroll
            for (int dx=0; dx<4; dx++){
                constexpr int dummy = 0; (void)dummy;
                int kx = cc - dx;
                if (kx < 0 || kx >= KS) continue;   // compile-time folds per (cc,dx)
                #pragma unroll
                for (int j=0;j<8;j++) acc[dx][j] = fmaf(wr[kx][j], vf[j], acc[dx][j]);
            }
        }
    }
    // epilogue: +v0, gelu, bn2, *v0
    size_t rbase = (size_t)(img*HH+hy)*WW;
    #pragma unroll
    for (int dx=0; dx<4; dx++){
        size_t pix = rbase + x0 + dx;
        short8v vc = *(const short8v*)(V0 + pix*256 + c0);
        short8v o;
        #pragma unroll
        for (int j=0;j<8;j++){
            float v0c = b2f((u16)vc[j]);
            float u1 = acc[dx][j] + v0c;
            float gl = gelu_exact(u1);
            float bn = (gl - bnm[c0r+j])*bnvr[c0r+j]*bng[c0r+j] + bnb[c0r+j];
            o[j] = (short)f2b(bn*v0c);
        }
        *(short8v*)(U + pix*256 + c0) = o;
    }
}

extern "C" void kernel_launch(void* const* d_in, const int* in_sizes, int n_in,
                              void* d_out, int out_size, void* d_ws, size_t ws_size,
                              hipStream_t stream)
{
    const float* x     = (const float*)d_in[0];
    const float* pos_w = (const float*)d_in[1];
    const float* pos_b = (const float*)d_in[2];
    const float* ln1g  = (const float*)d_in[3];
    const float* ln1b  = (const float*)d_in[4];
    const float* temp  = (const float*)d_in[5];
    const float* qkvw  = (const float*)d_in[6];
    const float* qkvdw = (const float*)d_in[7];
    const float* projw = (const float*)d_in[8];
    const float* gw1   = (const float*)d_in[9];
    const float* gb1   = (const float*)d_in[10];
    const float* gw2   = (const float*)d_in[11];
    const float* gb2   = (const float*)d_in[12];
    const float* a1    = (const float*)d_in[13];
    const float* a2    = (const float*)d_in[14];
    const float* a3    = (const float*)d_in[15];
    const float* a4    = (const float*)d_in[16];
    const float* ln2g  = (const float*)d_in[17];
    const float* ln2b  = (const float*)d_in[18];
    const float* fc1w  = (const float*)d_in[19];
    const float* bn1g  = (const float*)d_in[20];
    const float* bn1b  = (const float*)d_in[21];
    const float* bn1m  = (const float*)d_in[22];
    const float* bn1v  = (const float*)d_in[23];
    const float* bn2g  = (const float*)d_in[24];
    const float* bn2b  = (const float*)d_in[25];
    const float* bn2m  = (const float*)d_in[26];
    const float* bn2v  = (const float*)d_in[27];
    const float* fc2w  = (const float*)d_in[28];
    const float* bn3g  = (const float*)d_in[29];
    const float* bn3b  = (const float*)d_in[30];
    const float* bn3m  = (const float*)d_in[31];
    const float* bn3v  = (const float*)d_in[32];
    const float* dw0w  = (const float*)d_in[33];
    const float* dw0b  = (const float*)d_in[34];
    const float* dw1w  = (const float*)d_in[35];
    const float* dw1b  = (const float*)d_in[36];
    const float* dw2w  = (const float*)d_in[37];
    const float* dw2b  = (const float*)d_in[38];
    const float* dw3w  = (const float*)d_in[39];
    const float* dw3b  = (const float*)d_in[40];

    float* OUT = (float*)d_out;      // residual stream (fp32)

    // ---- fixed small buffers ----
    char* p = (char*)d_ws;
    float* gpix  = (float*)p;                 p += (size_t)NPIX*4;
    float* dynk  = (float*)p;                 p += 256;
    float* gpart = (float*)p;                 p += 64*16*168*4;
    float* gram  = (float*)p;                 p += 64*168*4;
    float* attnW = (float*)p;                 p += 64*144*4;
    u16*   wbf   = (u16*)p;                   p += (size_t)WTOT*2;
    size_t fixedB = (size_t)(p - (char*)d_ws);

    // ---- choose chunk size from ws_size: per-image 31.5 MB ----
    size_t perImg = (size_t)HW*2*(192+288+288+192);
    int CBr = 2;
    if (ws_size >= fixedB + 8*perImg) CBr = 8;
    else if (ws_size >= fixedB + 4*perImg) CBr = 4;
    int NCHUNKr = BB/CBr;
    size_t CHWr = (size_t)CBr*HW;

    u16* Ybf   = (u16*)p;                   p += CHWr*192*2;
    u16* QKVbf = (u16*)p;                   p += CHWr*288*2;
    u16* QKVdbf= (u16*)p;                   p += CHWr*288*2;
    u16* Pbf   = (u16*)p;
    u16* qkvwb = wbf;
    u16* projwb= wbf + WQ;
    u16* gw1b  = wbf + WQ + WP;
    u16* fc1b  = wbf + WQ + WP + WG;
    u16* fc2b  = wbf + WQ + WP + WG + WF1;
    u16* G1bf  = QKVbf;
    u16* Zbf   = Pbf;
    u16* V0bf  = QKVdbf;
    u16* Ubf   = QKVbf;

    wprep_k<<<(WTOT+255)/256, 256, 0, stream>>>(qkvw, projw, gw1, fc1w, fc2w, wbf);
    pos_conv_k<<<BB*HH*16*48/256, 256, 0, stream>>>(x, pos_w, pos_b, OUT);

    // gate phase
    for (int c=0; c<NCHUNKr; c++){
        const float* Ab = OUT + (size_t)c*CHWr*192;
        ln_k<<<CHWr/4, 256, 0, stream>>>(Ab, ln1g, ln1b, Ybf);
        dim3 g(CHWr/256, 2);
        gemm_bf16_k<GM_BIAS_RELU><<<g, 256, 0, stream>>>(Ybf, 192, gw1b, G1bf, 96,
            nullptr, 0, gb1, nullptr, nullptr, nullptr, 96, 192);
        gate2_k<<<CHWr/256, 256, 0, stream>>>(G1bf, gw2, gb2, gpix + (size_t)c*CHWr);
    }
    gate_reduce_k<<<1, 1024, 0, stream>>>(gpix, dynk);

    // main phase
    for (int c=0; c<NCHUNKr; c++){
        float* Ab = OUT + (size_t)c*CHWr*192;
        if (NCHUNKr > 1)   // single-chunk mode: Ybf from gate phase is still valid
            ln_k<<<CHWr/4, 256, 0, stream>>>(Ab, ln1g, ln1b, Ybf);
        {
            dim3 g(CHWr/256, 5);
            gemm_bf16_k<GM_NONE><<<g, 256, 0, stream>>>(Ybf, 192, qkvwb, QKVbf, 288,
                nullptr, 0, nullptr,nullptr,nullptr,nullptr, 288, 96);
        }
        qkv_dw_k<<<CHWr*36/256, 256, 0, stream>>>(QKVbf, qkvdw, QKVdbf);
        { dim3 g(CBr*8, 16); gram_k<<<g, 256, 0, stream>>>(QKVdbf, gpart); }
        gram_combine_k<<<(CBr*8*168+255)/256, 256, 0, stream>>>(gpart, gram, CBr*8*168);
        attn_k<<<CBr*8, 256, 0, stream>>>(gram, temp, dynk, a1,a2,a3,a4, attnW);
        attn_apply_k<<<CHWr*192/256, 256, 0, stream>>>(QKVdbf, Ybf, attnW, Pbf);
        {
            dim3 g(CHWr/256, 3);
            gemm_bf16_k<GM_RES><<<g, 256, 0, stream>>>(Pbf, 192, projwb, Ab, 192,
                Ab, 192, nullptr,nullptr,nullptr,nullptr, 192, 192);
        }
        ln_k<<<CHWr/4, 256, 0, stream>>>(Ab, ln2g, ln2b, Zbf);
        {
            dim3 g(CHWr/256, 4);
            gemm_bf16_k<GM_GELU_BN><<<g, 256, 0, stream>>>(Zbf, 192, fc1b, V0bf, 256,
                nullptr, 0, bn1g,bn1b,bn1m,bn1v, 256, 192);
        }
        int rows = (int)(CHWr/WW);
        ffn_dw_g<1><<<rows, 256, 0, stream>>>(V0bf, dw0w, dw0b, 0,
            bn2g,bn2b,bn2m,bn2v, Ubf);
        ffn_dw_g<3><<<rows, 256, 0, stream>>>(V0bf, dw1w, dw1b, 64,
            bn2g,bn2b,bn2m,bn2v, Ubf);
        ffn_dw_g<5><<<rows, 256, 0, stream>>>(V0bf, dw2w, dw2b, 128,
            bn2g,bn2b,bn2m,bn2v, Ubf);
        ffn_dw_g<7><<<rows, 256, 0, stream>>>(V0bf, dw3w, dw3b, 192,
            bn2g,bn2b,bn2m,bn2v, Ubf);
        {
            dim3 g(CHWr/256, 3);
            gemm_bf16_k<GM_BN_RES><<<g, 256, 0, stream>>>(Ubf, 256, fc2b, Ab, 192,
                Ab, 192, bn3g,bn3b,bn3m,bn3v, 192, 256);
        }
    }
}

// Round 8
// 795.892 us; speedup vs baseline: 4.1088x; 1.1170x over previous
//
#include <hip/hip_runtime.h>
#include <hip/hip_bf16.h>
#include <math.h>

#define BB 8
#define HH 128
#define WW 128
#define HW (HH*WW)          // 16384
#define NPIX (BB*HW)        // 131072

typedef unsigned short u16;
typedef __attribute__((ext_vector_type(4))) float  floatx4;
typedef __attribute__((ext_vector_type(4))) short  short4v;
typedef __attribute__((ext_vector_type(8))) short  short8v;

static __device__ __forceinline__ float gelu_exact(float x){
    return 0.5f*x*(1.0f+erff(x*0.70710678118654752440f));
}
static __device__ __forceinline__ float b2f(u16 v){
    union { unsigned u; float f; } x; x.u = ((unsigned)v)<<16; return x.f;
}
static __device__ __forceinline__ u16 f2b(float f){
    __hip_bfloat16 h = __float2bfloat16(f);
    return *(u16*)&h;
}

// ---------- weight prep: fp32 -> bf16 for the five GEMM weight matrices ----------
#define WQ 27648
#define WP 36864
#define WG 18432
#define WF1 49152
#define WF2 49152
#define WTOT (WQ+WP+WG+WF1+WF2)   // 181248
__global__ __launch_bounds__(256) void wprep_k(const float* __restrict__ a,
    const float* __restrict__ b, const float* __restrict__ c,
    const float* __restrict__ d, const float* __restrict__ e, u16* __restrict__ o)
{
    int i = blockIdx.x*256 + threadIdx.x;
    if (i >= WTOT) return;
    float v;
    if (i < WQ) v = a[i];
    else if (i < WQ+WP) v = b[i-WQ];
    else if (i < WQ+WP+WG) v = c[i-WQ-WP];
    else if (i < WQ+WP+WG+WF1) v = d[i-WQ-WP-WG];
    else v = e[i-WQ-WP-WG-WF1];
    o[i] = f2b(v);
}

// ---------- pos depthwise 3x3 + bias + residual, 8-col segments (16/row) ----------
__global__ __launch_bounds__(256) void pos_conv_k(const float* __restrict__ x,
    const float* __restrict__ w, const float* __restrict__ bias, float* __restrict__ out)
{
    int gid = blockIdx.x*256 + threadIdx.x;     // ((b*HH+hy)*16 + seg)*48 + c4
    int c4 = gid % 48; int rest = gid / 48;
    int seg = rest & 15; rest >>= 4;
    int hy = rest % HH; int b = rest / HH;
    int c0 = c4*4;
    float wr[3][3][4];
    #pragma unroll
    for (int j=0;j<4;j++)
        #pragma unroll
        for (int ky=0;ky<3;ky++)
            #pragma unroll
            for (int kx=0;kx<3;kx++)
                wr[ky][kx][j] = w[(c0+j)*9 + ky*3 + kx];
    float4 bias4 = *(const float4*)(bias + c0);
    const float4* x4 = (const float4*)x;
    const float4* r0 = x4 + ((size_t)(b*HH + hy-1)*WW)*48 + c4;
    const float4* r1 = x4 + ((size_t)(b*HH + hy  )*WW)*48 + c4;
    const float4* r2 = x4 + ((size_t)(b*HH + hy+1)*WW)*48 + c4;
    bool v0 = hy > 0, v2 = hy < HH-1;
    float4 z4 = make_float4(0.f,0.f,0.f,0.f);
    int s0 = seg*8;
    float4 cA[3], cB[3], cC[3], cN[3];
    bool la = s0 > 0;
    cA[0] = (v0&&la) ? r0[(size_t)(s0-1)*48] : z4;
    cA[1] = la ? r1[(size_t)(s0-1)*48] : z4;
    cA[2] = (v2&&la) ? r2[(size_t)(s0-1)*48] : z4;
    cB[0] = v0 ? r0[(size_t)s0*48] : z4;  cB[1] = r1[(size_t)s0*48];  cB[2] = v2 ? r2[(size_t)s0*48] : z4;
    cC[0] = v0 ? r0[(size_t)(s0+1)*48] : z4; cC[1] = r1[(size_t)(s0+1)*48]; cC[2] = v2 ? r2[(size_t)(s0+1)*48] : z4;
    float4* o4 = (float4*)out + ((size_t)(b*HH + hy)*WW)*48 + c4;
    for (int i2=0; i2<8; i2++){
        int wx = s0 + i2;
        bool okc = (wx+2) < WW;
        size_t noff = (size_t)(wx+2)*48;
        cN[0] = (v0 && okc) ? r0[noff] : z4;
        cN[1] = okc ? r1[noff] : z4;
        cN[2] = (v2 && okc) ? r2[noff] : z4;
        float4 acc = bias4;
        #pragma unroll
        for (int i=0;i<3;i++){
            acc.x = fmaf(wr[i][0][0], cA[i].x, acc.x);
            acc.y = fmaf(wr[i][0][1], cA[i].y, acc.y);
            acc.z = fmaf(wr[i][0][2], cA[i].z, acc.z);
            acc.w = fmaf(wr[i][0][3], cA[i].w, acc.w);
            acc.x = fmaf(wr[i][1][0], cB[i].x, acc.x);
            acc.y = fmaf(wr[i][1][1], cB[i].y, acc.y);
            acc.z = fmaf(wr[i][1][2], cB[i].z, acc.z);
            acc.w = fmaf(wr[i][1][3], cB[i].w, acc.w);
            acc.x = fmaf(wr[i][2][0], cC[i].x, acc.x);
            acc.y = fmaf(wr[i][2][1], cC[i].y, acc.y);
            acc.z = fmaf(wr[i][2][2], cC[i].z, acc.z);
            acc.w = fmaf(wr[i][2][3], cC[i].w, acc.w);
        }
        acc.x += cB[1].x; acc.y += cB[1].y; acc.z += cB[1].z; acc.w += cB[1].w;
        o4[(size_t)wx*48] = acc;
        #pragma unroll
        for (int i=0;i<3;i++){ cA[i]=cB[i]; cB[i]=cC[i]; cC[i]=cN[i]; }
    }
}

// ---------- LayerNorm over C=192 fp32 in -> bf16 out, wave per pixel ----------
__global__ __launch_bounds__(256) void ln_k(const float* __restrict__ in,
    const float* __restrict__ g, const float* __restrict__ bta, u16* __restrict__ out)
{
    int wid = threadIdx.x >> 6, lane = threadIdx.x & 63;
    size_t pix = (size_t)blockIdx.x*4 + wid;
    const float* row = in + pix*192;
    float x0 = row[lane], x1 = row[lane+64], x2 = row[lane+128];
    float s = x0+x1+x2;
    float q = x0*x0 + x1*x1 + x2*x2;
    #pragma unroll
    for (int off=32; off; off>>=1){ s += __shfl_xor(s,off,64); q += __shfl_xor(q,off,64); }
    float mean = s*(1.f/192.f);
    float var  = q*(1.f/192.f) - mean*mean;
    float inv  = rsqrtf(var + 1e-6f);
    u16* orow = out + pix*192;
    orow[lane]     = f2b((x0-mean)*inv*g[lane]     + bta[lane]);
    orow[lane+64]  = f2b((x1-mean)*inv*g[lane+64]  + bta[lane+64]);
    orow[lane+128] = f2b((x2-mean)*inv*g[lane+128] + bta[lane+128]);
}

// ---------- bf16 MFMA GEMM v2: W-in-LDS once, A streamed from global ----------
// block 256 thr = 4 waves; tile M=256 (64 rows/wave) x N=64 (full, 4 n-frags)
// K compile-time (96/192/256): K-loop fully unrolled, NO barriers in loop.
#define GM_NONE 0
#define GM_RES 1
#define GM_GELU_BN 2
#define GM_BN_RES 3
#define GM_BIAS_RELU 4
#define WSTR 264   // LDS row stride in shorts: 528B = 132 dw; 132%32=4 -> 2-way only

template<int MODE, int K>
__global__ __launch_bounds__(256) void gemm_bf16_k(
    const u16* __restrict__ A, int lda,
    const u16* __restrict__ W,
    void* __restrict__ Cv, int ldc,
    const float* __restrict__ R, int ldr,
    const float* __restrict__ bg, const float* __restrict__ bb,
    const float* __restrict__ bm_, const float* __restrict__ bv,
    int N)
{
    __shared__ u16 Ws[64*WSTR];
    int t = threadIdx.x;
    int bn = blockIdx.x * 64;
    int bm = blockIdx.y * 256;
    {   // stage W rows bn..bn+63, full K, once
        constexpr int KQ = K/4;     // 24/48/64, multiple of 8
        int brow = t >> 2, bq = t & 3;
        int n = bn + brow;
        bool nv = n < N;
        const u16* src = W + (size_t)n*K + bq*KQ;
        #pragma unroll
        for (int j=0; j<KQ; j+=8){
            short8v v = {};
            if (nv) v = *(const short8v*)(src + j);
            *(short8v*)&Ws[brow*WSTR + bq*KQ + j] = v;
        }
    }
    __syncthreads();
    int wave = t >> 6, lane = t & 63;
    int wm = wave*64;
    int lr = lane & 15, lk = lane >> 4;
    const u16* arow = A + (size_t)(bm + wm + lr)*lda + lk*8;
    floatx4 acc[4][4] = {};
    #pragma unroll
    for (int k0 = 0; k0 < K; k0 += 32){
        short8v afr[4];
        #pragma unroll
        for (int m=0;m<4;m++)
            afr[m] = *(const short8v*)(arow + (size_t)(m*16)*lda + k0);
        #pragma unroll
        for (int n2=0;n2<4;n2++){
            short8v bfr = *(const short8v*)&Ws[(n2*16+lr)*WSTR + k0 + lk*8];
            #pragma unroll
            for (int m=0;m<4;m++)
                acc[m][n2] = __builtin_amdgcn_mfma_f32_16x16x32_bf16(afr[m], bfr, acc[m][n2], 0,0,0);
        }
    }
    // epilogue: C/D frag layout col=lane&15, row=(lane>>4)*4+reg
    #pragma unroll
    for (int m=0;m<4;m++){
        #pragma unroll
        for (int n2=0;n2<4;n2++){
            int gcol = bn + n2*16 + lr;
            if (gcol >= N) continue;
            #pragma unroll
            for (int rg=0; rg<4; rg++){
                int grow = bm + wm + m*16 + lk*4 + rg;
                float v = acc[m][n2][rg];
                if (MODE == GM_RES){
                    v += R[(size_t)grow*ldr + gcol];
                    ((float*)Cv)[(size_t)grow*ldc + gcol] = v;
                } else if (MODE == GM_BN_RES){
                    float bnv = (v - bm_[gcol])*rsqrtf(bv[gcol]+1e-5f)*bg[gcol] + bb[gcol];
                    ((float*)Cv)[(size_t)grow*ldc + gcol] = bnv + R[(size_t)grow*ldr + gcol];
                } else if (MODE == GM_GELU_BN){
                    float gl = gelu_exact(v);
                    v = (gl - bm_[gcol])*rsqrtf(bv[gcol]+1e-5f)*bg[gcol] + bb[gcol];
                    ((u16*)Cv)[(size_t)grow*ldc + gcol] = f2b(v);
                } else if (MODE == GM_BIAS_RELU){
                    ((u16*)Cv)[(size_t)grow*ldc + gcol] = f2b(fmaxf(v + bg[gcol], 0.f));
                } else {
                    ((u16*)Cv)[(size_t)grow*ldc + gcol] = f2b(v);
                }
            }
        }
    }
}

// ---------- gate stage 2: sigmoid(G1 @ w2 + b2) per pixel, G1 bf16 ----------
__global__ __launch_bounds__(256) void gate2_k(const u16* __restrict__ G1,
    const float* __restrict__ w2, const float* __restrict__ b2, float* __restrict__ gpix)
{
    int pix = blockIdx.x*256 + threadIdx.x;
    const short4v* g4 = (const short4v*)(G1 + (size_t)pix*96);
    const float4* w4 = (const float4*)w2;
    float s = b2[0];
    #pragma unroll
    for (int j=0;j<24;j++){
        short4v g = g4[j]; float4 w = w4[j];
        s += b2f((u16)g.x)*w.x + b2f((u16)g.y)*w.y + b2f((u16)g.z)*w.z + b2f((u16)g.w)*w.w;
    }
    gpix[pix] = 1.f/(1.f+expf(-s));
}

// ---------- deterministic mean of gpix -> dyn_k ----------
__global__ __launch_bounds__(1024) void gate_reduce_k(const float* __restrict__ gpix,
                                                      float* __restrict__ dynk)
{
    __shared__ float sm[16];
    float s = 0.f;
    for (int i=threadIdx.x; i<NPIX; i+=1024) s += gpix[i];
    #pragma unroll
    for (int off=32; off; off>>=1) s += __shfl_xor(s,off,64);
    int wid = threadIdx.x>>6, lane = threadIdx.x&63;
    if (lane==0) sm[wid]=s;
    __syncthreads();
    if (threadIdx.x==0){
        float tot=0.f; for (int i=0;i<16;i++) tot+=sm[i];
        *dynk = floorf(12.0f * (tot/(float)NPIX));
    }
}

// ---------- qkv depthwise 3x3 (288 ch), bf16, 8-ch vectorized + LDS weights ----------
#define QPOS(c8) ((c8)*8 + ((c8)>>2)*4)
#define QTAPSTRIDE 324
__global__ __launch_bounds__(256) void qkv_dw_k(const u16* __restrict__ in,
    const float* __restrict__ w, u16* __restrict__ out)
{
    __shared__ float wlds[9*QTAPSTRIDE];
    int t = threadIdx.x;
    for (int i=t; i<2592; i+=256){
        int tap = i/288, cc = i%288;
        wlds[tap*QTAPSTRIDE + QPOS(cc>>3) + (cc&7)] = w[cc*9+tap];
    }
    __syncthreads();
    int idx = blockIdx.x*256 + t;          // over NB*HW*36
    int c8 = idx % 36; int pix = idx / 36;
    int wx = pix % WW; int hy = (pix / WW) % HH; int img = pix / HW;
    int c0 = c8*8;
    int wofs = QPOS(c8);
    float acc[8] = {};
    #pragma unroll
    for (int ky=0; ky<3; ky++){
        int hh = hy + ky - 1; if ((unsigned)hh >= HH) continue;
        #pragma unroll
        for (int kx=0; kx<3; kx++){
            int ww2 = wx + kx - 1; if ((unsigned)ww2 >= WW) continue;
            int tap = ky*3+kx;
            short8v v = *(const short8v*)(in + ((size_t)(img*HH+hh)*WW+ww2)*288 + c0);
            floatx4 wa = *(const floatx4*)&wlds[tap*QTAPSTRIDE + wofs];
            floatx4 wb = *(const floatx4*)&wlds[tap*QTAPSTRIDE + wofs + 4];
            #pragma unroll
            for (int j=0;j<4;j++) acc[j]   = fmaf(wa[j], b2f((u16)v[j]),   acc[j]);
            #pragma unroll
            for (int j=0;j<4;j++) acc[4+j] = fmaf(wb[j], b2f((u16)v[4+j]), acc[4+j]);
        }
    }
    short8v o;
    #pragma unroll
    for (int j=0;j<8;j++) o[j] = (short)f2b(acc[j]);
    *(short8v*)(out + (size_t)pix*288 + c0) = o;
}

// ---------- Gram partials per (img,head,slice): G[12][12], |q|^2, |k|^2 ----------
__global__ __launch_bounds__(256) void gram_k(const u16* __restrict__ QKVd,
                                              float* __restrict__ part)
{
    int bh = blockIdx.x;        // NB*8: img*8+h
    int slice = blockIdx.y;     // 16 (1024 pixels each)
    int img = bh >> 3, h = bh & 7;
    int qbase = h*12, kbase = 96 + h*12;
    const u16* base = QKVd + (size_t)img*HW*288;
    __shared__ float qs[64][12];
    __shared__ float ks[64][12];
    int t = threadIdx.x;
    float acc = 0.f;
    int c = (t<144) ? t/12 : (t<156 ? t-144 : t-156);
    int d = (t<144) ? t%12 : 0;
    for (int st=0; st<16; st++){
        int pix0 = slice*1024 + st*64;
        __syncthreads();
        for (int i=t; i<64*24; i+=256){
            int p = i/24, cc = i%24;
            float v = b2f(base[(size_t)(pix0 + p)*288 + (cc<12 ? qbase+cc : kbase+cc-12)]);
            if (cc<12) qs[p][cc]=v; else ks[p][cc-12]=v;
        }
        __syncthreads();
        if (t<144){        for (int p=0;p<64;p++) acc = fmaf(qs[p][c], ks[p][d], acc); }
        else if (t<156){   for (int p=0;p<64;p++) acc = fmaf(qs[p][c], qs[p][c], acc); }
        else if (t<168){   for (int p=0;p<64;p++) acc = fmaf(ks[p][c], ks[p][c], acc); }
    }
    if (t<168) part[((size_t)bh*16 + slice)*168 + t] = acc;
}

__global__ __launch_bounds__(256) void gram_combine_k(const float* __restrict__ part,
                                                      float* __restrict__ gram, int n)
{
    int i = blockIdx.x*256 + threadIdx.x;
    if (i >= n) return;
    int bh = i/168, t = i%168;
    float s = 0.f;
    for (int sl=0; sl<16; sl++) s += part[((size_t)bh*16+sl)*168 + t];
    gram[i] = s;
}

// ---------- attn 12x12: normalize, temperature, top-k mask, softmax ----------
__global__ __launch_bounds__(256) void attn_k(const float* __restrict__ gram,
    const float* __restrict__ temp, const float* __restrict__ dynk_p,
    const float* __restrict__ a1, const float* __restrict__ a2,
    const float* __restrict__ a3, const float* __restrict__ a4,
    float* __restrict__ attnW)
{
    int bh = blockIdx.x;   // NB*8: img*8+h
    int h = bh & 7;
    __shared__ float av[12][12];
    __shared__ float mv[12][12];
    __shared__ float nq[12], nk[12];
    int t = threadIdx.x;
    if (t < 12) nq[t] = fmaxf(sqrtf(gram[bh*168+144+t]), 1e-12f);
    else if (t < 24) nk[t-12] = fmaxf(sqrtf(gram[bh*168+156+(t-12)]), 1e-12f);
    __syncthreads();
    if (t < 144){
        int c=t/12, d=t%12;
        av[c][d] = gram[bh*168+t] / (nq[c]*nk[d]) * temp[h];
    }
    __syncthreads();
    float dk = *dynk_p;
    if (t < 144){
        int c=t/12, d=t%12; float v = av[c][d];
        int r = 0;
        #pragma unroll
        for (int j=0;j<12;j++){
            float o = av[c][j];
            r += (o > v) ? 1 : ((o == v && j < d) ? 1 : 0);
        }
        mv[c][d] = ((float)r < dk) ? v : -INFINITY;
    }
    __syncthreads();
    if (t < 12){
        float mx = -INFINITY;
        for (int d2=0; d2<12; d2++) mx = fmaxf(mx, mv[t][d2]);
        float e[12]; float s = 0.f;
        for (int d2=0; d2<12; d2++){ e[d2] = expf(mv[t][d2]-mx); s += e[d2]; }
        float sc = (a1[0]+a2[0]+a3[0]+a4[0]) / s;
        for (int d2=0; d2<12; d2++) attnW[(size_t)bh*144 + t*12 + d2] = e[d2]*sc;
    }
}

// ---------- attn apply + concat x2 -> P bf16 ----------
__global__ __launch_bounds__(256) void attn_apply_k(const u16* __restrict__ QKVd,
    const u16* __restrict__ Y, const float* __restrict__ attnW, u16* __restrict__ P)
{
    int idx = blockIdx.x*256 + threadIdx.x;          // NB*HW*192
    int c = idx % 192; size_t pix = (size_t)(idx / 192);
    int img = (int)(pix >> 14);
    u16 outv;
    if (c < 96){
        int h = c/12, cc = c%12;
        const u16* vr = QKVd + pix*288 + 192 + h*12;
        const float* aw = attnW + ((size_t)(img*8+h))*144 + cc*12;
        float s = 0.f;
        #pragma unroll
        for (int d=0; d<12; d++) s += aw[d]*b2f(vr[d]);
        outv = f2b(s);
    } else {
        outv = Y[pix*192 + c];
    }
    P[idx] = outv;
}

// ---------- FFN multi-scale depthwise, row-sweep, one kernel per scale group ----------
template<int KS>
__global__ __launch_bounds__(256) void ffn_dw_g(const u16* __restrict__ V0,
    const float* __restrict__ wsrc, const float* __restrict__ bsrc, int cbase,
    const float* __restrict__ bn2g, const float* __restrict__ bn2b,
    const float* __restrict__ bn2m, const float* __restrict__ bn2v,
    u16* __restrict__ U)
{
    constexpr int PAD = KS/2;
    __shared__ float wlds[KS*KS*64];
    __shared__ float bng[64], bnb[64], bnm[64], bnvr[64];
    int t = threadIdx.x;
    for (int i=t; i<KS*KS*64; i+=256){
        int tap = i >> 6, cc = i & 63;
        wlds[tap*64 + cc] = wsrc[cc*KS*KS + tap];
    }
    if (t < 64){
        bng[t] = bn2g[cbase+t]; bnb[t] = bn2b[cbase+t];
        bnm[t] = bn2m[cbase+t]; bnvr[t] = rsqrtf(bn2v[cbase+t]+1e-5f);
    }
    __syncthreads();
    int ci = t & 7, seg = t >> 3;
    int rowid = blockIdx.x;
    int img = rowid >> 7, hy = rowid & 127;
    int c0r = ci*8;
    int c0 = cbase + c0r;
    int x0 = seg*4;
    float acc[4][8];
    {
        floatx4 b0 = *(const floatx4*)(bsrc + c0r);
        floatx4 b1 = *(const floatx4*)(bsrc + c0r + 4);
        #pragma unroll
        for (int dx=0;dx<4;dx++){
            #pragma unroll
            for (int j=0;j<4;j++){ acc[dx][j]=b0[j]; acc[dx][4+j]=b1[j]; }
        }
    }
    #pragma unroll
    for (int ky=0; ky<KS; ky++){
        int hh = hy + ky - PAD;
        if ((unsigned)hh >= HH) continue;
        float wr[KS][8];
        #pragma unroll
        for (int kx=0; kx<KS; kx++){
            floatx4 wa = *(const floatx4*)&wlds[(ky*KS+kx)*64 + c0r];
            floatx4 wb = *(const floatx4*)&wlds[(ky*KS+kx)*64 + c0r + 4];
            #pragma unroll
            for (int j=0;j<4;j++){ wr[kx][j]=wa[j]; wr[kx][4+j]=wb[j]; }
        }
        const u16* rowp = V0 + ((size_t)(img*HH+hh)*WW)*256 + c0;
        #pragma unroll
        for (int cc=0; cc<4+2*PAD; cc++){
            int cx = x0 - PAD + cc;
            if ((unsigned)cx >= WW) continue;
            short8v v = *(const short8v*)(rowp + (size_t)cx*256);
            float vf[8];
            #pragma unroll
            for (int j=0;j<8;j++) vf[j] = b2f((u16)v[j]);
            #pragma unroll
            for (int dx=0; dx<4; dx++){
                int kx = cc - dx;
                if (kx < 0 || kx >= KS) continue;
                #pragma unroll
                for (int j=0;j<8;j++) acc[dx][j] = fmaf(wr[kx][j], vf[j], acc[dx][j]);
            }
        }
    }
    size_t rbase = (size_t)(img*HH+hy)*WW;
    #pragma unroll
    for (int dx=0; dx<4; dx++){
        size_t pix = rbase + x0 + dx;
        short8v vc = *(const short8v*)(V0 + pix*256 + c0);
        short8v o;
        #pragma unroll
        for (int j=0;j<8;j++){
            float v0c = b2f((u16)vc[j]);
            float u1 = acc[dx][j] + v0c;
            float gl = gelu_exact(u1);
            float bn = (gl - bnm[c0r+j])*bnvr[c0r+j]*bng[c0r+j] + bnb[c0r+j];
            o[j] = (short)f2b(bn*v0c);
        }
        *(short8v*)(U + pix*256 + c0) = o;
    }
}

extern "C" void kernel_launch(void* const* d_in, const int* in_sizes, int n_in,
                              void* d_out, int out_size, void* d_ws, size_t ws_size,
                              hipStream_t stream)
{
    const float* x     = (const float*)d_in[0];
    const float* pos_w = (const float*)d_in[1];
    const float* pos_b = (const float*)d_in[2];
    const float* ln1g  = (const float*)d_in[3];
    const float* ln1b  = (const float*)d_in[4];
    const float* temp  = (const float*)d_in[5];
    const float* qkvw  = (const float*)d_in[6];
    const float* qkvdw = (const float*)d_in[7];
    const float* projw = (const float*)d_in[8];
    const float* gw1   = (const float*)d_in[9];
    const float* gb1   = (const float*)d_in[10];
    const float* gw2   = (const float*)d_in[11];
    const float* gb2   = (const float*)d_in[12];
    const float* a1    = (const float*)d_in[13];
    const float* a2    = (const float*)d_in[14];
    const float* a3    = (const float*)d_in[15];
    const float* a4    = (const float*)d_in[16];
    const float* ln2g  = (const float*)d_in[17];
    const float* ln2b  = (const float*)d_in[18];
    const float* fc1w  = (const float*)d_in[19];
    const float* bn1g  = (const float*)d_in[20];
    const float* bn1b  = (const float*)d_in[21];
    const float* bn1m  = (const float*)d_in[22];
    const float* bn1v  = (const float*)d_in[23];
    const float* bn2g  = (const float*)d_in[24];
    const float* bn2b  = (const float*)d_in[25];
    const float* bn2m  = (const float*)d_in[26];
    const float* bn2v  = (const float*)d_in[27];
    const float* fc2w  = (const float*)d_in[28];
    const float* bn3g  = (const float*)d_in[29];
    const float* bn3b  = (const float*)d_in[30];
    const float* bn3m  = (const float*)d_in[31];
    const float* bn3v  = (const float*)d_in[32];
    const float* dw0w  = (const float*)d_in[33];
    const float* dw0b  = (const float*)d_in[34];
    const float* dw1w  = (const float*)d_in[35];
    const float* dw1b  = (const float*)d_in[36];
    const float* dw2w  = (const float*)d_in[37];
    const float* dw2b  = (const float*)d_in[38];
    const float* dw3w  = (const float*)d_in[39];
    const float* dw3b  = (const float*)d_in[40];

    float* OUT = (float*)d_out;      // residual stream (fp32)

    // ---- fixed small buffers ----
    char* p = (char*)d_ws;
    float* gpix  = (float*)p;                 p += (size_t)NPIX*4;
    float* dynk  = (float*)p;                 p += 256;
    float* gpart = (float*)p;                 p += 64*16*168*4;
    float* gram  = (float*)p;                 p += 64*168*4;
    float* attnW = (float*)p;                 p += 64*144*4;
    u16*   wbf   = (u16*)p;                   p += (size_t)WTOT*2;
    size_t fixedB = (size_t)(p - (char*)d_ws);

    // ---- choose chunk size from ws_size: per-image 31.5 MB ----
    size_t perImg = (size_t)HW*2*(192+288+288+192);
    int CBr = 2;
    if (ws_size >= fixedB + 8*perImg) CBr = 8;
    else if (ws_size >= fixedB + 4*perImg) CBr = 4;
    int NCHUNKr = BB/CBr;
    size_t CHWr = (size_t)CBr*HW;

    u16* Ybf   = (u16*)p;                   p += CHWr*192*2;
    u16* QKVbf = (u16*)p;                   p += CHWr*288*2;
    u16* QKVdbf= (u16*)p;                   p += CHWr*288*2;
    u16* Pbf   = (u16*)p;
    u16* qkvwb = wbf;
    u16* projwb= wbf + WQ;
    u16* gw1b  = wbf + WQ + WP;
    u16* fc1b  = wbf + WQ + WP + WG;
    u16* fc2b  = wbf + WQ + WP + WG + WF1;
    u16* G1bf  = QKVbf;
    u16* Zbf   = Pbf;
    u16* V0bf  = QKVdbf;
    u16* Ubf   = QKVbf;

    wprep_k<<<(WTOT+255)/256, 256, 0, stream>>>(qkvw, projw, gw1, fc1w, fc2w, wbf);
    pos_conv_k<<<BB*HH*16*48/256, 256, 0, stream>>>(x, pos_w, pos_b, OUT);

    // gate phase
    for (int c=0; c<NCHUNKr; c++){
        const float* Ab = OUT + (size_t)c*CHWr*192;
        ln_k<<<CHWr/4, 256, 0, stream>>>(Ab, ln1g, ln1b, Ybf);
        dim3 g(2, CHWr/256);
        gemm_bf16_k<GM_BIAS_RELU,192><<<g, 256, 0, stream>>>(Ybf, 192, gw1b, G1bf, 96,
            nullptr, 0, gb1, nullptr, nullptr, nullptr, 96);
        gate2_k<<<CHWr/256, 256, 0, stream>>>(G1bf, gw2, gb2, gpix + (size_t)c*CHWr);
    }
    gate_reduce_k<<<1, 1024, 0, stream>>>(gpix, dynk);

    // main phase
    for (int c=0; c<NCHUNKr; c++){
        float* Ab = OUT + (size_t)c*CHWr*192;
        if (NCHUNKr > 1)   // single-chunk mode: Ybf from gate phase is still valid
            ln_k<<<CHWr/4, 256, 0, stream>>>(Ab, ln1g, ln1b, Ybf);
        {
            dim3 g(5, CHWr/256);
            gemm_bf16_k<GM_NONE,96><<<g, 256, 0, stream>>>(Ybf, 192, qkvwb, QKVbf, 288,
                nullptr, 0, nullptr,nullptr,nullptr,nullptr, 288);
        }
        qkv_dw_k<<<CHWr*36/256, 256, 0, stream>>>(QKVbf, qkvdw, QKVdbf);
        { dim3 g(CBr*8, 16); gram_k<<<g, 256, 0, stream>>>(QKVdbf, gpart); }
        gram_combine_k<<<(CBr*8*168+255)/256, 256, 0, stream>>>(gpart, gram, CBr*8*168);
        attn_k<<<CBr*8, 256, 0, stream>>>(gram, temp, dynk, a1,a2,a3,a4, attnW);
        attn_apply_k<<<CHWr*192/256, 256, 0, stream>>>(QKVdbf, Ybf, attnW, Pbf);
        {
            dim3 g(3, CHWr/256);
            gemm_bf16_k<GM_RES,192><<<g, 256, 0, stream>>>(Pbf, 192, projwb, Ab, 192,
                Ab, 192, nullptr,nullptr,nullptr,nullptr, 192);
        }
        ln_k<<<CHWr/4, 256, 0, stream>>>(Ab, ln2g, ln2b, Zbf);
        {
            dim3 g(4, CHWr/256);
            gemm_bf16_k<GM_GELU_BN,192><<<g, 256, 0, stream>>>(Zbf, 192, fc1b, V0bf, 256,
                nullptr, 0, bn1g,bn1b,bn1m,bn1v, 256);
        }
        int rows = (int)(CHWr/WW);
        ffn_dw_g<1><<<rows, 256, 0, stream>>>(V0bf, dw0w, dw0b, 0,
            bn2g,bn2b,bn2m,bn2v, Ubf);
        ffn_dw_g<3><<<rows, 256, 0, stream>>>(V0bf, dw1w, dw1b, 64,
            bn2g,bn2b,bn2m,bn2v, Ubf);
        ffn_dw_g<5><<<rows, 256, 0, stream>>>(V0bf, dw2w, dw2b, 128,
            bn2g,bn2b,bn2m,bn2v, Ubf);
        ffn_dw_g<7><<<rows, 256, 0, stream>>>(V0bf, dw3w, dw3b, 192,
            bn2g,bn2b,bn2m,bn2v, Ubf);
        {
            dim3 g(3, CHWr/256);
            gemm_bf16_k<GM_BN_RES,256><<<g, 256, 0, stream>>>(Ubf, 256, fc2b, Ab, 192,
                Ab, 192, bn3g,bn3b,bn3m,bn3v, 192);
        }
    }
}

// Round 9
// 735.796 us; speedup vs baseline: 4.4444x; 1.0817x over previous
//
#include <hip/hip_runtime.h>
#include <hip/hip_bf16.h>
#include <math.h>

#define BB 8
#define HH 128
#define WW 128
#define HW (HH*WW)          // 16384
#define NPIX (BB*HW)        // 131072

typedef unsigned short u16;
typedef __attribute__((ext_vector_type(4))) float  floatx4;
typedef __attribute__((ext_vector_type(4))) short  short4v;
typedef __attribute__((ext_vector_type(8))) short  short8v;

static __device__ __forceinline__ float gelu_exact(float x){
    return 0.5f*x*(1.0f+erff(x*0.70710678118654752440f));
}
static __device__ __forceinline__ float b2f(u16 v){
    union { unsigned u; float f; } x; x.u = ((unsigned)v)<<16; return x.f;
}
static __device__ __forceinline__ u16 f2b(float f){
    __hip_bfloat16 h = __float2bfloat16(f);
    return *(u16*)&h;
}

// ---------- weight prep: fp32 -> bf16 for the five GEMM weight matrices ----------
#define WQ 27648
#define WP 36864
#define WG 18432
#define WF1 49152
#define WF2 49152
#define WTOT (WQ+WP+WG+WF1+WF2)   // 181248
__global__ __launch_bounds__(256) void wprep_k(const float* __restrict__ a,
    const float* __restrict__ b, const float* __restrict__ c,
    const float* __restrict__ d, const float* __restrict__ e, u16* __restrict__ o)
{
    int i = blockIdx.x*256 + threadIdx.x;
    if (i >= WTOT) return;
    float v;
    if (i < WQ) v = a[i];
    else if (i < WQ+WP) v = b[i-WQ];
    else if (i < WQ+WP+WG) v = c[i-WQ-WP];
    else if (i < WQ+WP+WG+WF1) v = d[i-WQ-WP-WG];
    else v = e[i-WQ-WP-WG-WF1];
    o[i] = f2b(v);
}

// ---------- pos depthwise 3x3 + bias + residual, 8-col segments, XCD-swizzled ----------
__global__ __launch_bounds__(256) void pos_conv_k(const float* __restrict__ x,
    const float* __restrict__ w, const float* __restrict__ bias, float* __restrict__ out)
{
    int bid = blockIdx.x;
    int sb = (bid & 7)*(gridDim.x >> 3) + (bid >> 3);   // each XCD owns contiguous slice
    int gid = sb*256 + threadIdx.x;     // ((b*HH+hy)*16 + seg)*48 + c4
    int c4 = gid % 48; int rest = gid / 48;
    int seg = rest & 15; rest >>= 4;
    int hy = rest % HH; int b = rest / HH;
    int c0 = c4*4;
    float wr[3][3][4];
    #pragma unroll
    for (int j=0;j<4;j++)
        #pragma unroll
        for (int ky=0;ky<3;ky++)
            #pragma unroll
            for (int kx=0;kx<3;kx++)
                wr[ky][kx][j] = w[(c0+j)*9 + ky*3 + kx];
    float4 bias4 = *(const float4*)(bias + c0);
    const float4* x4 = (const float4*)x;
    const float4* r0 = x4 + ((size_t)(b*HH + hy-1)*WW)*48 + c4;
    const float4* r1 = x4 + ((size_t)(b*HH + hy  )*WW)*48 + c4;
    const float4* r2 = x4 + ((size_t)(b*HH + hy+1)*WW)*48 + c4;
    bool v0 = hy > 0, v2 = hy < HH-1;
    float4 z4 = make_float4(0.f,0.f,0.f,0.f);
    int s0 = seg*8;
    float4 cA[3], cB[3], cC[3], cN[3];
    bool la = s0 > 0;
    cA[0] = (v0&&la) ? r0[(size_t)(s0-1)*48] : z4;
    cA[1] = la ? r1[(size_t)(s0-1)*48] : z4;
    cA[2] = (v2&&la) ? r2[(size_t)(s0-1)*48] : z4;
    cB[0] = v0 ? r0[(size_t)s0*48] : z4;  cB[1] = r1[(size_t)s0*48];  cB[2] = v2 ? r2[(size_t)s0*48] : z4;
    cC[0] = v0 ? r0[(size_t)(s0+1)*48] : z4; cC[1] = r1[(size_t)(s0+1)*48]; cC[2] = v2 ? r2[(size_t)(s0+1)*48] : z4;
    float4* o4 = (float4*)out + ((size_t)(b*HH + hy)*WW)*48 + c4;
    for (int i2=0; i2<8; i2++){
        int wx = s0 + i2;
        bool okc = (wx+2) < WW;
        size_t noff = (size_t)(wx+2)*48;
        cN[0] = (v0 && okc) ? r0[noff] : z4;
        cN[1] = okc ? r1[noff] : z4;
        cN[2] = (v2 && okc) ? r2[noff] : z4;
        float4 acc = bias4;
        #pragma unroll
        for (int i=0;i<3;i++){
            acc.x = fmaf(wr[i][0][0], cA[i].x, acc.x);
            acc.y = fmaf(wr[i][0][1], cA[i].y, acc.y);
            acc.z = fmaf(wr[i][0][2], cA[i].z, acc.z);
            acc.w = fmaf(wr[i][0][3], cA[i].w, acc.w);
            acc.x = fmaf(wr[i][1][0], cB[i].x, acc.x);
            acc.y = fmaf(wr[i][1][1], cB[i].y, acc.y);
            acc.z = fmaf(wr[i][1][2], cB[i].z, acc.z);
            acc.w = fmaf(wr[i][1][3], cB[i].w, acc.w);
            acc.x = fmaf(wr[i][2][0], cC[i].x, acc.x);
            acc.y = fmaf(wr[i][2][1], cC[i].y, acc.y);
            acc.z = fmaf(wr[i][2][2], cC[i].z, acc.z);
            acc.w = fmaf(wr[i][2][3], cC[i].w, acc.w);
        }
        acc.x += cB[1].x; acc.y += cB[1].y; acc.z += cB[1].z; acc.w += cB[1].w;
        o4[(size_t)wx*48] = acc;
        #pragma unroll
        for (int i=0;i<3;i++){ cA[i]=cB[i]; cB[i]=cC[i]; cC[i]=cN[i]; }
    }
}

// ---------- LayerNorm over C=192 fp32 in -> bf16 out, wave per pixel ----------
__global__ __launch_bounds__(256) void ln_k(const float* __restrict__ in,
    const float* __restrict__ g, const float* __restrict__ bta, u16* __restrict__ out)
{
    int wid = threadIdx.x >> 6, lane = threadIdx.x & 63;
    size_t pix = (size_t)blockIdx.x*4 + wid;
    const float* row = in + pix*192;
    float x0 = row[lane], x1 = row[lane+64], x2 = row[lane+128];
    float s = x0+x1+x2;
    float q = x0*x0 + x1*x1 + x2*x2;
    #pragma unroll
    for (int off=32; off; off>>=1){ s += __shfl_xor(s,off,64); q += __shfl_xor(q,off,64); }
    float mean = s*(1.f/192.f);
    float var  = q*(1.f/192.f) - mean*mean;
    float inv  = rsqrtf(var + 1e-6f);
    u16* orow = out + pix*192;
    orow[lane]     = f2b((x0-mean)*inv*g[lane]     + bta[lane]);
    orow[lane+64]  = f2b((x1-mean)*inv*g[lane+64]  + bta[lane+64]);
    orow[lane+128] = f2b((x2-mean)*inv*g[lane+128] + bta[lane+128]);
}

// ---------- bf16 MFMA GEMM v2: W-in-LDS once, A streamed from global ----------
#define GM_NONE 0
#define GM_RES 1
#define GM_GELU_BN 2
#define GM_BN_RES 3
#define GM_BIAS_RELU 4
#define WSTR 264   // LDS row stride in shorts: 528B = 132 dw; 132%32=4 -> 2-way only

template<int MODE, int K>
__global__ __launch_bounds__(256) void gemm_bf16_k(
    const u16* __restrict__ A, int lda,
    const u16* __restrict__ W,
    void* __restrict__ Cv, int ldc,
    const float* __restrict__ R, int ldr,
    const float* __restrict__ bg, const float* __restrict__ bb,
    const float* __restrict__ bm_, const float* __restrict__ bv,
    int N)
{
    __shared__ u16 Ws[64*WSTR];
    int t = threadIdx.x;
    int bn = blockIdx.x * 64;
    int bm = blockIdx.y * 256;
    {
        constexpr int KQ = K/4;
        int brow = t >> 2, bq = t & 3;
        int n = bn + brow;
        bool nv = n < N;
        const u16* src = W + (size_t)n*K + bq*KQ;
        #pragma unroll
        for (int j=0; j<KQ; j+=8){
            short8v v = {};
            if (nv) v = *(const short8v*)(src + j);
            *(short8v*)&Ws[brow*WSTR + bq*KQ + j] = v;
        }
    }
    __syncthreads();
    int wave = t >> 6, lane = t & 63;
    int wm = wave*64;
    int lr = lane & 15, lk = lane >> 4;
    const u16* arow = A + (size_t)(bm + wm + lr)*lda + lk*8;
    floatx4 acc[4][4] = {};
    #pragma unroll
    for (int k0 = 0; k0 < K; k0 += 32){
        short8v afr[4];
        #pragma unroll
        for (int m=0;m<4;m++)
            afr[m] = *(const short8v*)(arow + (size_t)(m*16)*lda + k0);
        #pragma unroll
        for (int n2=0;n2<4;n2++){
            short8v bfr = *(const short8v*)&Ws[(n2*16+lr)*WSTR + k0 + lk*8];
            #pragma unroll
            for (int m=0;m<4;m++)
                acc[m][n2] = __builtin_amdgcn_mfma_f32_16x16x32_bf16(afr[m], bfr, acc[m][n2], 0,0,0);
        }
    }
    #pragma unroll
    for (int m=0;m<4;m++){
        #pragma unroll
        for (int n2=0;n2<4;n2++){
            int gcol = bn + n2*16 + lr;
            if (gcol >= N) continue;
            #pragma unroll
            for (int rg=0; rg<4; rg++){
                int grow = bm + wm + m*16 + lk*4 + rg;
                float v = acc[m][n2][rg];
                if (MODE == GM_RES){
                    v += R[(size_t)grow*ldr + gcol];
                    ((float*)Cv)[(size_t)grow*ldc + gcol] = v;
                } else if (MODE == GM_BN_RES){
                    float bnv = (v - bm_[gcol])*rsqrtf(bv[gcol]+1e-5f)*bg[gcol] + bb[gcol];
                    ((float*)Cv)[(size_t)grow*ldc + gcol] = bnv + R[(size_t)grow*ldr + gcol];
                } else if (MODE == GM_GELU_BN){
                    float gl = gelu_exact(v);
                    v = (gl - bm_[gcol])*rsqrtf(bv[gcol]+1e-5f)*bg[gcol] + bb[gcol];
                    ((u16*)Cv)[(size_t)grow*ldc + gcol] = f2b(v);
                } else if (MODE == GM_BIAS_RELU){
                    ((u16*)Cv)[(size_t)grow*ldc + gcol] = f2b(fmaxf(v + bg[gcol], 0.f));
                } else {
                    ((u16*)Cv)[(size_t)grow*ldc + gcol] = f2b(v);
                }
            }
        }
    }
}

// ---------- gate stage 2: sigmoid(G1 @ w2 + b2) per pixel, G1 bf16 ----------
__global__ __launch_bounds__(256) void gate2_k(const u16* __restrict__ G1,
    const float* __restrict__ w2, const float* __restrict__ b2, float* __restrict__ gpix)
{
    int pix = blockIdx.x*256 + threadIdx.x;
    const short4v* g4 = (const short4v*)(G1 + (size_t)pix*96);
    const float4* w4 = (const float4*)w2;
    float s = b2[0];
    #pragma unroll
    for (int j=0;j<24;j++){
        short4v g = g4[j]; float4 w = w4[j];
        s += b2f((u16)g.x)*w.x + b2f((u16)g.y)*w.y + b2f((u16)g.z)*w.z + b2f((u16)g.w)*w.w;
    }
    gpix[pix] = 1.f/(1.f+expf(-s));
}

// ---------- deterministic mean of gpix -> dyn_k ----------
__global__ __launch_bounds__(1024) void gate_reduce_k(const float* __restrict__ gpix,
                                                      float* __restrict__ dynk)
{
    __shared__ float sm[16];
    float s = 0.f;
    for (int i=threadIdx.x; i<NPIX; i+=1024) s += gpix[i];
    #pragma unroll
    for (int off=32; off; off>>=1) s += __shfl_xor(s,off,64);
    int wid = threadIdx.x>>6, lane = threadIdx.x&63;
    if (lane==0) sm[wid]=s;
    __syncthreads();
    if (threadIdx.x==0){
        float tot=0.f; for (int i=0;i<16;i++) tot+=sm[i];
        *dynk = floorf(12.0f * (tot/(float)NPIX));
    }
}

// ---------- qkv depthwise 3x3 (288 ch), 2-col sweep, LDS weights, XCD-swizzled ----------
#define QPOS(c8) ((c8)*8 + ((c8)>>2)*4)
#define QTAPSTRIDE 324
__global__ __launch_bounds__(256) void qkv_dw_k(const u16* __restrict__ in,
    const float* __restrict__ w, u16* __restrict__ out)
{
    __shared__ float wlds[9*QTAPSTRIDE];
    int t = threadIdx.x;
    for (int i=t; i<2592; i+=256){
        int tap = i/288, cc = i%288;
        wlds[tap*QTAPSTRIDE + QPOS(cc>>3) + (cc&7)] = w[cc*9+tap];
    }
    __syncthreads();
    int bid = blockIdx.x;
    int sb = (bid & 7)*(gridDim.x >> 3) + (bid >> 3);
    int idx = sb*256 + t;                  // over NB*HW*18 (col pairs x 36 groups)
    int c8 = idx % 36; int px2 = idx / 36;
    int wp = px2 & 63; int hy = (px2 >> 6) & 127; int img = px2 >> 13;
    int wx0 = wp*2;
    int c0 = c8*8;
    int wofs = QPOS(c8);
    float acc0[8] = {}, acc1[8] = {};
    #pragma unroll
    for (int ky=0; ky<3; ky++){
        int hh = hy + ky - 1; if ((unsigned)hh >= HH) continue;
        const u16* rowp = in + ((size_t)(img*HH+hh)*WW)*288 + c0;
        #pragma unroll
        for (int cc=0; cc<4; cc++){
            int cx = wx0 - 1 + cc;
            if ((unsigned)cx >= WW) continue;
            short8v v = *(const short8v*)(rowp + (size_t)cx*288);
            float vf[8];
            #pragma unroll
            for (int j=0;j<8;j++) vf[j] = b2f((u16)v[j]);
            if (cc < 3){
                floatx4 wa = *(const floatx4*)&wlds[(ky*3+cc)*QTAPSTRIDE + wofs];
                floatx4 wb = *(const floatx4*)&wlds[(ky*3+cc)*QTAPSTRIDE + wofs + 4];
                #pragma unroll
                for (int j=0;j<4;j++){ acc0[j]   = fmaf(wa[j], vf[j],   acc0[j]);
                                       acc0[4+j] = fmaf(wb[j], vf[4+j], acc0[4+j]); }
            }
            if (cc >= 1){
                floatx4 wa = *(const floatx4*)&wlds[(ky*3+cc-1)*QTAPSTRIDE + wofs];
                floatx4 wb = *(const floatx4*)&wlds[(ky*3+cc-1)*QTAPSTRIDE + wofs + 4];
                #pragma unroll
                for (int j=0;j<4;j++){ acc1[j]   = fmaf(wa[j], vf[j],   acc1[j]);
                                       acc1[4+j] = fmaf(wb[j], vf[4+j], acc1[4+j]); }
            }
        }
    }
    size_t pix0 = (size_t)(img*HH+hy)*WW + wx0;
    short8v o0, o1;
    #pragma unroll
    for (int j=0;j<8;j++){ o0[j] = (short)f2b(acc0[j]); o1[j] = (short)f2b(acc1[j]); }
    *(short8v*)(out + pix0*288 + c0) = o0;
    *(short8v*)(out + (pix0+1)*288 + c0) = o1;
}

// ---------- Gram partials per (img,head,slice), vectorized staging ----------
__global__ __launch_bounds__(256) void gram_k(const u16* __restrict__ QKVd,
                                              float* __restrict__ part)
{
    int bh = blockIdx.x;        // NB*8: img*8+h
    int slice = blockIdx.y;     // 16 (1024 pixels each)
    int img = bh >> 3, h = bh & 7;
    int qbase = h*12, kbase = 96 + h*12;
    const u16* base = QKVd + (size_t)img*HW*288;
    __shared__ float qs[64][12];
    __shared__ float ks[64][12];
    int t = threadIdx.x;
    float acc = 0.f;
    int c = (t<144) ? t/12 : (t<156 ? t-144 : t-156);
    int d = (t<144) ? t%12 : 0;
    for (int st=0; st<16; st++){
        int pix0 = slice*1024 + st*64;
        __syncthreads();
        for (int i=t; i<384; i+=256){
            int p = i/6, j = i%6;
            const u16* src = base + (size_t)(pix0+p)*288 + (j<3 ? qbase + j*4 : kbase + (j-3)*4);
            short4v v = *(const short4v*)src;
            float f0=b2f((u16)v.x), f1=b2f((u16)v.y), f2=b2f((u16)v.z), f3=b2f((u16)v.w);
            if (j<3){ int jj=j*4;     qs[p][jj]=f0; qs[p][jj+1]=f1; qs[p][jj+2]=f2; qs[p][jj+3]=f3; }
            else    { int jj=(j-3)*4; ks[p][jj]=f0; ks[p][jj+1]=f1; ks[p][jj+2]=f2; ks[p][jj+3]=f3; }
        }
        __syncthreads();
        if (t<144){        for (int p=0;p<64;p++) acc = fmaf(qs[p][c], ks[p][d], acc); }
        else if (t<156){   for (int p=0;p<64;p++) acc = fmaf(qs[p][c], qs[p][c], acc); }
        else if (t<168){   for (int p=0;p<64;p++) acc = fmaf(ks[p][c], ks[p][c], acc); }
    }
    if (t<168) part[((size_t)bh*16 + slice)*168 + t] = acc;
}

__global__ __launch_bounds__(256) void gram_combine_k(const float* __restrict__ part,
                                                      float* __restrict__ gram, int n)
{
    int i = blockIdx.x*256 + threadIdx.x;
    if (i >= n) return;
    int bh = i/168, t = i%168;
    float s = 0.f;
    for (int sl=0; sl<16; sl++) s += part[((size_t)bh*16+sl)*168 + t];
    gram[i] = s;
}

// ---------- attn 12x12: normalize, temperature, top-k mask, softmax ----------
__global__ __launch_bounds__(256) void attn_k(const float* __restrict__ gram,
    const float* __restrict__ temp, const float* __restrict__ dynk_p,
    const float* __restrict__ a1, const float* __restrict__ a2,
    const float* __restrict__ a3, const float* __restrict__ a4,
    float* __restrict__ attnW)
{
    int bh = blockIdx.x;   // NB*8: img*8+h
    int h = bh & 7;
    __shared__ float av[12][12];
    __shared__ float mv[12][12];
    __shared__ float nq[12], nk[12];
    int t = threadIdx.x;
    if (t < 12) nq[t] = fmaxf(sqrtf(gram[bh*168+144+t]), 1e-12f);
    else if (t < 24) nk[t-12] = fmaxf(sqrtf(gram[bh*168+156+(t-12)]), 1e-12f);
    __syncthreads();
    if (t < 144){
        int c=t/12, d=t%12;
        av[c][d] = gram[bh*168+t] / (nq[c]*nk[d]) * temp[h];
    }
    __syncthreads();
    float dk = *dynk_p;
    if (t < 144){
        int c=t/12, d=t%12; float v = av[c][d];
        int r = 0;
        #pragma unroll
        for (int j=0;j<12;j++){
            float o = av[c][j];
            r += (o > v) ? 1 : ((o == v && j < d) ? 1 : 0);
        }
        mv[c][d] = ((float)r < dk) ? v : -INFINITY;
    }
    __syncthreads();
    if (t < 12){
        float mx = -INFINITY;
        for (int d2=0; d2<12; d2++) mx = fmaxf(mx, mv[t][d2]);
        float e[12]; float s = 0.f;
        for (int d2=0; d2<12; d2++){ e[d2] = expf(mv[t][d2]-mx); s += e[d2]; }
        float sc = (a1[0]+a2[0]+a3[0]+a4[0]) / s;
        for (int d2=0; d2<12; d2++) attnW[(size_t)bh*144 + t*12 + d2] = e[d2]*sc;
    }
}

// ---------- attn apply + concat x2 -> P bf16; thread = (pixel, head|copy-group) ----------
__global__ __launch_bounds__(256) void attn_apply_k(const u16* __restrict__ QKVd,
    const u16* __restrict__ Y, const float* __restrict__ attnW, u16* __restrict__ P)
{
    int gid = blockIdx.x*256 + threadIdx.x;          // NB*HW*20
    int grp = gid % 20; size_t pix = (size_t)(gid / 20);
    if (grp >= 8){
        int c0 = 96 + (grp-8)*8;
        *(short8v*)(P + pix*192 + c0) = *(const short8v*)(Y + pix*192 + c0);
        return;
    }
    int img = (int)(pix >> 14);
    int h = grp;
    const u16* vp = QKVd + pix*288 + 192 + h*12;
    float vf[12];
    #pragma unroll
    for (int j=0;j<3;j++){
        short4v v = *(const short4v*)(vp + j*4);
        vf[j*4+0]=b2f((u16)v.x); vf[j*4+1]=b2f((u16)v.y);
        vf[j*4+2]=b2f((u16)v.z); vf[j*4+3]=b2f((u16)v.w);
    }
    const float* awb = attnW + ((size_t)(img*8+h))*144;
    u16 o[12];
    #pragma unroll
    for (int cc=0; cc<12; cc++){
        const float4* ap = (const float4*)(awb + cc*12);   // 48B stride -> 16B aligned
        float4 a0 = ap[0], a1 = ap[1], a2 = ap[2];
        float s = a0.x*vf[0] + a0.y*vf[1] + a0.z*vf[2] + a0.w*vf[3]
                + a1.x*vf[4] + a1.y*vf[5] + a1.z*vf[6] + a1.w*vf[7]
                + a2.x*vf[8] + a2.y*vf[9] + a2.z*vf[10]+ a2.w*vf[11];
        o[cc] = f2b(s);
    }
    u16* op = P + pix*192 + h*12;
    *(short4v*)(op)   = *(short4v*)&o[0];
    *(short4v*)(op+4) = *(short4v*)&o[4];
    *(short4v*)(op+8) = *(short4v*)&o[8];
}

// ---------- FFN multi-scale depthwise, row-sweep per scale, XCD-swizzled ----------
template<int KS>
__global__ __launch_bounds__(256) void ffn_dw_g(const u16* __restrict__ V0,
    const float* __restrict__ wsrc, const float* __restrict__ bsrc, int cbase,
    const float* __restrict__ bn2g, const float* __restrict__ bn2b,
    const float* __restrict__ bn2m, const float* __restrict__ bn2v,
    u16* __restrict__ U)
{
    constexpr int PAD = KS/2;
    __shared__ float wlds[KS*KS*64];
    __shared__ float bng[64], bnb[64], bnm[64], bnvr[64];
    int t = threadIdx.x;
    for (int i=t; i<KS*KS*64; i+=256){
        int tap = i >> 6, cc = i & 63;
        wlds[tap*64 + cc] = wsrc[cc*KS*KS + tap];
    }
    if (t < 64){
        bng[t] = bn2g[cbase+t]; bnb[t] = bn2b[cbase+t];
        bnm[t] = bn2m[cbase+t]; bnvr[t] = rsqrtf(bn2v[cbase+t]+1e-5f);
    }
    __syncthreads();
    int ci = t & 7, seg = t >> 3;
    int bid = blockIdx.x;
    int rowid = (bid & 7)*(gridDim.x >> 3) + (bid >> 3);
    int img = rowid >> 7, hy = rowid & 127;
    int c0r = ci*8;
    int c0 = cbase + c0r;
    int x0 = seg*4;
    float acc[4][8];
    {
        floatx4 b0 = *(const floatx4*)(bsrc + c0r);
        floatx4 b1 = *(const floatx4*)(bsrc + c0r + 4);
        #pragma unroll
        for (int dx=0;dx<4;dx++){
            #pragma unroll
            for (int j=0;j<4;j++){ acc[dx][j]=b0[j]; acc[dx][4+j]=b1[j]; }
        }
    }
    #pragma unroll
    for (int ky=0; ky<KS; ky++){
        int hh = hy + ky - PAD;
        if ((unsigned)hh >= HH) continue;
        float wr[KS][8];
        #pragma unroll
        for (int kx=0; kx<KS; kx++){
            floatx4 wa = *(const floatx4*)&wlds[(ky*KS+kx)*64 + c0r];
            floatx4 wb = *(const floatx4*)&wlds[(ky*KS+kx)*64 + c0r + 4];
            #pragma unroll
            for (int j=0;j<4;j++){ wr[kx][j]=wa[j]; wr[kx][4+j]=wb[j]; }
        }
        const u16* rowp = V0 + ((size_t)(img*HH+hh)*WW)*256 + c0;
        #pragma unroll
        for (int cc=0; cc<4+2*PAD; cc++){
            int cx = x0 - PAD + cc;
            if ((unsigned)cx >= WW) continue;
            short8v v = *(const short8v*)(rowp + (size_t)cx*256);
            float vf[8];
            #pragma unroll
            for (int j=0;j<8;j++) vf[j] = b2f((u16)v[j]);
            #pragma unroll
            for (int dx=0; dx<4; dx++){
                int kx = cc - dx;
                if (kx < 0 || kx >= KS) continue;
                #pragma unroll
                for (int j=0;j<8;j++) acc[dx][j] = fmaf(wr[kx][j], vf[j], acc[dx][j]);
            }
        }
    }
    size_t rbase = (size_t)(img*HH+hy)*WW;
    #pragma unroll
    for (int dx=0; dx<4; dx++){
        size_t pix = rbase + x0 + dx;
        short8v vc = *(const short8v*)(V0 + pix*256 + c0);
        short8v o;
        #pragma unroll
        for (int j=0;j<8;j++){
            float v0c = b2f((u16)vc[j]);
            float u1 = acc[dx][j] + v0c;
            float gl = gelu_exact(u1);
            float bn = (gl - bnm[c0r+j])*bnvr[c0r+j]*bng[c0r+j] + bnb[c0r+j];
            o[j] = (short)f2b(bn*v0c);
        }
        *(short8v*)(U + pix*256 + c0) = o;
    }
}

extern "C" void kernel_launch(void* const* d_in, const int* in_sizes, int n_in,
                              void* d_out, int out_size, void* d_ws, size_t ws_size,
                              hipStream_t stream)
{
    const float* x     = (const float*)d_in[0];
    const float* pos_w = (const float*)d_in[1];
    const float* pos_b = (const float*)d_in[2];
    const float* ln1g  = (const float*)d_in[3];
    const float* ln1b  = (const float*)d_in[4];
    const float* temp  = (const float*)d_in[5];
    const float* qkvw  = (const float*)d_in[6];
    const float* qkvdw = (const float*)d_in[7];
    const float* projw = (const float*)d_in[8];
    const float* gw1   = (const float*)d_in[9];
    const float* gb1   = (const float*)d_in[10];
    const float* gw2   = (const float*)d_in[11];
    const float* gb2   = (const float*)d_in[12];
    const float* a1    = (const float*)d_in[13];
    const float* a2    = (const float*)d_in[14];
    const float* a3    = (const float*)d_in[15];
    const float* a4    = (const float*)d_in[16];
    const float* ln2g  = (const float*)d_in[17];
    const float* ln2b  = (const float*)d_in[18];
    const float* fc1w  = (const float*)d_in[19];
    const float* bn1g  = (const float*)d_in[20];
    const float* bn1b  = (const float*)d_in[21];
    const float* bn1m  = (const float*)d_in[22];
    const float* bn1v  = (const float*)d_in[23];
    const float* bn2g  = (const float*)d_in[24];
    const float* bn2b  = (const float*)d_in[25];
    const float* bn2m  = (const float*)d_in[26];
    const float* bn2v  = (const float*)d_in[27];
    const float* fc2w  = (const float*)d_in[28];
    const float* bn3g  = (const float*)d_in[29];
    const float* bn3b  = (const float*)d_in[30];
    const float* bn3m  = (const float*)d_in[31];
    const float* bn3v  = (const float*)d_in[32];
    const float* dw0w  = (const float*)d_in[33];
    const float* dw0b  = (const float*)d_in[34];
    const float* dw1w  = (const float*)d_in[35];
    const float* dw1b  = (const float*)d_in[36];
    const float* dw2w  = (const float*)d_in[37];
    const float* dw2b  = (const float*)d_in[38];
    const float* dw3w  = (const float*)d_in[39];
    const float* dw3b  = (const float*)d_in[40];

    float* OUT = (float*)d_out;      // residual stream (fp32)

    // ---- fixed small buffers ----
    char* p = (char*)d_ws;
    float* gpix  = (float*)p;                 p += (size_t)NPIX*4;
    float* dynk  = (float*)p;                 p += 256;
    float* gpart = (float*)p;                 p += 64*16*168*4;
    float* gram  = (float*)p;                 p += 64*168*4;
    float* attnW = (float*)p;                 p += 64*144*4;
    u16*   wbf   = (u16*)p;                   p += (size_t)WTOT*2;
    size_t fixedB = (size_t)(p - (char*)d_ws);

    // ---- choose chunk size from ws_size: per-image 31.5 MB ----
    size_t perImg = (size_t)HW*2*(192+288+288+192);
    int CBr = 2;
    if (ws_size >= fixedB + 8*perImg) CBr = 8;
    else if (ws_size >= fixedB + 4*perImg) CBr = 4;
    int NCHUNKr = BB/CBr;
    size_t CHWr = (size_t)CBr*HW;

    u16* Ybf   = (u16*)p;                   p += CHWr*192*2;
    u16* QKVbf = (u16*)p;                   p += CHWr*288*2;
    u16* QKVdbf= (u16*)p;                   p += CHWr*288*2;
    u16* Pbf   = (u16*)p;
    u16* qkvwb = wbf;
    u16* projwb= wbf + WQ;
    u16* gw1b  = wbf + WQ + WP;
    u16* fc1b  = wbf + WQ + WP + WG;
    u16* fc2b  = wbf + WQ + WP + WG + WF1;
    u16* G1bf  = QKVbf;
    u16* Zbf   = Pbf;
    u16* V0bf  = QKVdbf;
    u16* Ubf   = QKVbf;

    wprep_k<<<(WTOT+255)/256, 256, 0, stream>>>(qkvw, projw, gw1, fc1w, fc2w, wbf);
    pos_conv_k<<<BB*HH*16*48/256, 256, 0, stream>>>(x, pos_w, pos_b, OUT);

    // gate phase
    for (int c=0; c<NCHUNKr; c++){
        const float* Ab = OUT + (size_t)c*CHWr*192;
        ln_k<<<CHWr/4, 256, 0, stream>>>(Ab, ln1g, ln1b, Ybf);
        dim3 g(2, CHWr/256);
        gemm_bf16_k<GM_BIAS_RELU,192><<<g, 256, 0, stream>>>(Ybf, 192, gw1b, G1bf, 96,
            nullptr, 0, gb1, nullptr, nullptr, nullptr, 96);
        gate2_k<<<CHWr/256, 256, 0, stream>>>(G1bf, gw2, gb2, gpix + (size_t)c*CHWr);
    }
    gate_reduce_k<<<1, 1024, 0, stream>>>(gpix, dynk);

    // main phase
    for (int c=0; c<NCHUNKr; c++){
        float* Ab = OUT + (size_t)c*CHWr*192;
        if (NCHUNKr > 1)   // single-chunk mode: Ybf from gate phase is still valid
            ln_k<<<CHWr/4, 256, 0, stream>>>(Ab, ln1g, ln1b, Ybf);
        {
            dim3 g(5, CHWr/256);
            gemm_bf16_k<GM_NONE,96><<<g, 256, 0, stream>>>(Ybf, 192, qkvwb, QKVbf, 288,
                nullptr, 0, nullptr,nullptr,nullptr,nullptr, 288);
        }
        qkv_dw_k<<<CHWr*18/256, 256, 0, stream>>>(QKVbf, qkvdw, QKVdbf);
        { dim3 g(CBr*8, 16); gram_k<<<g, 256, 0, stream>>>(QKVdbf, gpart); }
        gram_combine_k<<<(CBr*8*168+255)/256, 256, 0, stream>>>(gpart, gram, CBr*8*168);
        attn_k<<<CBr*8, 256, 0, stream>>>(gram, temp, dynk, a1,a2,a3,a4, attnW);
        attn_apply_k<<<CHWr*20/256, 256, 0, stream>>>(QKVdbf, Ybf, attnW, Pbf);
        {
            dim3 g(3, CHWr/256);
            gemm_bf16_k<GM_RES,192><<<g, 256, 0, stream>>>(Pbf, 192, projwb, Ab, 192,
                Ab, 192, nullptr,nullptr,nullptr,nullptr, 192);
        }
        ln_k<<<CHWr/4, 256, 0, stream>>>(Ab, ln2g, ln2b, Zbf);
        {
            dim3 g(4, CHWr/256);
            gemm_bf16_k<GM_GELU_BN,192><<<g, 256, 0, stream>>>(Zbf, 192, fc1b, V0bf, 256,
                nullptr, 0, bn1g,bn1b,bn1m,bn1v, 256);
        }
        int rows = (int)(CHWr/WW);
        ffn_dw_g<1><<<rows, 256, 0, stream>>>(V0bf, dw0w, dw0b, 0,
            bn2g,bn2b,bn2m,bn2v, Ubf);
        ffn_dw_g<3><<<rows, 256, 0, stream>>>(V0bf, dw1w, dw1b, 64,
            bn2g,bn2b,bn2m,bn2v, Ubf);
        ffn_dw_g<5><<<rows, 256, 0, stream>>>(V0bf, dw2w, dw2b, 128,
            bn2g,bn2b,bn2m,bn2v, Ubf);
        ffn_dw_g<7><<<rows, 256, 0, stream>>>(V0bf, dw3w, dw3b, 192,
            bn2g,bn2b,bn2m,bn2v, Ubf);
        {
            dim3 g(3, CHWr/256);
            gemm_bf16_k<GM_BN_RES,256><<<g, 256, 0, stream>>>(Ubf, 256, fc2b, Ab, 192,
                Ab, 192, bn3g,bn3b,bn3m,bn3v, 192);
        }
    }
}

// Round 10
// 655.489 us; speedup vs baseline: 4.9889x; 1.1225x over previous
//
#include <hip/hip_runtime.h>
#include <hip/hip_bf16.h>
#include <math.h>

#define BB 8
#define HH 128
#define WW 128
#define HW (HH*WW)          // 16384
#define NPIX (BB*HW)        // 131072

typedef unsigned short u16;
typedef __attribute__((ext_vector_type(4))) float  floatx4;
typedef __attribute__((ext_vector_type(4))) short  short4v;
typedef __attribute__((ext_vector_type(8))) short  short8v;

static __device__ __forceinline__ float gelu_exact(float x){
    return 0.5f*x*(1.0f+erff(x*0.70710678118654752440f));
}
static __device__ __forceinline__ float b2f(u16 v){
    union { unsigned u; float f; } x; x.u = ((unsigned)v)<<16; return x.f;
}
static __device__ __forceinline__ u16 f2b(float f){
    __hip_bfloat16 h = __float2bfloat16(f);
    return *(u16*)&h;
}

// ---------- weight prep: fp32 -> bf16 for the five GEMM weight matrices ----------
#define WQ 27648
#define WP 36864
#define WG 18432
#define WF1 49152
#define WF2 49152
#define WTOT (WQ+WP+WG+WF1+WF2)   // 181248
__global__ __launch_bounds__(256) void wprep_k(const float* __restrict__ a,
    const float* __restrict__ b, const float* __restrict__ c,
    const float* __restrict__ d, const float* __restrict__ e, u16* __restrict__ o)
{
    int i = blockIdx.x*256 + threadIdx.x;
    if (i >= WTOT) return;
    float v;
    if (i < WQ) v = a[i];
    else if (i < WQ+WP) v = b[i-WQ];
    else if (i < WQ+WP+WG) v = c[i-WQ-WP];
    else if (i < WQ+WP+WG+WF1) v = d[i-WQ-WP-WG];
    else v = e[i-WQ-WP-WG-WF1];
    o[i] = f2b(v);
}

// ---------- pos depthwise 3x3 + bias + residual -> bf16 A, XCD-swizzled ----------
__global__ __launch_bounds__(256) void pos_conv_k(const float* __restrict__ x,
    const float* __restrict__ w, const float* __restrict__ bias, u16* __restrict__ out)
{
    int bid = blockIdx.x;
    int sb = (bid & 7)*(gridDim.x >> 3) + (bid >> 3);   // each XCD owns contiguous slice
    int gid = sb*256 + threadIdx.x;     // ((b*HH+hy)*16 + seg)*48 + c4
    int c4 = gid % 48; int rest = gid / 48;
    int seg = rest & 15; rest >>= 4;
    int hy = rest % HH; int b = rest / HH;
    int c0 = c4*4;
    float wr[3][3][4];
    #pragma unroll
    for (int j=0;j<4;j++)
        #pragma unroll
        for (int ky=0;ky<3;ky++)
            #pragma unroll
            for (int kx=0;kx<3;kx++)
                wr[ky][kx][j] = w[(c0+j)*9 + ky*3 + kx];
    float4 bias4 = *(const float4*)(bias + c0);
    const float4* x4 = (const float4*)x;
    const float4* r0 = x4 + ((size_t)(b*HH + hy-1)*WW)*48 + c4;
    const float4* r1 = x4 + ((size_t)(b*HH + hy  )*WW)*48 + c4;
    const float4* r2 = x4 + ((size_t)(b*HH + hy+1)*WW)*48 + c4;
    bool v0 = hy > 0, v2 = hy < HH-1;
    float4 z4 = make_float4(0.f,0.f,0.f,0.f);
    int s0 = seg*8;
    float4 cA[3], cB[3], cC[3], cN[3];
    bool la = s0 > 0;
    cA[0] = (v0&&la) ? r0[(size_t)(s0-1)*48] : z4;
    cA[1] = la ? r1[(size_t)(s0-1)*48] : z4;
    cA[2] = (v2&&la) ? r2[(size_t)(s0-1)*48] : z4;
    cB[0] = v0 ? r0[(size_t)s0*48] : z4;  cB[1] = r1[(size_t)s0*48];  cB[2] = v2 ? r2[(size_t)s0*48] : z4;
    cC[0] = v0 ? r0[(size_t)(s0+1)*48] : z4; cC[1] = r1[(size_t)(s0+1)*48]; cC[2] = v2 ? r2[(size_t)(s0+1)*48] : z4;
    u16* orow = out + ((size_t)(b*HH + hy)*WW)*192 + c0;
    for (int i2=0; i2<8; i2++){
        int wx = s0 + i2;
        bool okc = (wx+2) < WW;
        size_t noff = (size_t)(wx+2)*48;
        cN[0] = (v0 && okc) ? r0[noff] : z4;
        cN[1] = okc ? r1[noff] : z4;
        cN[2] = (v2 && okc) ? r2[noff] : z4;
        float4 acc = bias4;
        #pragma unroll
        for (int i=0;i<3;i++){
            acc.x = fmaf(wr[i][0][0], cA[i].x, acc.x);
            acc.y = fmaf(wr[i][0][1], cA[i].y, acc.y);
            acc.z = fmaf(wr[i][0][2], cA[i].z, acc.z);
            acc.w = fmaf(wr[i][0][3], cA[i].w, acc.w);
            acc.x = fmaf(wr[i][1][0], cB[i].x, acc.x);
            acc.y = fmaf(wr[i][1][1], cB[i].y, acc.y);
            acc.z = fmaf(wr[i][1][2], cB[i].z, acc.z);
            acc.w = fmaf(wr[i][1][3], cB[i].w, acc.w);
            acc.x = fmaf(wr[i][2][0], cC[i].x, acc.x);
            acc.y = fmaf(wr[i][2][1], cC[i].y, acc.y);
            acc.z = fmaf(wr[i][2][2], cC[i].z, acc.z);
            acc.w = fmaf(wr[i][2][3], cC[i].w, acc.w);
        }
        acc.x += cB[1].x; acc.y += cB[1].y; acc.z += cB[1].z; acc.w += cB[1].w;
        short4v o; o.x=(short)f2b(acc.x); o.y=(short)f2b(acc.y);
        o.z=(short)f2b(acc.z); o.w=(short)f2b(acc.w);
        *(short4v*)(orow + (size_t)wx*192) = o;
        #pragma unroll
        for (int i=0;i<3;i++){ cA[i]=cB[i]; cB[i]=cC[i]; cC[i]=cN[i]; }
    }
}

// ---------- LayerNorm over C=192, bf16 in -> bf16 out, wave per pixel ----------
__global__ __launch_bounds__(256) void ln_k(const u16* __restrict__ in,
    const float* __restrict__ g, const float* __restrict__ bta, u16* __restrict__ out)
{
    int wid = threadIdx.x >> 6, lane = threadIdx.x & 63;
    size_t pix = (size_t)blockIdx.x*4 + wid;
    const u16* row = in + pix*192;
    float x0 = b2f(row[lane]), x1 = b2f(row[lane+64]), x2 = b2f(row[lane+128]);
    float s = x0+x1+x2;
    float q = x0*x0 + x1*x1 + x2*x2;
    #pragma unroll
    for (int off=32; off; off>>=1){ s += __shfl_xor(s,off,64); q += __shfl_xor(q,off,64); }
    float mean = s*(1.f/192.f);
    float var  = q*(1.f/192.f) - mean*mean;
    float inv  = rsqrtf(var + 1e-6f);
    u16* orow = out + pix*192;
    orow[lane]     = f2b((x0-mean)*inv*g[lane]     + bta[lane]);
    orow[lane+64]  = f2b((x1-mean)*inv*g[lane+64]  + bta[lane+64]);
    orow[lane+128] = f2b((x2-mean)*inv*g[lane+128] + bta[lane+128]);
}

// ---------- bf16 MFMA GEMM: W-in-LDS once, A streamed from global (optional 2-panel A) ----------
#define GM_NONE 0
#define GM_RES 1
#define GM_GELU_BN 2
#define GM_BN_RES 3
#define GM_BIAS_RELU 4
#define WSTR 264   // LDS row stride in shorts: 528B = 132 dw; 132%32=4 -> 2-way only

template<int MODE, int K, bool SPLIT=false>
__global__ __launch_bounds__(256) void gemm_bf16_k(
    const u16* __restrict__ A, int lda,
    const u16* __restrict__ A2, int lda2,
    const u16* __restrict__ W,
    void* __restrict__ Cv, int ldc,
    const u16* __restrict__ R, int ldr,
    const float* __restrict__ bg, const float* __restrict__ bb,
    const float* __restrict__ bm_, const float* __restrict__ bv,
    int N)
{
    __shared__ u16 Ws[64*WSTR];
    int t = threadIdx.x;
    int bn = blockIdx.x * 64;
    int bm = blockIdx.y * 256;
    {
        constexpr int KQ = K/4;
        int brow = t >> 2, bq = t & 3;
        int n = bn + brow;
        bool nv = n < N;
        const u16* src = W + (size_t)n*K + bq*KQ;
        #pragma unroll
        for (int j=0; j<KQ; j+=8){
            short8v v = {};
            if (nv) v = *(const short8v*)(src + j);
            *(short8v*)&Ws[brow*WSTR + bq*KQ + j] = v;
        }
    }
    __syncthreads();
    int wave = t >> 6, lane = t & 63;
    int wm = wave*64;
    int lr = lane & 15, lk = lane >> 4;
    const u16* arow  = A + (size_t)(bm + wm + lr)*lda + lk*8;
    const u16* arow2 = SPLIT ? (A2 + (size_t)(bm + wm + lr)*lda2 + lk*8) : nullptr;
    floatx4 acc[4][4] = {};
    #pragma unroll
    for (int k0 = 0; k0 < K; k0 += 32){
        short8v afr[4];
        if (SPLIT && k0 >= 96){
            #pragma unroll
            for (int m=0;m<4;m++)
                afr[m] = *(const short8v*)(arow2 + (size_t)(m*16)*lda2 + (k0-96));
        } else {
            #pragma unroll
            for (int m=0;m<4;m++)
                afr[m] = *(const short8v*)(arow + (size_t)(m*16)*lda + k0);
        }
        #pragma unroll
        for (int n2=0;n2<4;n2++){
            short8v bfr = *(const short8v*)&Ws[(n2*16+lr)*WSTR + k0 + lk*8];
            #pragma unroll
            for (int m=0;m<4;m++)
                acc[m][n2] = __builtin_amdgcn_mfma_f32_16x16x32_bf16(afr[m], bfr, acc[m][n2], 0,0,0);
        }
    }
    #pragma unroll
    for (int m=0;m<4;m++){
        #pragma unroll
        for (int n2=0;n2<4;n2++){
            int gcol = bn + n2*16 + lr;
            if (gcol >= N) continue;
            #pragma unroll
            for (int rg=0; rg<4; rg++){
                int grow = bm + wm + m*16 + lk*4 + rg;
                float v = acc[m][n2][rg];
                if (MODE == GM_RES){
                    v += b2f(R[(size_t)grow*ldr + gcol]);
                    ((u16*)Cv)[(size_t)grow*ldc + gcol] = f2b(v);
                } else if (MODE == GM_BN_RES){
                    float bnv = (v - bm_[gcol])*rsqrtf(bv[gcol]+1e-5f)*bg[gcol] + bb[gcol];
                    ((float*)Cv)[(size_t)grow*ldc + gcol] = bnv + b2f(R[(size_t)grow*ldr + gcol]);
                } else if (MODE == GM_GELU_BN){
                    float gl = gelu_exact(v);
                    v = (gl - bm_[gcol])*rsqrtf(bv[gcol]+1e-5f)*bg[gcol] + bb[gcol];
                    ((u16*)Cv)[(size_t)grow*ldc + gcol] = f2b(v);
                } else if (MODE == GM_BIAS_RELU){
                    ((u16*)Cv)[(size_t)grow*ldc + gcol] = f2b(fmaxf(v + bg[gcol], 0.f));
                } else {
                    ((u16*)Cv)[(size_t)grow*ldc + gcol] = f2b(v);
                }
            }
        }
    }
}

// ---------- gate stage 2: sigmoid(G1 @ w2 + b2) per pixel, G1 bf16 ----------
__global__ __launch_bounds__(256) void gate2_k(const u16* __restrict__ G1,
    const float* __restrict__ w2, const float* __restrict__ b2, float* __restrict__ gpix)
{
    int pix = blockIdx.x*256 + threadIdx.x;
    const short4v* g4 = (const short4v*)(G1 + (size_t)pix*96);
    const float4* w4 = (const float4*)w2;
    float s = b2[0];
    #pragma unroll
    for (int j=0;j<24;j++){
        short4v g = g4[j]; float4 w = w4[j];
        s += b2f((u16)g.x)*w.x + b2f((u16)g.y)*w.y + b2f((u16)g.z)*w.z + b2f((u16)g.w)*w.w;
    }
    gpix[pix] = 1.f/(1.f+expf(-s));
}

// ---------- deterministic mean of gpix -> dyn_k ----------
__global__ __launch_bounds__(1024) void gate_reduce_k(const float* __restrict__ gpix,
                                                      float* __restrict__ dynk)
{
    __shared__ float sm[16];
    float s = 0.f;
    for (int i=threadIdx.x; i<NPIX; i+=1024) s += gpix[i];
    #pragma unroll
    for (int off=32; off; off>>=1) s += __shfl_xor(s,off,64);
    int wid = threadIdx.x>>6, lane = threadIdx.x&63;
    if (lane==0) sm[wid]=s;
    __syncthreads();
    if (threadIdx.x==0){
        float tot=0.f; for (int i=0;i<16;i++) tot+=sm[i];
        *dynk = floorf(12.0f * (tot/(float)NPIX));
    }
}

// ---------- qkv depthwise 3x3 (288 ch), 2-col sweep, LDS weights, XCD-swizzled ----------
#define QPOS(c8) ((c8)*8 + ((c8)>>2)*4)
#define QTAPSTRIDE 324
__global__ __launch_bounds__(256) void qkv_dw_k(const u16* __restrict__ in,
    const float* __restrict__ w, u16* __restrict__ out)
{
    __shared__ float wlds[9*QTAPSTRIDE];
    int t = threadIdx.x;
    for (int i=t; i<2592; i+=256){
        int tap = i/288, cc = i%288;
        wlds[tap*QTAPSTRIDE + QPOS(cc>>3) + (cc&7)] = w[cc*9+tap];
    }
    __syncthreads();
    int bid = blockIdx.x;
    int sb = (bid & 7)*(gridDim.x >> 3) + (bid >> 3);
    int idx = sb*256 + t;                  // over NB*HW*18 (col pairs x 36 groups)
    int c8 = idx % 36; int px2 = idx / 36;
    int wp = px2 & 63; int hy = (px2 >> 6) & 127; int img = px2 >> 13;
    int wx0 = wp*2;
    int c0 = c8*8;
    int wofs = QPOS(c8);
    float acc0[8] = {}, acc1[8] = {};
    #pragma unroll
    for (int ky=0; ky<3; ky++){
        int hh = hy + ky - 1; if ((unsigned)hh >= HH) continue;
        const u16* rowp = in + ((size_t)(img*HH+hh)*WW)*288 + c0;
        #pragma unroll
        for (int cc=0; cc<4; cc++){
            int cx = wx0 - 1 + cc;
            if ((unsigned)cx >= WW) continue;
            short8v v = *(const short8v*)(rowp + (size_t)cx*288);
            float vf[8];
            #pragma unroll
            for (int j=0;j<8;j++) vf[j] = b2f((u16)v[j]);
            if (cc < 3){
                floatx4 wa = *(const floatx4*)&wlds[(ky*3+cc)*QTAPSTRIDE + wofs];
                floatx4 wb = *(const floatx4*)&wlds[(ky*3+cc)*QTAPSTRIDE + wofs + 4];
                #pragma unroll
                for (int j=0;j<4;j++){ acc0[j]   = fmaf(wa[j], vf[j],   acc0[j]);
                                       acc0[4+j] = fmaf(wb[j], vf[4+j], acc0[4+j]); }
            }
            if (cc >= 1){
                floatx4 wa = *(const floatx4*)&wlds[(ky*3+cc-1)*QTAPSTRIDE + wofs];
                floatx4 wb = *(const floatx4*)&wlds[(ky*3+cc-1)*QTAPSTRIDE + wofs + 4];
                #pragma unroll
                for (int j=0;j<4;j++){ acc1[j]   = fmaf(wa[j], vf[j],   acc1[j]);
                                       acc1[4+j] = fmaf(wb[j], vf[4+j], acc1[4+j]); }
            }
        }
    }
    size_t pix0 = (size_t)(img*HH+hy)*WW + wx0;
    short8v o0, o1;
    #pragma unroll
    for (int j=0;j<8;j++){ o0[j] = (short)f2b(acc0[j]); o1[j] = (short)f2b(acc1[j]); }
    *(short8v*)(out + pix0*288 + c0) = o0;
    *(short8v*)(out + (pix0+1)*288 + c0) = o1;
}

// ---------- Gram partials per (img,head,slice), vectorized staging ----------
__global__ __launch_bounds__(256) void gram_k(const u16* __restrict__ QKVd,
                                              float* __restrict__ part)
{
    int bh = blockIdx.x;        // NB*8: img*8+h
    int slice = blockIdx.y;     // 16 (1024 pixels each)
    int img = bh >> 3, h = bh & 7;
    int qbase = h*12, kbase = 96 + h*12;
    const u16* base = QKVd + (size_t)img*HW*288;
    __shared__ float qs[64][12];
    __shared__ float ks[64][12];
    int t = threadIdx.x;
    float acc = 0.f;
    int c = (t<144) ? t/12 : (t<156 ? t-144 : t-156);
    int d = (t<144) ? t%12 : 0;
    for (int st=0; st<16; st++){
        int pix0 = slice*1024 + st*64;
        __syncthreads();
        for (int i=t; i<384; i+=256){
            int p = i/6, j = i%6;
            const u16* src = base + (size_t)(pix0+p)*288 + (j<3 ? qbase + j*4 : kbase + (j-3)*4);
            short4v v = *(const short4v*)src;
            float f0=b2f((u16)v.x), f1=b2f((u16)v.y), f2=b2f((u16)v.z), f3=b2f((u16)v.w);
            if (j<3){ int jj=j*4;     qs[p][jj]=f0; qs[p][jj+1]=f1; qs[p][jj+2]=f2; qs[p][jj+3]=f3; }
            else    { int jj=(j-3)*4; ks[p][jj]=f0; ks[p][jj+1]=f1; ks[p][jj+2]=f2; ks[p][jj+3]=f3; }
        }
        __syncthreads();
        if (t<144){        for (int p=0;p<64;p++) acc = fmaf(qs[p][c], ks[p][d], acc); }
        else if (t<156){   for (int p=0;p<64;p++) acc = fmaf(qs[p][c], qs[p][c], acc); }
        else if (t<168){   for (int p=0;p<64;p++) acc = fmaf(ks[p][c], ks[p][c], acc); }
    }
    if (t<168) part[((size_t)bh*16 + slice)*168 + t] = acc;
}

__global__ __launch_bounds__(256) void gram_combine_k(const float* __restrict__ part,
                                                      float* __restrict__ gram, int n)
{
    int i = blockIdx.x*256 + threadIdx.x;
    if (i >= n) return;
    int bh = i/168, t = i%168;
    float s = 0.f;
    for (int sl=0; sl<16; sl++) s += part[((size_t)bh*16+sl)*168 + t];
    gram[i] = s;
}

// ---------- attn 12x12: normalize, temperature, top-k mask, softmax ----------
__global__ __launch_bounds__(256) void attn_k(const float* __restrict__ gram,
    const float* __restrict__ temp, const float* __restrict__ dynk_p,
    const float* __restrict__ a1, const float* __restrict__ a2,
    const float* __restrict__ a3, const float* __restrict__ a4,
    float* __restrict__ attnW)
{
    int bh = blockIdx.x;   // NB*8: img*8+h
    int h = bh & 7;
    __shared__ float av[12][12];
    __shared__ float mv[12][12];
    __shared__ float nq[12], nk[12];
    int t = threadIdx.x;
    if (t < 12) nq[t] = fmaxf(sqrtf(gram[bh*168+144+t]), 1e-12f);
    else if (t < 24) nk[t-12] = fmaxf(sqrtf(gram[bh*168+156+(t-12)]), 1e-12f);
    __syncthreads();
    if (t < 144){
        int c=t/12, d=t%12;
        av[c][d] = gram[bh*168+t] / (nq[c]*nk[d]) * temp[h];
    }
    __syncthreads();
    float dk = *dynk_p;
    if (t < 144){
        int c=t/12, d=t%12; float v = av[c][d];
        int r = 0;
        #pragma unroll
        for (int j=0;j<12;j++){
            float o = av[c][j];
            r += (o > v) ? 1 : ((o == v && j < d) ? 1 : 0);
        }
        mv[c][d] = ((float)r < dk) ? v : -INFINITY;
    }
    __syncthreads();
    if (t < 12){
        float mx = -INFINITY;
        for (int d2=0; d2<12; d2++) mx = fmaxf(mx, mv[t][d2]);
        float e[12]; float s = 0.f;
        for (int d2=0; d2<12; d2++){ e[d2] = expf(mv[t][d2]-mx); s += e[d2]; }
        float sc = (a1[0]+a2[0]+a3[0]+a4[0]) / s;
        for (int d2=0; d2<12; d2++) attnW[(size_t)bh*144 + t*12 + d2] = e[d2]*sc;
    }
}

// ---------- attn apply -> P96 bf16 (attention half only); thread = (pixel, head) ----------
__global__ __launch_bounds__(256) void attn_apply_k(const u16* __restrict__ QKVd,
    const float* __restrict__ attnW, u16* __restrict__ P)
{
    int gid = blockIdx.x*256 + threadIdx.x;          // NB*HW*8
    int h = gid % 8; size_t pix = (size_t)(gid / 8);
    int img = (int)(pix >> 14);
    const u16* vp = QKVd + pix*288 + 192 + h*12;
    float vf[12];
    #pragma unroll
    for (int j=0;j<3;j++){
        short4v v = *(const short4v*)(vp + j*4);
        vf[j*4+0]=b2f((u16)v.x); vf[j*4+1]=b2f((u16)v.y);
        vf[j*4+2]=b2f((u16)v.z); vf[j*4+3]=b2f((u16)v.w);
    }
    const float* awb = attnW + ((size_t)(img*8+h))*144;
    u16 o[12];
    #pragma unroll
    for (int cc=0; cc<12; cc++){
        const float4* ap = (const float4*)(awb + cc*12);   // 48B stride -> 16B aligned
        float4 a0 = ap[0], a1 = ap[1], a2 = ap[2];
        float s = a0.x*vf[0] + a0.y*vf[1] + a0.z*vf[2] + a0.w*vf[3]
                + a1.x*vf[4] + a1.y*vf[5] + a1.z*vf[6] + a1.w*vf[7]
                + a2.x*vf[8] + a2.y*vf[9] + a2.z*vf[10]+ a2.w*vf[11];
        o[cc] = f2b(s);
    }
    u16* op = P + pix*96 + h*12;
    *(short4v*)(op)   = *(short4v*)&o[0];
    *(short4v*)(op+4) = *(short4v*)&o[4];
    *(short4v*)(op+8) = *(short4v*)&o[8];
}

// ---------- FFN multi-scale depthwise, row-sweep per scale, XCD-swizzled ----------
template<int KS>
__global__ __launch_bounds__(256) void ffn_dw_g(const u16* __restrict__ V0,
    const float* __restrict__ wsrc, const float* __restrict__ bsrc, int cbase,
    const float* __restrict__ bn2g, const float* __restrict__ bn2b,
    const float* __restrict__ bn2m, const float* __restrict__ bn2v,
    u16* __restrict__ U)
{
    constexpr int PAD = KS/2;
    __shared__ float wlds[KS*KS*64];
    __shared__ float bng[64], bnb[64], bnm[64], bnvr[64];
    int t = threadIdx.x;
    for (int i=t; i<KS*KS*64; i+=256){
        int tap = i >> 6, cc = i & 63;
        wlds[tap*64 + cc] = wsrc[cc*KS*KS + tap];
    }
    if (t < 64){
        bng[t] = bn2g[cbase+t]; bnb[t] = bn2b[cbase+t];
        bnm[t] = bn2m[cbase+t]; bnvr[t] = rsqrtf(bn2v[cbase+t]+1e-5f);
    }
    __syncthreads();
    int ci = t & 7, seg = t >> 3;
    int bid = blockIdx.x;
    int rowid = (bid & 7)*(gridDim.x >> 3) + (bid >> 3);
    int img = rowid >> 7, hy = rowid & 127;
    int c0r = ci*8;
    int c0 = cbase + c0r;
    int x0 = seg*4;
    float acc[4][8];
    {
        floatx4 b0 = *(const floatx4*)(bsrc + c0r);
        floatx4 b1 = *(const floatx4*)(bsrc + c0r + 4);
        #pragma unroll
        for (int dx=0;dx<4;dx++){
            #pragma unroll
            for (int j=0;j<4;j++){ acc[dx][j]=b0[j]; acc[dx][4+j]=b1[j]; }
        }
    }
    #pragma unroll
    for (int ky=0; ky<KS; ky++){
        int hh = hy + ky - PAD;
        if ((unsigned)hh >= HH) continue;
        float wr[KS][8];
        #pragma unroll
        for (int kx=0; kx<KS; kx++){
            floatx4 wa = *(const floatx4*)&wlds[(ky*KS+kx)*64 + c0r];
            floatx4 wb = *(const floatx4*)&wlds[(ky*KS+kx)*64 + c0r + 4];
            #pragma unroll
            for (int j=0;j<4;j++){ wr[kx][j]=wa[j]; wr[kx][4+j]=wb[j]; }
        }
        const u16* rowp = V0 + ((size_t)(img*HH+hh)*WW)*256 + c0;
        #pragma unroll
        for (int cc=0; cc<4+2*PAD; cc++){
            int cx = x0 - PAD + cc;
            if ((unsigned)cx >= WW) continue;
            short8v v = *(const short8v*)(rowp + (size_t)cx*256);
            float vf[8];
            #pragma unroll
            for (int j=0;j<8;j++) vf[j] = b2f((u16)v[j]);
            #pragma unroll
            for (int dx=0; dx<4; dx++){
                int kx = cc - dx;
                if (kx < 0 || kx >= KS) continue;
                #pragma unroll
                for (int j=0;j<8;j++) acc[dx][j] = fmaf(wr[kx][j], vf[j], acc[dx][j]);
            }
        }
    }
    size_t rbase = (size_t)(img*HH+hy)*WW;
    #pragma unroll
    for (int dx=0; dx<4; dx++){
        size_t pix = rbase + x0 + dx;
        short8v vc = *(const short8v*)(V0 + pix*256 + c0);
        short8v o;
        #pragma unroll
        for (int j=0;j<8;j++){
            float v0c = b2f((u16)vc[j]);
            float u1 = acc[dx][j] + v0c;
            float gl = gelu_exact(u1);
            float bn = (gl - bnm[c0r+j])*bnvr[c0r+j]*bng[c0r+j] + bnb[c0r+j];
            o[j] = (short)f2b(bn*v0c);
        }
        *(short8v*)(U + pix*256 + c0) = o;
    }
}

extern "C" void kernel_launch(void* const* d_in, const int* in_sizes, int n_in,
                              void* d_out, int out_size, void* d_ws, size_t ws_size,
                              hipStream_t stream)
{
    const float* x     = (const float*)d_in[0];
    const float* pos_w = (const float*)d_in[1];
    const float* pos_b = (const float*)d_in[2];
    const float* ln1g  = (const float*)d_in[3];
    const float* ln1b  = (const float*)d_in[4];
    const float* temp  = (const float*)d_in[5];
    const float* qkvw  = (const float*)d_in[6];
    const float* qkvdw = (const float*)d_in[7];
    const float* projw = (const float*)d_in[8];
    const float* gw1   = (const float*)d_in[9];
    const float* gb1   = (const float*)d_in[10];
    const float* gw2   = (const float*)d_in[11];
    const float* gb2   = (const float*)d_in[12];
    const float* a1    = (const float*)d_in[13];
    const float* a2    = (const float*)d_in[14];
    const float* a3    = (const float*)d_in[15];
    const float* a4    = (const float*)d_in[16];
    const float* ln2g  = (const float*)d_in[17];
    const float* ln2b  = (const float*)d_in[18];
    const float* fc1w  = (const float*)d_in[19];
    const float* bn1g  = (const float*)d_in[20];
    const float* bn1b  = (const float*)d_in[21];
    const float* bn1m  = (const float*)d_in[22];
    const float* bn1v  = (const float*)d_in[23];
    const float* bn2g  = (const float*)d_in[24];
    const float* bn2b  = (const float*)d_in[25];
    const float* bn2m  = (const float*)d_in[26];
    const float* bn2v  = (const float*)d_in[27];
    const float* fc2w  = (const float*)d_in[28];
    const float* bn3g  = (const float*)d_in[29];
    const float* bn3b  = (const float*)d_in[30];
    const float* bn3m  = (const float*)d_in[31];
    const float* bn3v  = (const float*)d_in[32];
    const float* dw0w  = (const float*)d_in[33];
    const float* dw0b  = (const float*)d_in[34];
    const float* dw1w  = (const float*)d_in[35];
    const float* dw1b  = (const float*)d_in[36];
    const float* dw2w  = (const float*)d_in[37];
    const float* dw2b  = (const float*)d_in[38];
    const float* dw3w  = (const float*)d_in[39];
    const float* dw3b  = (const float*)d_in[40];

    float* OUT = (float*)d_out;      // final fp32 output (written once by fc2)

    // ---- fixed small buffers + bf16 residual stream A ----
    char* p = (char*)d_ws;
    float* gpix  = (float*)p;                 p += (size_t)NPIX*4;
    float* dynk  = (float*)p;                 p += 256;
    float* gpart = (float*)p;                 p += 64*16*168*4;
    float* gram  = (float*)p;                 p += 64*168*4;
    float* attnW = (float*)p;                 p += 64*144*4;
    u16*   wbf   = (u16*)p;                   p += (size_t)WTOT*2;
    u16*   Abf   = (u16*)p;                   p += (size_t)NPIX*192*2;   // 50.3 MB
    size_t fixedB = (size_t)(p - (char*)d_ws);

    // ---- choose chunk size from ws_size: per-image = Y(192)+B1(288)+B2(288) bf16 ----
    size_t perImg = (size_t)HW*2*(192+288+288);   // 25,165,824
    int CBr = 2;
    if (ws_size >= fixedB + 8*perImg) CBr = 8;
    else if (ws_size >= fixedB + 4*perImg) CBr = 4;
    int NCHUNKr = BB/CBr;
    size_t CHWr = (size_t)CBr*HW;

    u16* Ybf = (u16*)p;                   p += CHWr*192*2;
    u16* B1  = (u16*)p;                   p += CHWr*288*2;
    u16* B2  = (u16*)p;
    u16* qkvwb = wbf;
    u16* projwb= wbf + WQ;
    u16* gw1b  = wbf + WQ + WP;
    u16* fc1b  = wbf + WQ + WP + WG;
    u16* fc2b  = wbf + WQ + WP + WG + WF1;
    u16* G1bf  = B1;     // gate phase
    u16* QKVbf = B1;     // qkv out
    u16* QKVdbf= B2;     // qkv_dw out
    u16* P96   = B1;     // attn out (QKV dead)
    u16* Zbf   = B2;     // LN2 out (QKVd dead)
    u16* V0bf  = B1;     // fc1 out (P96 dead)
    u16* Ubf   = B2;     // ffn out (Z dead)

    wprep_k<<<(WTOT+255)/256, 256, 0, stream>>>(qkvw, projw, gw1, fc1w, fc2w, wbf);
    pos_conv_k<<<BB*HH*16*48/256, 256, 0, stream>>>(x, pos_w, pos_b, Abf);

    // gate phase
    for (int c=0; c<NCHUNKr; c++){
        const u16* Ab = Abf + (size_t)c*CHWr*192;
        ln_k<<<CHWr/4, 256, 0, stream>>>(Ab, ln1g, ln1b, Ybf);
        dim3 g(2, CHWr/256);
        gemm_bf16_k<GM_BIAS_RELU,192><<<g, 256, 0, stream>>>(Ybf, 192, nullptr, 0,
            gw1b, G1bf, 96, nullptr, 0, gb1, nullptr, nullptr, nullptr, 96);
        gate2_k<<<CHWr/256, 256, 0, stream>>>(G1bf, gw2, gb2, gpix + (size_t)c*CHWr);
    }
    gate_reduce_k<<<1, 1024, 0, stream>>>(gpix, dynk);

    // main phase
    for (int c=0; c<NCHUNKr; c++){
        u16* Ab = Abf + (size_t)c*CHWr*192;
        if (NCHUNKr > 1)   // single-chunk mode: Ybf from gate phase is still valid
            ln_k<<<CHWr/4, 256, 0, stream>>>(Ab, ln1g, ln1b, Ybf);
        {
            dim3 g(5, CHWr/256);
            gemm_bf16_k<GM_NONE,96><<<g, 256, 0, stream>>>(Ybf, 192, nullptr, 0,
                qkvwb, QKVbf, 288, nullptr, 0, nullptr,nullptr,nullptr,nullptr, 288);
        }
        qkv_dw_k<<<CHWr*18/256, 256, 0, stream>>>(QKVbf, qkvdw, QKVdbf);
        { dim3 g(CBr*8, 16); gram_k<<<g, 256, 0, stream>>>(QKVdbf, gpart); }
        gram_combine_k<<<(CBr*8*168+255)/256, 256, 0, stream>>>(gpart, gram, CBr*8*168);
        attn_k<<<CBr*8, 256, 0, stream>>>(gram, temp, dynk, a1,a2,a3,a4, attnW);
        attn_apply_k<<<CHWr*8/256, 256, 0, stream>>>(QKVdbf, attnW, P96);
        {   // proj + residual: A += [P96 | Y[:,96:]] @ projw^T  (bf16 in-place)
            dim3 g(3, CHWr/256);
            gemm_bf16_k<GM_RES,192,true><<<g, 256, 0, stream>>>(P96, 96, Ybf+96, 192,
                projwb, Ab, 192, Ab, 192, nullptr,nullptr,nullptr,nullptr, 192);
        }
        ln_k<<<CHWr/4, 256, 0, stream>>>(Ab, ln2g, ln2b, Zbf);
        {
            dim3 g(4, CHWr/256);
            gemm_bf16_k<GM_GELU_BN,192><<<g, 256, 0, stream>>>(Zbf, 192, nullptr, 0,
                fc1b, V0bf, 256, nullptr, 0, bn1g,bn1b,bn1m,bn1v, 256);
        }
        int rows = (int)(CHWr/WW);
        ffn_dw_g<1><<<rows, 256, 0, stream>>>(V0bf, dw0w, dw0b, 0,
            bn2g,bn2b,bn2m,bn2v, Ubf);
        ffn_dw_g<3><<<rows, 256, 0, stream>>>(V0bf, dw1w, dw1b, 64,
            bn2g,bn2b,bn2m,bn2v, Ubf);
        ffn_dw_g<5><<<rows, 256, 0, stream>>>(V0bf, dw2w, dw2b, 128,
            bn2g,bn2b,bn2m,bn2v, Ubf);
        ffn_dw_g<7><<<rows, 256, 0, stream>>>(V0bf, dw3w, dw3b, 192,
            bn2g,bn2b,bn2m,bn2v, Ubf);
        {   // fc2 + bn3 + residual -> fp32 OUT
            dim3 g(3, CHWr/256);
            gemm_bf16_k<GM_BN_RES,256><<<g, 256, 0, stream>>>(Ubf, 256, nullptr, 0,
                fc2b, OUT + (size_t)c*CHWr*192, 192, Ab, 192, bn3g,bn3b,bn3m,bn3v, 192);
        }
    }
}

// Round 11
// 654.991 us; speedup vs baseline: 4.9927x; 1.0008x over previous
//
#include <hip/hip_runtime.h>
#include <hip/hip_bf16.h>
#include <math.h>

#define BB 8
#define HH 128
#define WW 128
#define HW (HH*WW)          // 16384
#define NPIX (BB*HW)        // 131072

typedef unsigned short u16;
typedef __attribute__((ext_vector_type(4))) float  floatx4;
typedef __attribute__((ext_vector_type(4))) short  short4v;
typedef __attribute__((ext_vector_type(8))) short  short8v;

static __device__ __forceinline__ float gelu_exact(float x){
    return 0.5f*x*(1.0f+erff(x*0.70710678118654752440f));
}
static __device__ __forceinline__ float b2f(u16 v){
    union { unsigned u; float f; } x; x.u = ((unsigned)v)<<16; return x.f;
}
static __device__ __forceinline__ u16 f2b(float f){
    __hip_bfloat16 h = __float2bfloat16(f);
    return *(u16*)&h;
}

// ---------- weight prep: fp32 -> bf16 for the five GEMM weight matrices ----------
#define WQ 27648
#define WP 36864
#define WG 18432
#define WF1 49152
#define WF2 49152
#define WTOT (WQ+WP+WG+WF1+WF2)   // 181248
__global__ __launch_bounds__(256) void wprep_k(const float* __restrict__ a,
    const float* __restrict__ b, const float* __restrict__ c,
    const float* __restrict__ d, const float* __restrict__ e, u16* __restrict__ o)
{
    int i = blockIdx.x*256 + threadIdx.x;
    if (i >= WTOT) return;
    float v;
    if (i < WQ) v = a[i];
    else if (i < WQ+WP) v = b[i-WQ];
    else if (i < WQ+WP+WG) v = c[i-WQ-WP];
    else if (i < WQ+WP+WG+WF1) v = d[i-WQ-WP-WG];
    else v = e[i-WQ-WP-WG-WF1];
    o[i] = f2b(v);
}

// ---------- pos depthwise 3x3 + bias + residual -> bf16 A, 2-col-deep prefetch ----------
__global__ __launch_bounds__(256) void pos_conv_k(const float* __restrict__ x,
    const float* __restrict__ w, const float* __restrict__ bias, u16* __restrict__ out)
{
    int bid = blockIdx.x;
    int sb = (bid & 7)*(gridDim.x >> 3) + (bid >> 3);   // each XCD owns contiguous slice
    int gid = sb*256 + threadIdx.x;     // ((b*HH+hy)*16 + seg)*48 + c4
    int c4 = gid % 48; int rest = gid / 48;
    int seg = rest & 15; rest >>= 4;
    int hy = rest % HH; int b = rest / HH;
    int c0 = c4*4;
    float wr[3][3][4];
    #pragma unroll
    for (int j=0;j<4;j++)
        #pragma unroll
        for (int ky=0;ky<3;ky++)
            #pragma unroll
            for (int kx=0;kx<3;kx++)
                wr[ky][kx][j] = w[(c0+j)*9 + ky*3 + kx];
    float4 bias4 = *(const float4*)(bias + c0);
    const float4* x4 = (const float4*)x;
    const float4* r0 = x4 + ((size_t)(b*HH + hy-1)*WW)*48 + c4;
    const float4* r1 = x4 + ((size_t)(b*HH + hy  )*WW)*48 + c4;
    const float4* r2 = x4 + ((size_t)(b*HH + hy+1)*WW)*48 + c4;
    bool v0 = hy > 0, v2 = hy < HH-1;
    float4 z4 = make_float4(0.f,0.f,0.f,0.f);
    int s0 = seg*8;
    // rolling window: cA(wx-1) cB(wx) cC(wx+1); prefetched cP(wx+2); loading cN(wx+3)
    float4 cA[3], cB[3], cC[3], cP[3], cN[3];
    bool la = s0 > 0;
    cA[0] = (v0&&la) ? r0[(size_t)(s0-1)*48] : z4;
    cA[1] = la ? r1[(size_t)(s0-1)*48] : z4;
    cA[2] = (v2&&la) ? r2[(size_t)(s0-1)*48] : z4;
    cB[0] = v0 ? r0[(size_t)s0*48] : z4;  cB[1] = r1[(size_t)s0*48];  cB[2] = v2 ? r2[(size_t)s0*48] : z4;
    cC[0] = v0 ? r0[(size_t)(s0+1)*48] : z4; cC[1] = r1[(size_t)(s0+1)*48]; cC[2] = v2 ? r2[(size_t)(s0+1)*48] : z4;
    {
        bool ok = (s0+2) < WW;
        size_t off = (size_t)(s0+2)*48;
        cP[0] = (v0&&ok) ? r0[off] : z4;
        cP[1] = ok ? r1[off] : z4;
        cP[2] = (v2&&ok) ? r2[off] : z4;
    }
    u16* orow = out + ((size_t)(b*HH + hy)*WW)*192 + c0;
    for (int i2=0; i2<8; i2++){
        int wx = s0 + i2;
        bool okc = (wx+3) < WW;
        size_t noff = (size_t)(wx+3)*48;
        cN[0] = (v0 && okc) ? r0[noff] : z4;
        cN[1] = okc ? r1[noff] : z4;
        cN[2] = (v2 && okc) ? r2[noff] : z4;
        float4 acc = bias4;
        #pragma unroll
        for (int i=0;i<3;i++){
            acc.x = fmaf(wr[i][0][0], cA[i].x, acc.x);
            acc.y = fmaf(wr[i][0][1], cA[i].y, acc.y);
            acc.z = fmaf(wr[i][0][2], cA[i].z, acc.z);
            acc.w = fmaf(wr[i][0][3], cA[i].w, acc.w);
            acc.x = fmaf(wr[i][1][0], cB[i].x, acc.x);
            acc.y = fmaf(wr[i][1][1], cB[i].y, acc.y);
            acc.z = fmaf(wr[i][1][2], cB[i].z, acc.z);
            acc.w = fmaf(wr[i][1][3], cB[i].w, acc.w);
            acc.x = fmaf(wr[i][2][0], cC[i].x, acc.x);
            acc.y = fmaf(wr[i][2][1], cC[i].y, acc.y);
            acc.z = fmaf(wr[i][2][2], cC[i].z, acc.z);
            acc.w = fmaf(wr[i][2][3], cC[i].w, acc.w);
        }
        acc.x += cB[1].x; acc.y += cB[1].y; acc.z += cB[1].z; acc.w += cB[1].w;
        short4v o; o.x=(short)f2b(acc.x); o.y=(short)f2b(acc.y);
        o.z=(short)f2b(acc.z); o.w=(short)f2b(acc.w);
        *(short4v*)(orow + (size_t)wx*192) = o;
        #pragma unroll
        for (int i=0;i<3;i++){ cA[i]=cB[i]; cB[i]=cC[i]; cC[i]=cP[i]; cP[i]=cN[i]; }
    }
}

// ---------- LayerNorm over C=192, bf16 in -> bf16 out, wave per pixel ----------
__global__ __launch_bounds__(256) void ln_k(const u16* __restrict__ in,
    const float* __restrict__ g, const float* __restrict__ bta, u16* __restrict__ out)
{
    int wid = threadIdx.x >> 6, lane = threadIdx.x & 63;
    size_t pix = (size_t)blockIdx.x*4 + wid;
    const u16* row = in + pix*192;
    float x0 = b2f(row[lane]), x1 = b2f(row[lane+64]), x2 = b2f(row[lane+128]);
    float s = x0+x1+x2;
    float q = x0*x0 + x1*x1 + x2*x2;
    #pragma unroll
    for (int off=32; off; off>>=1){ s += __shfl_xor(s,off,64); q += __shfl_xor(q,off,64); }
    float mean = s*(1.f/192.f);
    float var  = q*(1.f/192.f) - mean*mean;
    float inv  = rsqrtf(var + 1e-6f);
    u16* orow = out + pix*192;
    orow[lane]     = f2b((x0-mean)*inv*g[lane]     + bta[lane]);
    orow[lane+64]  = f2b((x1-mean)*inv*g[lane+64]  + bta[lane+64]);
    orow[lane+128] = f2b((x2-mean)*inv*g[lane+128] + bta[lane+128]);
}

// ---------- bf16 MFMA GEMM: W-in-LDS once, A streamed from global (optional 2-panel A) ----------
#define GM_NONE 0
#define GM_RES 1
#define GM_GELU_BN 2
#define GM_BN_RES 3
#define GM_BIAS_RELU 4
#define WSTR 264   // LDS row stride in shorts: 528B = 132 dw; 132%32=4 -> 2-way only

template<int MODE, int K, bool SPLIT=false>
__global__ __launch_bounds__(256) void gemm_bf16_k(
    const u16* __restrict__ A, int lda,
    const u16* __restrict__ A2, int lda2,
    const u16* __restrict__ W,
    void* __restrict__ Cv, int ldc,
    const u16* __restrict__ R, int ldr,
    const float* __restrict__ bg, const float* __restrict__ bb,
    const float* __restrict__ bm_, const float* __restrict__ bv,
    int N)
{
    __shared__ u16 Ws[64*WSTR];
    int t = threadIdx.x;
    int bn = blockIdx.x * 64;
    int bm = blockIdx.y * 256;
    {
        constexpr int KQ = K/4;
        int brow = t >> 2, bq = t & 3;
        int n = bn + brow;
        bool nv = n < N;
        const u16* src = W + (size_t)n*K + bq*KQ;
        #pragma unroll
        for (int j=0; j<KQ; j+=8){
            short8v v = {};
            if (nv) v = *(const short8v*)(src + j);
            *(short8v*)&Ws[brow*WSTR + bq*KQ + j] = v;
        }
    }
    __syncthreads();
    int wave = t >> 6, lane = t & 63;
    int wm = wave*64;
    int lr = lane & 15, lk = lane >> 4;
    const u16* arow  = A + (size_t)(bm + wm + lr)*lda + lk*8;
    const u16* arow2 = SPLIT ? (A2 + (size_t)(bm + wm + lr)*lda2 + lk*8) : nullptr;
    floatx4 acc[4][4] = {};
    #pragma unroll
    for (int k0 = 0; k0 < K; k0 += 32){
        short8v afr[4];
        if (SPLIT && k0 >= 96){
            #pragma unroll
            for (int m=0;m<4;m++)
                afr[m] = *(const short8v*)(arow2 + (size_t)(m*16)*lda2 + (k0-96));
        } else {
            #pragma unroll
            for (int m=0;m<4;m++)
                afr[m] = *(const short8v*)(arow + (size_t)(m*16)*lda + k0);
        }
        #pragma unroll
        for (int n2=0;n2<4;n2++){
            short8v bfr = *(const short8v*)&Ws[(n2*16+lr)*WSTR + k0 + lk*8];
            #pragma unroll
            for (int m=0;m<4;m++)
                acc[m][n2] = __builtin_amdgcn_mfma_f32_16x16x32_bf16(afr[m], bfr, acc[m][n2], 0,0,0);
        }
    }
    #pragma unroll
    for (int m=0;m<4;m++){
        #pragma unroll
        for (int n2=0;n2<4;n2++){
            int gcol = bn + n2*16 + lr;
            if (gcol >= N) continue;
            #pragma unroll
            for (int rg=0; rg<4; rg++){
                int grow = bm + wm + m*16 + lk*4 + rg;
                float v = acc[m][n2][rg];
                if (MODE == GM_RES){
                    v += b2f(R[(size_t)grow*ldr + gcol]);
                    ((u16*)Cv)[(size_t)grow*ldc + gcol] = f2b(v);
                } else if (MODE == GM_BN_RES){
                    float bnv = (v - bm_[gcol])*rsqrtf(bv[gcol]+1e-5f)*bg[gcol] + bb[gcol];
                    ((float*)Cv)[(size_t)grow*ldc + gcol] = bnv + b2f(R[(size_t)grow*ldr + gcol]);
                } else if (MODE == GM_GELU_BN){
                    float gl = gelu_exact(v);
                    v = (gl - bm_[gcol])*rsqrtf(bv[gcol]+1e-5f)*bg[gcol] + bb[gcol];
                    ((u16*)Cv)[(size_t)grow*ldc + gcol] = f2b(v);
                } else if (MODE == GM_BIAS_RELU){
                    ((u16*)Cv)[(size_t)grow*ldc + gcol] = f2b(fmaxf(v + bg[gcol], 0.f));
                } else {
                    ((u16*)Cv)[(size_t)grow*ldc + gcol] = f2b(v);
                }
            }
        }
    }
}

// ---------- gate stage 2: sigmoid(G1 @ w2 + b2) per pixel, G1 bf16 ----------
__global__ __launch_bounds__(256) void gate2_k(const u16* __restrict__ G1,
    const float* __restrict__ w2, const float* __restrict__ b2, float* __restrict__ gpix)
{
    int pix = blockIdx.x*256 + threadIdx.x;
    const short4v* g4 = (const short4v*)(G1 + (size_t)pix*96);
    const float4* w4 = (const float4*)w2;
    float s = b2[0];
    #pragma unroll
    for (int j=0;j<24;j++){
        short4v g = g4[j]; float4 w = w4[j];
        s += b2f((u16)g.x)*w.x + b2f((u16)g.y)*w.y + b2f((u16)g.z)*w.z + b2f((u16)g.w)*w.w;
    }
    gpix[pix] = 1.f/(1.f+expf(-s));
}

// ---------- deterministic mean of gpix -> dyn_k ----------
__global__ __launch_bounds__(1024) void gate_reduce_k(const float* __restrict__ gpix,
                                                      float* __restrict__ dynk)
{
    __shared__ float sm[16];
    float s = 0.f;
    for (int i=threadIdx.x; i<NPIX; i+=1024) s += gpix[i];
    #pragma unroll
    for (int off=32; off; off>>=1) s += __shfl_xor(s,off,64);
    int wid = threadIdx.x>>6, lane = threadIdx.x&63;
    if (lane==0) sm[wid]=s;
    __syncthreads();
    if (threadIdx.x==0){
        float tot=0.f; for (int i=0;i<16;i++) tot+=sm[i];
        *dynk = floorf(12.0f * (tot/(float)NPIX));
    }
}

// ---------- qkv depthwise 3x3 (288 ch), 2-col sweep, LDS weights, XCD-swizzled ----------
// output split into Q|K|V planes of 96 ch (planeStride elems apart)
#define QPOS(c8) ((c8)*8 + ((c8)>>2)*4)
#define QTAPSTRIDE 324
__global__ __launch_bounds__(256) void qkv_dw_k(const u16* __restrict__ in,
    const float* __restrict__ w, u16* __restrict__ out, size_t planeStride)
{
    __shared__ float wlds[9*QTAPSTRIDE];
    int t = threadIdx.x;
    for (int i=t; i<2592; i+=256){
        int tap = i/288, cc = i%288;
        wlds[tap*QTAPSTRIDE + QPOS(cc>>3) + (cc&7)] = w[cc*9+tap];
    }
    __syncthreads();
    int bid = blockIdx.x;
    int sb = (bid & 7)*(gridDim.x >> 3) + (bid >> 3);
    int idx = sb*256 + t;                  // over NB*HW*18 (col pairs x 36 groups)
    int c8 = idx % 36; int px2 = idx / 36;
    int wp = px2 & 63; int hy = (px2 >> 6) & 127; int img = px2 >> 13;
    int wx0 = wp*2;
    int c0 = c8*8;
    int wofs = QPOS(c8);
    float acc0[8] = {}, acc1[8] = {};
    #pragma unroll
    for (int ky=0; ky<3; ky++){
        int hh = hy + ky - 1; if ((unsigned)hh >= HH) continue;
        const u16* rowp = in + ((size_t)(img*HH+hh)*WW)*288 + c0;
        #pragma unroll
        for (int cc=0; cc<4; cc++){
            int cx = wx0 - 1 + cc;
            if ((unsigned)cx >= WW) continue;
            short8v v = *(const short8v*)(rowp + (size_t)cx*288);
            float vf[8];
            #pragma unroll
            for (int j=0;j<8;j++) vf[j] = b2f((u16)v[j]);
            if (cc < 3){
                floatx4 wa = *(const floatx4*)&wlds[(ky*3+cc)*QTAPSTRIDE + wofs];
                floatx4 wb = *(const floatx4*)&wlds[(ky*3+cc)*QTAPSTRIDE + wofs + 4];
                #pragma unroll
                for (int j=0;j<4;j++){ acc0[j]   = fmaf(wa[j], vf[j],   acc0[j]);
                                       acc0[4+j] = fmaf(wb[j], vf[4+j], acc0[4+j]); }
            }
            if (cc >= 1){
                floatx4 wa = *(const floatx4*)&wlds[(ky*3+cc-1)*QTAPSTRIDE + wofs];
                floatx4 wb = *(const floatx4*)&wlds[(ky*3+cc-1)*QTAPSTRIDE + wofs + 4];
                #pragma unroll
                for (int j=0;j<4;j++){ acc1[j]   = fmaf(wa[j], vf[j],   acc1[j]);
                                       acc1[4+j] = fmaf(wb[j], vf[4+j], acc1[4+j]); }
            }
        }
    }
    size_t pix0 = (size_t)(img*HH+hy)*WW + wx0;
    int sec = c0/96, qc0 = c0 - sec*96;
    u16* outp = out + (size_t)sec*planeStride + qc0;
    short8v o0, o1;
    #pragma unroll
    for (int j=0;j<8;j++){ o0[j] = (short)f2b(acc0[j]); o1[j] = (short)f2b(acc1[j]); }
    *(short8v*)(outp + pix0*96) = o0;
    *(short8v*)(outp + (pix0+1)*96) = o1;
}

// ---------- Gram partials per (img,head,slice), Q/K planes, vectorized staging ----------
__global__ __launch_bounds__(256) void gram_k(const u16* __restrict__ Qp,
    const u16* __restrict__ Kp, float* __restrict__ part)
{
    int bh = blockIdx.x;        // NB*8: img*8+h
    int slice = blockIdx.y;     // 16 (1024 pixels each)
    int img = bh >> 3, h = bh & 7;
    const u16* Qb = Qp + (size_t)img*HW*96 + h*12;
    const u16* Kb = Kp + (size_t)img*HW*96 + h*12;
    __shared__ float qs[64][12];
    __shared__ float ks[64][12];
    int t = threadIdx.x;
    float acc = 0.f;
    int c = (t<144) ? t/12 : (t<156 ? t-144 : t-156);
    int d = (t<144) ? t%12 : 0;
    for (int st=0; st<16; st++){
        int pix0 = slice*1024 + st*64;
        __syncthreads();
        for (int i=t; i<384; i+=256){
            int p = i/6, j = i%6;
            const u16* src = (j<3) ? (Qb + (size_t)(pix0+p)*96 + j*4)
                                   : (Kb + (size_t)(pix0+p)*96 + (j-3)*4);
            short4v v = *(const short4v*)src;
            float f0=b2f((u16)v.x), f1=b2f((u16)v.y), f2=b2f((u16)v.z), f3=b2f((u16)v.w);
            if (j<3){ int jj=j*4;     qs[p][jj]=f0; qs[p][jj+1]=f1; qs[p][jj+2]=f2; qs[p][jj+3]=f3; }
            else    { int jj=(j-3)*4; ks[p][jj]=f0; ks[p][jj+1]=f1; ks[p][jj+2]=f2; ks[p][jj+3]=f3; }
        }
        __syncthreads();
        if (t<144){        for (int p=0;p<64;p++) acc = fmaf(qs[p][c], ks[p][d], acc); }
        else if (t<156){   for (int p=0;p<64;p++) acc = fmaf(qs[p][c], qs[p][c], acc); }
        else if (t<168){   for (int p=0;p<64;p++) acc = fmaf(ks[p][c], ks[p][c], acc); }
    }
    if (t<168) part[((size_t)bh*16 + slice)*168 + t] = acc;
}

__global__ __launch_bounds__(256) void gram_combine_k(const float* __restrict__ part,
                                                      float* __restrict__ gram, int n)
{
    int i = blockIdx.x*256 + threadIdx.x;
    if (i >= n) return;
    int bh = i/168, t = i%168;
    float s = 0.f;
    for (int sl=0; sl<16; sl++) s += part[((size_t)bh*16+sl)*168 + t];
    gram[i] = s;
}

// ---------- attn 12x12: normalize, temperature, top-k mask, softmax ----------
__global__ __launch_bounds__(256) void attn_k(const float* __restrict__ gram,
    const float* __restrict__ temp, const float* __restrict__ dynk_p,
    const float* __restrict__ a1, const float* __restrict__ a2,
    const float* __restrict__ a3, const float* __restrict__ a4,
    float* __restrict__ attnW)
{
    int bh = blockIdx.x;   // NB*8: img*8+h
    int h = bh & 7;
    __shared__ float av[12][12];
    __shared__ float mv[12][12];
    __shared__ float nq[12], nk[12];
    int t = threadIdx.x;
    if (t < 12) nq[t] = fmaxf(sqrtf(gram[bh*168+144+t]), 1e-12f);
    else if (t < 24) nk[t-12] = fmaxf(sqrtf(gram[bh*168+156+(t-12)]), 1e-12f);
    __syncthreads();
    if (t < 144){
        int c=t/12, d=t%12;
        av[c][d] = gram[bh*168+t] / (nq[c]*nk[d]) * temp[h];
    }
    __syncthreads();
    float dk = *dynk_p;
    if (t < 144){
        int c=t/12, d=t%12; float v = av[c][d];
        int r = 0;
        #pragma unroll
        for (int j=0;j<12;j++){
            float o = av[c][j];
            r += (o > v) ? 1 : ((o == v && j < d) ? 1 : 0);
        }
        mv[c][d] = ((float)r < dk) ? v : -INFINITY;
    }
    __syncthreads();
    if (t < 12){
        float mx = -INFINITY;
        for (int d2=0; d2<12; d2++) mx = fmaxf(mx, mv[t][d2]);
        float e[12]; float s = 0.f;
        for (int d2=0; d2<12; d2++){ e[d2] = expf(mv[t][d2]-mx); s += e[d2]; }
        float sc = (a1[0]+a2[0]+a3[0]+a4[0]) / s;
        for (int d2=0; d2<12; d2++) attnW[(size_t)bh*144 + t*12 + d2] = e[d2]*sc;
    }
}

// ---------- attn apply -> P96 bf16 (V plane input); thread = (pixel, head) ----------
__global__ __launch_bounds__(256) void attn_apply_k(const u16* __restrict__ Vp,
    const float* __restrict__ attnW, u16* __restrict__ P)
{
    int gid = blockIdx.x*256 + threadIdx.x;          // NB*HW*8
    int h = gid % 8; size_t pix = (size_t)(gid / 8);
    int img = (int)(pix >> 14);
    const u16* vp = Vp + pix*96 + h*12;
    float vf[12];
    #pragma unroll
    for (int j=0;j<3;j++){
        short4v v = *(const short4v*)(vp + j*4);
        vf[j*4+0]=b2f((u16)v.x); vf[j*4+1]=b2f((u16)v.y);
        vf[j*4+2]=b2f((u16)v.z); vf[j*4+3]=b2f((u16)v.w);
    }
    const float* awb = attnW + ((size_t)(img*8+h))*144;
    u16 o[12];
    #pragma unroll
    for (int cc=0; cc<12; cc++){
        const float4* ap = (const float4*)(awb + cc*12);   // 48B stride -> 16B aligned
        float4 a0 = ap[0], a1 = ap[1], a2 = ap[2];
        float s = a0.x*vf[0] + a0.y*vf[1] + a0.z*vf[2] + a0.w*vf[3]
                + a1.x*vf[4] + a1.y*vf[5] + a1.z*vf[6] + a1.w*vf[7]
                + a2.x*vf[8] + a2.y*vf[9] + a2.z*vf[10]+ a2.w*vf[11];
        o[cc] = f2b(s);
    }
    u16* op = P + pix*96 + h*12;
    *(short4v*)(op)   = *(short4v*)&o[0];
    *(short4v*)(op+4) = *(short4v*)&o[4];
    *(short4v*)(op+8) = *(short4v*)&o[8];
}

// ---------- FFN multi-scale depthwise, row-sweep per scale, XCD-swizzled ----------
template<int KS>
__global__ __launch_bounds__(256) void ffn_dw_g(const u16* __restrict__ V0,
    const float* __restrict__ wsrc, const float* __restrict__ bsrc, int cbase,
    const float* __restrict__ bn2g, const float* __restrict__ bn2b,
    const float* __restrict__ bn2m, const float* __restrict__ bn2v,
    u16* __restrict__ U)
{
    constexpr int PAD = KS/2;
    __shared__ float wlds[KS*KS*64];
    __shared__ float bng[64], bnb[64], bnm[64], bnvr[64];
    int t = threadIdx.x;
    for (int i=t; i<KS*KS*64; i+=256){
        int tap = i >> 6, cc = i & 63;
        wlds[tap*64 + cc] = wsrc[cc*KS*KS + tap];
    }
    if (t < 64){
        bng[t] = bn2g[cbase+t]; bnb[t] = bn2b[cbase+t];
        bnm[t] = bn2m[cbase+t]; bnvr[t] = rsqrtf(bn2v[cbase+t]+1e-5f);
    }
    __syncthreads();
    int ci = t & 7, seg = t >> 3;
    int bid = blockIdx.x;
    int rowid = (bid & 7)*(gridDim.x >> 3) + (bid >> 3);
    int img = rowid >> 7, hy = rowid & 127;
    int c0r = ci*8;
    int c0 = cbase + c0r;
    int x0 = seg*4;
    float acc[4][8];
    {
        floatx4 b0 = *(const floatx4*)(bsrc + c0r);
        floatx4 b1 = *(const floatx4*)(bsrc + c0r + 4);
        #pragma unroll
        for (int dx=0;dx<4;dx++){
            #pragma unroll
            for (int j=0;j<4;j++){ acc[dx][j]=b0[j]; acc[dx][4+j]=b1[j]; }
        }
    }
    #pragma unroll
    for (int ky=0; ky<KS; ky++){
        int hh = hy + ky - PAD;
        if ((unsigned)hh >= HH) continue;
        float wr[KS][8];
        #pragma unroll
        for (int kx=0; kx<KS; kx++){
            floatx4 wa = *(const floatx4*)&wlds[(ky*KS+kx)*64 + c0r];
            floatx4 wb = *(const floatx4*)&wlds[(ky*KS+kx)*64 + c0r + 4];
            #pragma unroll
            for (int j=0;j<4;j++){ wr[kx][j]=wa[j]; wr[kx][4+j]=wb[j]; }
        }
        const u16* rowp = V0 + ((size_t)(img*HH+hh)*WW)*256 + c0;
        #pragma unroll
        for (int cc=0; cc<4+2*PAD; cc++){
            int cx = x0 - PAD + cc;
            if ((unsigned)cx >= WW) continue;
            short8v v = *(const short8v*)(rowp + (size_t)cx*256);
            float vf[8];
            #pragma unroll
            for (int j=0;j<8;j++) vf[j] = b2f((u16)v[j]);
            #pragma unroll
            for (int dx=0; dx<4; dx++){
                int kx = cc - dx;
                if (kx < 0 || kx >= KS) continue;
                #pragma unroll
                for (int j=0;j<8;j++) acc[dx][j] = fmaf(wr[kx][j], vf[j], acc[dx][j]);
            }
        }
    }
    size_t rbase = (size_t)(img*HH+hy)*WW;
    #pragma unroll
    for (int dx=0; dx<4; dx++){
        size_t pix = rbase + x0 + dx;
        short8v vc = *(const short8v*)(V0 + pix*256 + c0);
        short8v o;
        #pragma unroll
        for (int j=0;j<8;j++){
            float v0c = b2f((u16)vc[j]);
            float u1 = acc[dx][j] + v0c;
            float gl = gelu_exact(u1);
            float bn = (gl - bnm[c0r+j])*bnvr[c0r+j]*bng[c0r+j] + bnb[c0r+j];
            o[j] = (short)f2b(bn*v0c);
        }
        *(short8v*)(U + pix*256 + c0) = o;
    }
}

extern "C" void kernel_launch(void* const* d_in, const int* in_sizes, int n_in,
                              void* d_out, int out_size, void* d_ws, size_t ws_size,
                              hipStream_t stream)
{
    const float* x     = (const float*)d_in[0];
    const float* pos_w = (const float*)d_in[1];
    const float* pos_b = (const float*)d_in[2];
    const float* ln1g  = (const float*)d_in[3];
    const float* ln1b  = (const float*)d_in[4];
    const float* temp  = (const float*)d_in[5];
    const float* qkvw  = (const float*)d_in[6];
    const float* qkvdw = (const float*)d_in[7];
    const float* projw = (const float*)d_in[8];
    const float* gw1   = (const float*)d_in[9];
    const float* gb1   = (const float*)d_in[10];
    const float* gw2   = (const float*)d_in[11];
    const float* gb2   = (const float*)d_in[12];
    const float* a1    = (const float*)d_in[13];
    const float* a2    = (const float*)d_in[14];
    const float* a3    = (const float*)d_in[15];
    const float* a4    = (const float*)d_in[16];
    const float* ln2g  = (const float*)d_in[17];
    const float* ln2b  = (const float*)d_in[18];
    const float* fc1w  = (const float*)d_in[19];
    const float* bn1g  = (const float*)d_in[20];
    const float* bn1b  = (const float*)d_in[21];
    const float* bn1m  = (const float*)d_in[22];
    const float* bn1v  = (const float*)d_in[23];
    const float* bn2g  = (const float*)d_in[24];
    const float* bn2b  = (const float*)d_in[25];
    const float* bn2m  = (const float*)d_in[26];
    const float* bn2v  = (const float*)d_in[27];
    const float* fc2w  = (const float*)d_in[28];
    const float* bn3g  = (const float*)d_in[29];
    const float* bn3b  = (const float*)d_in[30];
    const float* bn3m  = (const float*)d_in[31];
    const float* bn3v  = (const float*)d_in[32];
    const float* dw0w  = (const float*)d_in[33];
    const float* dw0b  = (const float*)d_in[34];
    const float* dw1w  = (const float*)d_in[35];
    const float* dw1b  = (const float*)d_in[36];
    const float* dw2w  = (const float*)d_in[37];
    const float* dw2b  = (const float*)d_in[38];
    const float* dw3w  = (const float*)d_in[39];
    const float* dw3b  = (const float*)d_in[40];

    float* OUT = (float*)d_out;      // final fp32 output (written once by fc2)

    // ---- fixed small buffers + bf16 residual stream A ----
    char* p = (char*)d_ws;
    float* gpix  = (float*)p;                 p += (size_t)NPIX*4;
    float* dynk  = (float*)p;                 p += 256;
    float* gpart = (float*)p;                 p += 64*16*168*4;
    float* gram  = (float*)p;                 p += 64*168*4;
    float* attnW = (float*)p;                 p += 64*144*4;
    u16*   wbf   = (u16*)p;                   p += (size_t)WTOT*2;
    u16*   Abf   = (u16*)p;                   p += (size_t)NPIX*192*2;   // 50.3 MB
    size_t fixedB = (size_t)(p - (char*)d_ws);

    // ---- choose chunk size from ws_size: per-image = Y(192)+B1(288)+B2(288) bf16 ----
    size_t perImg = (size_t)HW*2*(192+288+288);   // 25,165,824
    int CBr = 2;
    if (ws_size >= fixedB + 8*perImg) CBr = 8;
    else if (ws_size >= fixedB + 4*perImg) CBr = 4;
    int NCHUNKr = BB/CBr;
    size_t CHWr = (size_t)CBr*HW;

    u16* Ybf = (u16*)p;                   p += CHWr*192*2;
    u16* B1  = (u16*)p;                   p += CHWr*288*2;
    u16* B2  = (u16*)p;
    u16* qkvwb = wbf;
    u16* projwb= wbf + WQ;
    u16* gw1b  = wbf + WQ + WP;
    u16* fc1b  = wbf + WQ + WP + WG;
    u16* fc2b  = wbf + WQ + WP + WG + WF1;
    u16* G1bf  = B1;     // gate phase
    u16* QKVbf = B1;     // qkv out (288 interleaved)
    u16* QKVdbf= B2;     // qkv_dw out: Q|K|V planes of CHWr*96 each
    u16* P96   = B1;     // attn out (QKV dead)
    u16* Zbf   = B2;     // LN2 out (QKVd dead)
    u16* V0bf  = B1;     // fc1 out (P96 dead)
    u16* Ubf   = B2;     // ffn out (Z dead)

    wprep_k<<<(WTOT+255)/256, 256, 0, stream>>>(qkvw, projw, gw1, fc1w, fc2w, wbf);
    pos_conv_k<<<BB*HH*16*48/256, 256, 0, stream>>>(x, pos_w, pos_b, Abf);

    // gate phase
    for (int c=0; c<NCHUNKr; c++){
        const u16* Ab = Abf + (size_t)c*CHWr*192;
        ln_k<<<CHWr/4, 256, 0, stream>>>(Ab, ln1g, ln1b, Ybf);
        dim3 g(2, CHWr/256);
        gemm_bf16_k<GM_BIAS_RELU,192><<<g, 256, 0, stream>>>(Ybf, 192, nullptr, 0,
            gw1b, G1bf, 96, nullptr, 0, gb1, nullptr, nullptr, nullptr, 96);
        gate2_k<<<CHWr/256, 256, 0, stream>>>(G1bf, gw2, gb2, gpix + (size_t)c*CHWr);
    }
    gate_reduce_k<<<1, 1024, 0, stream>>>(gpix, dynk);

    // main phase
    for (int c=0; c<NCHUNKr; c++){
        u16* Ab = Abf + (size_t)c*CHWr*192;
        if (NCHUNKr > 1)   // single-chunk mode: Ybf from gate phase is still valid
            ln_k<<<CHWr/4, 256, 0, stream>>>(Ab, ln1g, ln1b, Ybf);
        {
            dim3 g(5, CHWr/256);
            gemm_bf16_k<GM_NONE,96><<<g, 256, 0, stream>>>(Ybf, 192, nullptr, 0,
                qkvwb, QKVbf, 288, nullptr, 0, nullptr,nullptr,nullptr,nullptr, 288);
        }
        size_t pstr = CHWr*96;
        qkv_dw_k<<<CHWr*18/256, 256, 0, stream>>>(QKVbf, qkvdw, QKVdbf, pstr);
        { dim3 g(CBr*8, 16); gram_k<<<g, 256, 0, stream>>>(QKVdbf, QKVdbf + pstr, gpart); }
        gram_combine_k<<<(CBr*8*168+255)/256, 256, 0, stream>>>(gpart, gram, CBr*8*168);
        attn_k<<<CBr*8, 256, 0, stream>>>(gram, temp, dynk, a1,a2,a3,a4, attnW);
        attn_apply_k<<<CHWr*8/256, 256, 0, stream>>>(QKVdbf + 2*pstr, attnW, P96);
        {   // proj + residual: A += [P96 | Y[:,96:]] @ projw^T  (bf16 in-place)
            dim3 g(3, CHWr/256);
            gemm_bf16_k<GM_RES,192,true><<<g, 256, 0, stream>>>(P96, 96, Ybf+96, 192,
                projwb, Ab, 192, Ab, 192, nullptr,nullptr,nullptr,nullptr, 192);
        }
        ln_k<<<CHWr/4, 256, 0, stream>>>(Ab, ln2g, ln2b, Zbf);
        {
            dim3 g(4, CHWr/256);
            gemm_bf16_k<GM_GELU_BN,192><<<g, 256, 0, stream>>>(Zbf, 192, nullptr, 0,
                fc1b, V0bf, 256, nullptr, 0, bn1g,bn1b,bn1m,bn1v, 256);
        }
        int rows = (int)(CHWr/WW);
        ffn_dw_g<1><<<rows, 256, 0, stream>>>(V0bf, dw0w, dw0b, 0,
            bn2g,bn2b,bn2m,bn2v, Ubf);
        ffn_dw_g<3><<<rows, 256, 0, stream>>>(V0bf, dw1w, dw1b, 64,
            bn2g,bn2b,bn2m,bn2v, Ubf);
        ffn_dw_g<5><<<rows, 256, 0, stream>>>(V0bf, dw2w, dw2b, 128,
            bn2g,bn2b,bn2m,bn2v, Ubf);
        ffn_dw_g<7><<<rows, 256, 0, stream>>>(V0bf, dw3w, dw3b, 192,
            bn2g,bn2b,bn2m,bn2v, Ubf);
        {   // fc2 + bn3 + residual -> fp32 OUT
            dim3 g(3, CHWr/256);
            gemm_bf16_k<GM_BN_RES,256><<<g, 256, 0, stream>>>(Ubf, 256, nullptr, 0,
                fc2b, OUT + (size_t)c*CHWr*192, 192, Ab, 192, bn3g,bn3b,bn3m,bn3v, 192);
        }
    }
}

// Round 12
// 650.688 us; speedup vs baseline: 5.0257x; 1.0066x over previous
//
#include <hip/hip_runtime.h>
#include <hip/hip_bf16.h>
#include <math.h>

#define BB 8
#define HH 128
#define WW 128
#define HW (HH*WW)          // 16384
#define NPIX (BB*HW)        // 131072

typedef unsigned short u16;
typedef __attribute__((ext_vector_type(4))) float  floatx4;
typedef __attribute__((ext_vector_type(4))) short  short4v;
typedef __attribute__((ext_vector_type(8))) short  short8v;

static __device__ __forceinline__ float gelu_exact(float x){
    return 0.5f*x*(1.0f+erff(x*0.70710678118654752440f));
}
static __device__ __forceinline__ float b2f(u16 v){
    union { unsigned u; float f; } x; x.u = ((unsigned)v)<<16; return x.f;
}
static __device__ __forceinline__ u16 f2b(float f){
    __hip_bfloat16 h = __float2bfloat16(f);
    return *(u16*)&h;
}

// ---------- weight prep: fp32 -> bf16 GEMM weights + transposed pos weights ----------
#define WQ 27648
#define WP 36864
#define WG 18432
#define WF1 49152
#define WF2 49152
#define WTOT (WQ+WP+WG+WF1+WF2)   // 181248
__global__ __launch_bounds__(256) void wprep_k(const float* __restrict__ a,
    const float* __restrict__ b, const float* __restrict__ c,
    const float* __restrict__ d, const float* __restrict__ e,
    const float* __restrict__ posw, u16* __restrict__ o, float* __restrict__ wT)
{
    int i = blockIdx.x*256 + threadIdx.x;
    if (i < 1728){   // wT[tap][192]: wT[tap*192+c] = posw[c*9+tap]
        wT[i] = posw[(i%192)*9 + (i/192)];
    }
    if (i >= WTOT) return;
    float v;
    if (i < WQ) v = a[i];
    else if (i < WQ+WP) v = b[i-WQ];
    else if (i < WQ+WP+WG) v = c[i-WQ-WP];
    else if (i < WQ+WP+WG+WF1) v = d[i-WQ-WP-WG];
    else v = e[i-WQ-WP-WG-WF1];
    o[i] = f2b(v);
}

// ---------- pos depthwise 3x3 + bias + residual -> bf16 A; TLP: thread=(pixel,c4) ----------
// 9 independent clamped loads, border masks folded into weights (branchless)
__global__ __launch_bounds__(192) void pos_conv_k(const float* __restrict__ x,
    const float* __restrict__ wT, const float* __restrict__ bias, u16* __restrict__ out)
{
    int bid = blockIdx.x;
    int sb = (bid & 7)*(gridDim.x >> 3) + (bid >> 3);   // XCD image-slice swizzle
    int t = threadIdx.x;
    int c4 = t % 48;
    size_t pix = (size_t)sb*4 + (t/48);
    int wx = (int)(pix % WW);
    int hy = (int)((pix / WW) % HH);
    int b  = (int)(pix / HW);
    int c0 = c4*4;

    int hcl[3], wcl[3];
    float my[3], mx[3];
    #pragma unroll
    for (int i=0;i<3;i++){
        int hh = hy + i - 1;
        my[i] = ((unsigned)hh < HH) ? 1.f : 0.f;
        hcl[i] = min(max(hh,0),HH-1);
        int ww2 = wx + i - 1;
        mx[i] = ((unsigned)ww2 < WW) ? 1.f : 0.f;
        wcl[i] = min(max(ww2,0),WW-1);
    }
    const float4* x4 = (const float4*)x;
    float4 xv[3][3];
    #pragma unroll
    for (int i=0;i<3;i++){
        size_t rb = ((size_t)(b*HH + hcl[i])*WW)*48 + c4;
        #pragma unroll
        for (int k=0;k<3;k++)
            xv[i][k] = x4[rb + (size_t)wcl[k]*48];
    }
    floatx4 wv[9];
    #pragma unroll
    for (int tap=0; tap<9; tap++)
        wv[tap] = *(const floatx4*)&wT[tap*192 + c0];

    float4 acc = *(const float4*)(bias + c0);
    #pragma unroll
    for (int i=0;i<3;i++){
        #pragma unroll
        for (int k=0;k<3;k++){
            float m = my[i]*mx[k];
            floatx4 w = wv[i*3+k];
            acc.x = fmaf(w[0]*m, xv[i][k].x, acc.x);
            acc.y = fmaf(w[1]*m, xv[i][k].y, acc.y);
            acc.z = fmaf(w[2]*m, xv[i][k].z, acc.z);
            acc.w = fmaf(w[3]*m, xv[i][k].w, acc.w);
        }
    }
    acc.x += xv[1][1].x; acc.y += xv[1][1].y; acc.z += xv[1][1].z; acc.w += xv[1][1].w;
    short4v o; o.x=(short)f2b(acc.x); o.y=(short)f2b(acc.y);
    o.z=(short)f2b(acc.z); o.w=(short)f2b(acc.w);
    *(short4v*)(out + pix*192 + c0) = o;
}

// ---------- LayerNorm over C=192, bf16 in -> bf16 out, wave per pixel ----------
__global__ __launch_bounds__(256) void ln_k(const u16* __restrict__ in,
    const float* __restrict__ g, const float* __restrict__ bta, u16* __restrict__ out)
{
    int wid = threadIdx.x >> 6, lane = threadIdx.x & 63;
    size_t pix = (size_t)blockIdx.x*4 + wid;
    const u16* row = in + pix*192;
    float x0 = b2f(row[lane]), x1 = b2f(row[lane+64]), x2 = b2f(row[lane+128]);
    float s = x0+x1+x2;
    float q = x0*x0 + x1*x1 + x2*x2;
    #pragma unroll
    for (int off=32; off; off>>=1){ s += __shfl_xor(s,off,64); q += __shfl_xor(q,off,64); }
    float mean = s*(1.f/192.f);
    float var  = q*(1.f/192.f) - mean*mean;
    float inv  = rsqrtf(var + 1e-6f);
    u16* orow = out + pix*192;
    orow[lane]     = f2b((x0-mean)*inv*g[lane]     + bta[lane]);
    orow[lane+64]  = f2b((x1-mean)*inv*g[lane+64]  + bta[lane+64]);
    orow[lane+128] = f2b((x2-mean)*inv*g[lane+128] + bta[lane+128]);
}

// ---------- bf16 MFMA GEMM: W-in-LDS once, A streamed; grid=(m,n) for XCD A-locality ----------
#define GM_NONE 0
#define GM_RES 1
#define GM_GELU_BN 2
#define GM_BN_RES 3
#define GM_BIAS_RELU 4
#define WSTR 264   // LDS row stride in shorts: 528B = 132 dw; 132%32=4 -> 2-way only

template<int MODE, int K, bool SPLIT=false>
__global__ __launch_bounds__(256) void gemm_bf16_k(
    const u16* __restrict__ A, int lda,
    const u16* __restrict__ A2, int lda2,
    const u16* __restrict__ W,
    void* __restrict__ Cv, int ldc,
    const u16* __restrict__ R, int ldr,
    const float* __restrict__ bg, const float* __restrict__ bb,
    const float* __restrict__ bm_, const float* __restrict__ bv,
    int N)
{
    __shared__ u16 Ws[64*WSTR];
    int t = threadIdx.x;
    int bn = blockIdx.y * 64;      // n along y: blocks sharing A-panel differ by gridDim.x
    int bm = blockIdx.x * 256;     // (gridDim.x multiple of 8 -> same XCD -> A L2-local)
    {
        constexpr int KQ = K/4;
        int brow = t >> 2, bq = t & 3;
        int n = bn + brow;
        bool nv = n < N;
        const u16* src = W + (size_t)n*K + bq*KQ;
        #pragma unroll
        for (int j=0; j<KQ; j+=8){
            short8v v = {};
            if (nv) v = *(const short8v*)(src + j);
            *(short8v*)&Ws[brow*WSTR + bq*KQ + j] = v;
        }
    }
    __syncthreads();
    int wave = t >> 6, lane = t & 63;
    int wm = wave*64;
    int lr = lane & 15, lk = lane >> 4;
    const u16* arow  = A + (size_t)(bm + wm + lr)*lda + lk*8;
    const u16* arow2 = SPLIT ? (A2 + (size_t)(bm + wm + lr)*lda2 + lk*8) : nullptr;
    floatx4 acc[4][4] = {};
    #pragma unroll
    for (int k0 = 0; k0 < K; k0 += 32){
        short8v afr[4];
        if (SPLIT && k0 >= 96){
            #pragma unroll
            for (int m=0;m<4;m++)
                afr[m] = *(const short8v*)(arow2 + (size_t)(m*16)*lda2 + (k0-96));
        } else {
            #pragma unroll
            for (int m=0;m<4;m++)
                afr[m] = *(const short8v*)(arow + (size_t)(m*16)*lda + k0);
        }
        #pragma unroll
        for (int n2=0;n2<4;n2++){
            short8v bfr = *(const short8v*)&Ws[(n2*16+lr)*WSTR + k0 + lk*8];
            #pragma unroll
            for (int m=0;m<4;m++)
                acc[m][n2] = __builtin_amdgcn_mfma_f32_16x16x32_bf16(afr[m], bfr, acc[m][n2], 0,0,0);
        }
    }
    #pragma unroll
    for (int m=0;m<4;m++){
        #pragma unroll
        for (int n2=0;n2<4;n2++){
            int gcol = bn + n2*16 + lr;
            if (gcol >= N) continue;
            #pragma unroll
            for (int rg=0; rg<4; rg++){
                int grow = bm + wm + m*16 + lk*4 + rg;
                float v = acc[m][n2][rg];
                if (MODE == GM_RES){
                    v += b2f(R[(size_t)grow*ldr + gcol]);
                    ((u16*)Cv)[(size_t)grow*ldc + gcol] = f2b(v);
                } else if (MODE == GM_BN_RES){
                    float bnv = (v - bm_[gcol])*rsqrtf(bv[gcol]+1e-5f)*bg[gcol] + bb[gcol];
                    ((float*)Cv)[(size_t)grow*ldc + gcol] = bnv + b2f(R[(size_t)grow*ldr + gcol]);
                } else if (MODE == GM_GELU_BN){
                    float gl = gelu_exact(v);
                    v = (gl - bm_[gcol])*rsqrtf(bv[gcol]+1e-5f)*bg[gcol] + bb[gcol];
                    ((u16*)Cv)[(size_t)grow*ldc + gcol] = f2b(v);
                } else if (MODE == GM_BIAS_RELU){
                    ((u16*)Cv)[(size_t)grow*ldc + gcol] = f2b(fmaxf(v + bg[gcol], 0.f));
                } else {
                    ((u16*)Cv)[(size_t)grow*ldc + gcol] = f2b(v);
                }
            }
        }
    }
}

// ---------- gate stage 2: sigmoid(G1 @ w2 + b2) per pixel, G1 bf16 ----------
__global__ __launch_bounds__(256) void gate2_k(const u16* __restrict__ G1,
    const float* __restrict__ w2, const float* __restrict__ b2, float* __restrict__ gpix)
{
    int pix = blockIdx.x*256 + threadIdx.x;
    const short4v* g4 = (const short4v*)(G1 + (size_t)pix*96);
    const float4* w4 = (const float4*)w2;
    float s = b2[0];
    #pragma unroll
    for (int j=0;j<24;j++){
        short4v g = g4[j]; float4 w = w4[j];
        s += b2f((u16)g.x)*w.x + b2f((u16)g.y)*w.y + b2f((u16)g.z)*w.z + b2f((u16)g.w)*w.w;
    }
    gpix[pix] = 1.f/(1.f+expf(-s));
}

// ---------- deterministic mean of gpix -> dyn_k ----------
__global__ __launch_bounds__(1024) void gate_reduce_k(const float* __restrict__ gpix,
                                                      float* __restrict__ dynk)
{
    __shared__ float sm[16];
    float s = 0.f;
    for (int i=threadIdx.x; i<NPIX; i+=1024) s += gpix[i];
    #pragma unroll
    for (int off=32; off; off>>=1) s += __shfl_xor(s,off,64);
    int wid = threadIdx.x>>6, lane = threadIdx.x&63;
    if (lane==0) sm[wid]=s;
    __syncthreads();
    if (threadIdx.x==0){
        float tot=0.f; for (int i=0;i<16;i++) tot+=sm[i];
        *dynk = floorf(12.0f * (tot/(float)NPIX));
    }
}

// ---------- qkv depthwise 3x3 (288 ch), 2-col sweep, LDS weights, XCD-swizzled ----------
// output split into Q|K|V planes of 96 ch (planeStride elems apart)
#define QPOS(c8) ((c8)*8 + ((c8)>>2)*4)
#define QTAPSTRIDE 324
__global__ __launch_bounds__(256) void qkv_dw_k(const u16* __restrict__ in,
    const float* __restrict__ w, u16* __restrict__ out, size_t planeStride)
{
    __shared__ float wlds[9*QTAPSTRIDE];
    int t = threadIdx.x;
    for (int i=t; i<2592; i+=256){
        int tap = i/288, cc = i%288;
        wlds[tap*QTAPSTRIDE + QPOS(cc>>3) + (cc&7)] = w[cc*9+tap];
    }
    __syncthreads();
    int bid = blockIdx.x;
    int sb = (bid & 7)*(gridDim.x >> 3) + (bid >> 3);
    int idx = sb*256 + t;                  // over NB*HW*18 (col pairs x 36 groups)
    int c8 = idx % 36; int px2 = idx / 36;
    int wp = px2 & 63; int hy = (px2 >> 6) & 127; int img = px2 >> 13;
    int wx0 = wp*2;
    int c0 = c8*8;
    int wofs = QPOS(c8);
    float acc0[8] = {}, acc1[8] = {};
    #pragma unroll
    for (int ky=0; ky<3; ky++){
        int hh = hy + ky - 1; if ((unsigned)hh >= HH) continue;
        const u16* rowp = in + ((size_t)(img*HH+hh)*WW)*288 + c0;
        #pragma unroll
        for (int cc=0; cc<4; cc++){
            int cx = wx0 - 1 + cc;
            if ((unsigned)cx >= WW) continue;
            short8v v = *(const short8v*)(rowp + (size_t)cx*288);
            float vf[8];
            #pragma unroll
            for (int j=0;j<8;j++) vf[j] = b2f((u16)v[j]);
            if (cc < 3){
                floatx4 wa = *(const floatx4*)&wlds[(ky*3+cc)*QTAPSTRIDE + wofs];
                floatx4 wb = *(const floatx4*)&wlds[(ky*3+cc)*QTAPSTRIDE + wofs + 4];
                #pragma unroll
                for (int j=0;j<4;j++){ acc0[j]   = fmaf(wa[j], vf[j],   acc0[j]);
                                       acc0[4+j] = fmaf(wb[j], vf[4+j], acc0[4+j]); }
            }
            if (cc >= 1){
                floatx4 wa = *(const floatx4*)&wlds[(ky*3+cc-1)*QTAPSTRIDE + wofs];
                floatx4 wb = *(const floatx4*)&wlds[(ky*3+cc-1)*QTAPSTRIDE + wofs + 4];
                #pragma unroll
                for (int j=0;j<4;j++){ acc1[j]   = fmaf(wa[j], vf[j],   acc1[j]);
                                       acc1[4+j] = fmaf(wb[j], vf[4+j], acc1[4+j]); }
            }
        }
    }
    size_t pix0 = (size_t)(img*HH+hy)*WW + wx0;
    int sec = c0/96, qc0 = c0 - sec*96;
    u16* outp = out + (size_t)sec*planeStride + qc0;
    short8v o0, o1;
    #pragma unroll
    for (int j=0;j<8;j++){ o0[j] = (short)f2b(acc0[j]); o1[j] = (short)f2b(acc1[j]); }
    *(short8v*)(outp + pix0*96) = o0;
    *(short8v*)(outp + (pix0+1)*96) = o1;
}

// ---------- Gram partials per (img,head,slice), Q/K planes, vectorized staging ----------
__global__ __launch_bounds__(256) void gram_k(const u16* __restrict__ Qp,
    const u16* __restrict__ Kp, float* __restrict__ part)
{
    int bh = blockIdx.x;        // NB*8: img*8+h
    int slice = blockIdx.y;     // 16 (1024 pixels each)
    int img = bh >> 3, h = bh & 7;
    const u16* Qb = Qp + (size_t)img*HW*96 + h*12;
    const u16* Kb = Kp + (size_t)img*HW*96 + h*12;
    __shared__ float qs[64][12];
    __shared__ float ks[64][12];
    int t = threadIdx.x;
    float acc = 0.f;
    int c = (t<144) ? t/12 : (t<156 ? t-144 : t-156);
    int d = (t<144) ? t%12 : 0;
    for (int st=0; st<16; st++){
        int pix0 = slice*1024 + st*64;
        __syncthreads();
        for (int i=t; i<384; i+=256){
            int p = i/6, j = i%6;
            const u16* src = (j<3) ? (Qb + (size_t)(pix0+p)*96 + j*4)
                                   : (Kb + (size_t)(pix0+p)*96 + (j-3)*4);
            short4v v = *(const short4v*)src;
            float f0=b2f((u16)v.x), f1=b2f((u16)v.y), f2=b2f((u16)v.z), f3=b2f((u16)v.w);
            if (j<3){ int jj=j*4;     qs[p][jj]=f0; qs[p][jj+1]=f1; qs[p][jj+2]=f2; qs[p][jj+3]=f3; }
            else    { int jj=(j-3)*4; ks[p][jj]=f0; ks[p][jj+1]=f1; ks[p][jj+2]=f2; ks[p][jj+3]=f3; }
        }
        __syncthreads();
        if (t<144){        for (int p=0;p<64;p++) acc = fmaf(qs[p][c], ks[p][d], acc); }
        else if (t<156){   for (int p=0;p<64;p++) acc = fmaf(qs[p][c], qs[p][c], acc); }
        else if (t<168){   for (int p=0;p<64;p++) acc = fmaf(ks[p][c], ks[p][c], acc); }
    }
    if (t<168) part[((size_t)bh*16 + slice)*168 + t] = acc;
}

__global__ __launch_bounds__(256) void gram_combine_k(const float* __restrict__ part,
                                                      float* __restrict__ gram, int n)
{
    int i = blockIdx.x*256 + threadIdx.x;
    if (i >= n) return;
    int bh = i/168, t = i%168;
    float s = 0.f;
    for (int sl=0; sl<16; sl++) s += part[((size_t)bh*16+sl)*168 + t];
    gram[i] = s;
}

// ---------- attn 12x12: normalize, temperature, top-k mask, softmax ----------
__global__ __launch_bounds__(256) void attn_k(const float* __restrict__ gram,
    const float* __restrict__ temp, const float* __restrict__ dynk_p,
    const float* __restrict__ a1, const float* __restrict__ a2,
    const float* __restrict__ a3, const float* __restrict__ a4,
    float* __restrict__ attnW)
{
    int bh = blockIdx.x;   // NB*8: img*8+h
    int h = bh & 7;
    __shared__ float av[12][12];
    __shared__ float mv[12][12];
    __shared__ float nq[12], nk[12];
    int t = threadIdx.x;
    if (t < 12) nq[t] = fmaxf(sqrtf(gram[bh*168+144+t]), 1e-12f);
    else if (t < 24) nk[t-12] = fmaxf(sqrtf(gram[bh*168+156+(t-12)]), 1e-12f);
    __syncthreads();
    if (t < 144){
        int c=t/12, d=t%12;
        av[c][d] = gram[bh*168+t] / (nq[c]*nk[d]) * temp[h];
    }
    __syncthreads();
    float dk = *dynk_p;
    if (t < 144){
        int c=t/12, d=t%12; float v = av[c][d];
        int r = 0;
        #pragma unroll
        for (int j=0;j<12;j++){
            float o = av[c][j];
            r += (o > v) ? 1 : ((o == v && j < d) ? 1 : 0);
        }
        mv[c][d] = ((float)r < dk) ? v : -INFINITY;
    }
    __syncthreads();
    if (t < 12){
        float mx = -INFINITY;
        for (int d2=0; d2<12; d2++) mx = fmaxf(mx, mv[t][d2]);
        float e[12]; float s = 0.f;
        for (int d2=0; d2<12; d2++){ e[d2] = expf(mv[t][d2]-mx); s += e[d2]; }
        float sc = (a1[0]+a2[0]+a3[0]+a4[0]) / s;
        for (int d2=0; d2<12; d2++) attnW[(size_t)bh*144 + t*12 + d2] = e[d2]*sc;
    }
}

// ---------- attn apply -> P96 bf16 (V plane input); thread = (pixel, head) ----------
__global__ __launch_bounds__(256) void attn_apply_k(const u16* __restrict__ Vp,
    const float* __restrict__ attnW, u16* __restrict__ P)
{
    int gid = blockIdx.x*256 + threadIdx.x;          // NB*HW*8
    int h = gid % 8; size_t pix = (size_t)(gid / 8);
    int img = (int)(pix >> 14);
    const u16* vp = Vp + pix*96 + h*12;
    float vf[12];
    #pragma unroll
    for (int j=0;j<3;j++){
        short4v v = *(const short4v*)(vp + j*4);
        vf[j*4+0]=b2f((u16)v.x); vf[j*4+1]=b2f((u16)v.y);
        vf[j*4+2]=b2f((u16)v.z); vf[j*4+3]=b2f((u16)v.w);
    }
    const float* awb = attnW + ((size_t)(img*8+h))*144;
    u16 o[12];
    #pragma unroll
    for (int cc=0; cc<12; cc++){
        const float4* ap = (const float4*)(awb + cc*12);   // 48B stride -> 16B aligned
        float4 a0 = ap[0], a1 = ap[1], a2 = ap[2];
        float s = a0.x*vf[0] + a0.y*vf[1] + a0.z*vf[2] + a0.w*vf[3]
                + a1.x*vf[4] + a1.y*vf[5] + a1.z*vf[6] + a1.w*vf[7]
                + a2.x*vf[8] + a2.y*vf[9] + a2.z*vf[10]+ a2.w*vf[11];
        o[cc] = f2b(s);
    }
    u16* op = P + pix*96 + h*12;
    *(short4v*)(op)   = *(short4v*)&o[0];
    *(short4v*)(op+4) = *(short4v*)&o[4];
    *(short4v*)(op+8) = *(short4v*)&o[8];
}

// ---------- FFN multi-scale depthwise, row-sweep per scale, XCD-swizzled ----------
template<int KS>
__global__ __launch_bounds__(256) void ffn_dw_g(const u16* __restrict__ V0,
    const float* __restrict__ wsrc, const float* __restrict__ bsrc, int cbase,
    const float* __restrict__ bn2g, const float* __restrict__ bn2b,
    const float* __restrict__ bn2m, const float* __restrict__ bn2v,
    u16* __restrict__ U)
{
    constexpr int PAD = KS/2;
    __shared__ float wlds[KS*KS*64];
    __shared__ float bng[64], bnb[64], bnm[64], bnvr[64];
    int t = threadIdx.x;
    for (int i=t; i<KS*KS*64; i+=256){
        int tap = i >> 6, cc = i & 63;
        wlds[tap*64 + cc] = wsrc[cc*KS*KS + tap];
    }
    if (t < 64){
        bng[t] = bn2g[cbase+t]; bnb[t] = bn2b[cbase+t];
        bnm[t] = bn2m[cbase+t]; bnvr[t] = rsqrtf(bn2v[cbase+t]+1e-5f);
    }
    __syncthreads();
    int ci = t & 7, seg = t >> 3;
    int bid = blockIdx.x;
    int rowid = (bid & 7)*(gridDim.x >> 3) + (bid >> 3);
    int img = rowid >> 7, hy = rowid & 127;
    int c0r = ci*8;
    int c0 = cbase + c0r;
    int x0 = seg*4;
    float acc[4][8];
    {
        floatx4 b0 = *(const floatx4*)(bsrc + c0r);
        floatx4 b1 = *(const floatx4*)(bsrc + c0r + 4);
        #pragma unroll
        for (int dx=0;dx<4;dx++){
            #pragma unroll
            for (int j=0;j<4;j++){ acc[dx][j]=b0[j]; acc[dx][4+j]=b1[j]; }
        }
    }
    #pragma unroll
    for (int ky=0; ky<KS; ky++){
        int hh = hy + ky - PAD;
        if ((unsigned)hh >= HH) continue;
        float wr[KS][8];
        #pragma unroll
        for (int kx=0; kx<KS; kx++){
            floatx4 wa = *(const floatx4*)&wlds[(ky*KS+kx)*64 + c0r];
            floatx4 wb = *(const floatx4*)&wlds[(ky*KS+kx)*64 + c0r + 4];
            #pragma unroll
            for (int j=0;j<4;j++){ wr[kx][j]=wa[j]; wr[kx][4+j]=wb[j]; }
        }
        const u16* rowp = V0 + ((size_t)(img*HH+hh)*WW)*256 + c0;
        #pragma unroll
        for (int cc=0; cc<4+2*PAD; cc++){
            int cx = x0 - PAD + cc;
            if ((unsigned)cx >= WW) continue;
            short8v v = *(const short8v*)(rowp + (size_t)cx*256);
            float vf[8];
            #pragma unroll
            for (int j=0;j<8;j++) vf[j] = b2f((u16)v[j]);
            #pragma unroll
            for (int dx=0; dx<4; dx++){
                int kx = cc - dx;
                if (kx < 0 || kx >= KS) continue;
                #pragma unroll
                for (int j=0;j<8;j++) acc[dx][j] = fmaf(wr[kx][j], vf[j], acc[dx][j]);
            }
        }
    }
    size_t rbase = (size_t)(img*HH+hy)*WW;
    #pragma unroll
    for (int dx=0; dx<4; dx++){
        size_t pix = rbase + x0 + dx;
        short8v vc = *(const short8v*)(V0 + pix*256 + c0);
        short8v o;
        #pragma unroll
        for (int j=0;j<8;j++){
            float v0c = b2f((u16)vc[j]);
            float u1 = acc[dx][j] + v0c;
            float gl = gelu_exact(u1);
            float bn = (gl - bnm[c0r+j])*bnvr[c0r+j]*bng[c0r+j] + bnb[c0r+j];
            o[j] = (short)f2b(bn*v0c);
        }
        *(short8v*)(U + pix*256 + c0) = o;
    }
}

extern "C" void kernel_launch(void* const* d_in, const int* in_sizes, int n_in,
                              void* d_out, int out_size, void* d_ws, size_t ws_size,
                              hipStream_t stream)
{
    const float* x     = (const float*)d_in[0];
    const float* pos_w = (const float*)d_in[1];
    const float* pos_b = (const float*)d_in[2];
    const float* ln1g  = (const float*)d_in[3];
    const float* ln1b  = (const float*)d_in[4];
    const float* temp  = (const float*)d_in[5];
    const float* qkvw  = (const float*)d_in[6];
    const float* qkvdw = (const float*)d_in[7];
    const float* projw = (const float*)d_in[8];
    const float* gw1   = (const float*)d_in[9];
    const float* gb1   = (const float*)d_in[10];
    const float* gw2   = (const float*)d_in[11];
    const float* gb2   = (const float*)d_in[12];
    const float* a1    = (const float*)d_in[13];
    const float* a2    = (const float*)d_in[14];
    const float* a3    = (const float*)d_in[15];
    const float* a4    = (const float*)d_in[16];
    const float* ln2g  = (const float*)d_in[17];
    const float* ln2b  = (const float*)d_in[18];
    const float* fc1w  = (const float*)d_in[19];
    const float* bn1g  = (const float*)d_in[20];
    const float* bn1b  = (const float*)d_in[21];
    const float* bn1m  = (const float*)d_in[22];
    const float* bn1v  = (const float*)d_in[23];
    const float* bn2g  = (const float*)d_in[24];
    const float* bn2b  = (const float*)d_in[25];
    const float* bn2m  = (const float*)d_in[26];
    const float* bn2v  = (const float*)d_in[27];
    const float* fc2w  = (const float*)d_in[28];
    const float* bn3g  = (const float*)d_in[29];
    const float* bn3b  = (const float*)d_in[30];
    const float* bn3m  = (const float*)d_in[31];
    const float* bn3v  = (const float*)d_in[32];
    const float* dw0w  = (const float*)d_in[33];
    const float* dw0b  = (const float*)d_in[34];
    const float* dw1w  = (const float*)d_in[35];
    const float* dw1b  = (const float*)d_in[36];
    const float* dw2w  = (const float*)d_in[37];
    const float* dw2b  = (const float*)d_in[38];
    const float* dw3w  = (const float*)d_in[39];
    const float* dw3b  = (const float*)d_in[40];

    float* OUT = (float*)d_out;      // final fp32 output (written once by fc2)

    // ---- fixed small buffers + bf16 residual stream A ----
    char* p = (char*)d_ws;
    float* gpix  = (float*)p;                 p += (size_t)NPIX*4;
    float* dynk  = (float*)p;                 p += 256;
    float* gpart = (float*)p;                 p += 64*16*168*4;
    float* gram  = (float*)p;                 p += 64*168*4;
    float* attnW = (float*)p;                 p += 64*144*4;
    float* wposT = (float*)p;                 p += 1728*4;
    u16*   wbf   = (u16*)p;                   p += (size_t)WTOT*2;
    u16*   Abf   = (u16*)p;                   p += (size_t)NPIX*192*2;   // 50.3 MB
    size_t fixedB = (size_t)(p - (char*)d_ws);

    // ---- choose chunk size from ws_size: per-image = Y(192)+B1(288)+B2(288) bf16 ----
    size_t perImg = (size_t)HW*2*(192+288+288);   // 25,165,824
    int CBr = 2;
    if (ws_size >= fixedB + 8*perImg) CBr = 8;
    else if (ws_size >= fixedB + 4*perImg) CBr = 4;
    int NCHUNKr = BB/CBr;
    size_t CHWr = (size_t)CBr*HW;

    u16* Ybf = (u16*)p;                   p += CHWr*192*2;
    u16* B1  = (u16*)p;                   p += CHWr*288*2;
    u16* B2  = (u16*)p;
    u16* qkvwb = wbf;
    u16* projwb= wbf + WQ;
    u16* gw1b  = wbf + WQ + WP;
    u16* fc1b  = wbf + WQ + WP + WG;
    u16* fc2b  = wbf + WQ + WP + WG + WF1;
    u16* G1bf  = B1;     // gate phase
    u16* QKVbf = B1;     // qkv out (288 interleaved)
    u16* QKVdbf= B2;     // qkv_dw out: Q|K|V planes of CHWr*96 each
    u16* P96   = B1;     // attn out (QKV dead)
    u16* Zbf   = B2;     // LN2 out (QKVd dead)
    u16* V0bf  = B1;     // fc1 out (P96 dead)
    u16* Ubf   = B2;     // ffn out (Z dead)

    wprep_k<<<(WTOT+255)/256, 256, 0, stream>>>(qkvw, projw, gw1, fc1w, fc2w,
                                                pos_w, wbf, wposT);
    pos_conv_k<<<NPIX/4, 192, 0, stream>>>(x, wposT, pos_b, Abf);

    // gate phase
    for (int c=0; c<NCHUNKr; c++){
        const u16* Ab = Abf + (size_t)c*CHWr*192;
        ln_k<<<CHWr/4, 256, 0, stream>>>(Ab, ln1g, ln1b, Ybf);
        dim3 g(CHWr/256, 2);
        gemm_bf16_k<GM_BIAS_RELU,192><<<g, 256, 0, stream>>>(Ybf, 192, nullptr, 0,
            gw1b, G1bf, 96, nullptr, 0, gb1, nullptr, nullptr, nullptr, 96);
        gate2_k<<<CHWr/256, 256, 0, stream>>>(G1bf, gw2, gb2, gpix + (size_t)c*CHWr);
    }
    gate_reduce_k<<<1, 1024, 0, stream>>>(gpix, dynk);

    // main phase
    for (int c=0; c<NCHUNKr; c++){
        u16* Ab = Abf + (size_t)c*CHWr*192;
        if (NCHUNKr > 1)   // single-chunk mode: Ybf from gate phase is still valid
            ln_k<<<CHWr/4, 256, 0, stream>>>(Ab, ln1g, ln1b, Ybf);
        {
            dim3 g(CHWr/256, 5);
            gemm_bf16_k<GM_NONE,96><<<g, 256, 0, stream>>>(Ybf, 192, nullptr, 0,
                qkvwb, QKVbf, 288, nullptr, 0, nullptr,nullptr,nullptr,nullptr, 288);
        }
        size_t pstr = CHWr*96;
        qkv_dw_k<<<CHWr*18/256, 256, 0, stream>>>(QKVbf, qkvdw, QKVdbf, pstr);
        { dim3 g(CBr*8, 16); gram_k<<<g, 256, 0, stream>>>(QKVdbf, QKVdbf + pstr, gpart); }
        gram_combine_k<<<(CBr*8*168+255)/256, 256, 0, stream>>>(gpart, gram, CBr*8*168);
        attn_k<<<CBr*8, 256, 0, stream>>>(gram, temp, dynk, a1,a2,a3,a4, attnW);
        attn_apply_k<<<CHWr*8/256, 256, 0, stream>>>(QKVdbf + 2*pstr, attnW, P96);
        {   // proj + residual: A += [P96 | Y[:,96:]] @ projw^T  (bf16 in-place)
            dim3 g(CHWr/256, 3);
            gemm_bf16_k<GM_RES,192,true><<<g, 256, 0, stream>>>(P96, 96, Ybf+96, 192,
                projwb, Ab, 192, Ab, 192, nullptr,nullptr,nullptr,nullptr, 192);
        }
        ln_k<<<CHWr/4, 256, 0, stream>>>(Ab, ln2g, ln2b, Zbf);
        {
            dim3 g(CHWr/256, 4);
            gemm_bf16_k<GM_GELU_BN,192><<<g, 256, 0, stream>>>(Zbf, 192, nullptr, 0,
                fc1b, V0bf, 256, nullptr, 0, bn1g,bn1b,bn1m,bn1v, 256);
        }
        int rows = (int)(CHWr/WW);
        ffn_dw_g<1><<<rows, 256, 0, stream>>>(V0bf, dw0w, dw0b, 0,
            bn2g,bn2b,bn2m,bn2v, Ubf);
        ffn_dw_g<3><<<rows, 256, 0, stream>>>(V0bf, dw1w, dw1b, 64,
            bn2g,bn2b,bn2m,bn2v, Ubf);
        ffn_dw_g<5><<<rows, 256, 0, stream>>>(V0bf, dw2w, dw2b, 128,
            bn2g,bn2b,bn2m,bn2v, Ubf);
        ffn_dw_g<7><<<rows, 256, 0, stream>>>(V0bf, dw3w, dw3b, 192,
            bn2g,bn2b,bn2m,bn2v, Ubf);
        {   // fc2 + bn3 + residual -> fp32 OUT
            dim3 g(CHWr/256, 3);
            gemm_bf16_k<GM_BN_RES,256><<<g, 256, 0, stream>>>(Ubf, 256, nullptr, 0,
                fc2b, OUT + (size_t)c*CHWr*192, 192, Ab, 192, bn3g,bn3b,bn3m,bn3v, 192);
        }
    }
}

// Round 14
// 641.457 us; speedup vs baseline: 5.0980x; 1.0144x over previous
//
#include <hip/hip_runtime.h>
#include <hip/hip_bf16.h>
#include <math.h>

#define BB 8
#define HH 128
#define WW 128
#define HW (HH*WW)          // 16384
#define NPIX (BB*HW)        // 131072

typedef unsigned short u16;
typedef __attribute__((ext_vector_type(4))) float  floatx4;
typedef __attribute__((ext_vector_type(4))) short  short4v;
typedef __attribute__((ext_vector_type(8))) short  short8v;

static __device__ __forceinline__ float gelu_exact(float x){
    return 0.5f*x*(1.0f+erff(x*0.70710678118654752440f));
}
static __device__ __forceinline__ float b2f(u16 v){
    union { unsigned u; float f; } x; x.u = ((unsigned)v)<<16; return x.f;
}
static __device__ __forceinline__ u16 f2b(float f){
    __hip_bfloat16 h = __float2bfloat16(f);
    return *(u16*)&h;
}

// ---------- weight prep: fp32 -> bf16 GEMM weights + transposed pos weights ----------
#define WQ 27648
#define WP 36864
#define WG 18432
#define WF1 49152
#define WF2 49152
#define WTOT (WQ+WP+WG+WF1+WF2)   // 181248
__global__ __launch_bounds__(256) void wprep_k(const float* __restrict__ a,
    const float* __restrict__ b, const float* __restrict__ c,
    const float* __restrict__ d, const float* __restrict__ e,
    const float* __restrict__ posw, u16* __restrict__ o, float* __restrict__ wT)
{
    int i = blockIdx.x*256 + threadIdx.x;
    if (i < 1728){   // wT[tap][192]: wT[tap*192+c] = posw[c*9+tap]
        wT[i] = posw[(i%192)*9 + (i/192)];
    }
    if (i >= WTOT) return;
    float v;
    if (i < WQ) v = a[i];
    else if (i < WQ+WP) v = b[i-WQ];
    else if (i < WQ+WP+WG) v = c[i-WQ-WP];
    else if (i < WQ+WP+WG+WF1) v = d[i-WQ-WP-WG];
    else v = e[i-WQ-WP-WG-WF1];
    o[i] = f2b(v);
}

// ---------- pos depthwise 3x3 + bias + residual -> bf16 A; TLP: thread=(pixel,c4) ----------
// (round-12 proven version: 9 independent clamped loads, branchless border masks)
__global__ __launch_bounds__(192) void pos_conv_k(const float* __restrict__ x,
    const float* __restrict__ wT, const float* __restrict__ bias, u16* __restrict__ out)
{
    int bid = blockIdx.x;
    int sb = (bid & 7)*(gridDim.x >> 3) + (bid >> 3);   // XCD image-slice swizzle
    int t = threadIdx.x;
    int c4 = t % 48;
    size_t pix = (size_t)sb*4 + (t/48);
    int wx = (int)(pix % WW);
    int hy = (int)((pix / WW) % HH);
    int b  = (int)(pix / HW);
    int c0 = c4*4;

    int hcl[3], wcl[3];
    float my[3], mx[3];
    #pragma unroll
    for (int i=0;i<3;i++){
        int hh = hy + i - 1;
        my[i] = ((unsigned)hh < HH) ? 1.f : 0.f;
        hcl[i] = min(max(hh,0),HH-1);
        int ww2 = wx + i - 1;
        mx[i] = ((unsigned)ww2 < WW) ? 1.f : 0.f;
        wcl[i] = min(max(ww2,0),WW-1);
    }
    const float4* x4 = (const float4*)x;
    float4 xv[3][3];
    #pragma unroll
    for (int i=0;i<3;i++){
        size_t rb = ((size_t)(b*HH + hcl[i])*WW)*48 + c4;
        #pragma unroll
        for (int k=0;k<3;k++)
            xv[i][k] = x4[rb + (size_t)wcl[k]*48];
    }
    floatx4 wv[9];
    #pragma unroll
    for (int tap=0; tap<9; tap++)
        wv[tap] = *(const floatx4*)&wT[tap*192 + c0];

    float4 acc = *(const float4*)(bias + c0);
    #pragma unroll
    for (int i=0;i<3;i++){
        #pragma unroll
        for (int k=0;k<3;k++){
            float m = my[i]*mx[k];
            floatx4 w = wv[i*3+k];
            acc.x = fmaf(w[0]*m, xv[i][k].x, acc.x);
            acc.y = fmaf(w[1]*m, xv[i][k].y, acc.y);
            acc.z = fmaf(w[2]*m, xv[i][k].z, acc.z);
            acc.w = fmaf(w[3]*m, xv[i][k].w, acc.w);
        }
    }
    acc.x += xv[1][1].x; acc.y += xv[1][1].y; acc.z += xv[1][1].z; acc.w += xv[1][1].w;
    short4v o; o.x=(short)f2b(acc.x); o.y=(short)f2b(acc.y);
    o.z=(short)f2b(acc.z); o.w=(short)f2b(acc.w);
    *(short4v*)(out + pix*192 + c0) = o;
}

// ---------- LayerNorm over C=192, bf16 in -> bf16 out, wave per pixel ----------
__global__ __launch_bounds__(256) void ln_k(const u16* __restrict__ in,
    const float* __restrict__ g, const float* __restrict__ bta, u16* __restrict__ out)
{
    int wid = threadIdx.x >> 6, lane = threadIdx.x & 63;
    size_t pix = (size_t)blockIdx.x*4 + wid;
    const u16* row = in + pix*192;
    float x0 = b2f(row[lane]), x1 = b2f(row[lane+64]), x2 = b2f(row[lane+128]);
    float s = x0+x1+x2;
    float q = x0*x0 + x1*x1 + x2*x2;
    #pragma unroll
    for (int off=32; off; off>>=1){ s += __shfl_xor(s,off,64); q += __shfl_xor(q,off,64); }
    float mean = s*(1.f/192.f);
    float var  = q*(1.f/192.f) - mean*mean;
    float inv  = rsqrtf(var + 1e-6f);
    u16* orow = out + pix*192;
    orow[lane]     = f2b((x0-mean)*inv*g[lane]     + bta[lane]);
    orow[lane+64]  = f2b((x1-mean)*inv*g[lane+64]  + bta[lane+64]);
    orow[lane+128] = f2b((x2-mean)*inv*g[lane+128] + bta[lane+128]);
}

// ---------- bf16 MFMA GEMM: W-in-LDS once, A streamed; grid=(m,n) for XCD A-locality ----------
#define GM_NONE 0
#define GM_RES 1
#define GM_GELU_BN 2
#define GM_BN_RES 3
#define GM_BIAS_RELU 4
#define WSTR 264   // LDS row stride in shorts: 528B = 132 dw; 132%32=4 -> 2-way only

template<int MODE, int K, bool SPLIT=false>
__global__ __launch_bounds__(256) void gemm_bf16_k(
    const u16* __restrict__ A, int lda,
    const u16* __restrict__ A2, int lda2,
    const u16* __restrict__ W,
    void* __restrict__ Cv, int ldc,
    const u16* __restrict__ R, int ldr,
    const float* __restrict__ bg, const float* __restrict__ bb,
    const float* __restrict__ bm_, const float* __restrict__ bv,
    int N)
{
    __shared__ u16 Ws[64*WSTR];
    int t = threadIdx.x;
    int bn = blockIdx.y * 64;      // n along y: blocks sharing A-panel differ by gridDim.x
    int bm = blockIdx.x * 256;     // (gridDim.x multiple of 8 -> same XCD -> A L2-local)
    {
        constexpr int KQ = K/4;
        int brow = t >> 2, bq = t & 3;
        int n = bn + brow;
        bool nv = n < N;
        const u16* src = W + (size_t)n*K + bq*KQ;
        #pragma unroll
        for (int j=0; j<KQ; j+=8){
            short8v v = {};
            if (nv) v = *(const short8v*)(src + j);
            *(short8v*)&Ws[brow*WSTR + bq*KQ + j] = v;
        }
    }
    __syncthreads();
    int wave = t >> 6, lane = t & 63;
    int wm = wave*64;
    int lr = lane & 15, lk = lane >> 4;
    const u16* arow  = A + (size_t)(bm + wm + lr)*lda + lk*8;
    const u16* arow2 = SPLIT ? (A2 + (size_t)(bm + wm + lr)*lda2 + lk*8) : nullptr;
    floatx4 acc[4][4] = {};
    #pragma unroll
    for (int k0 = 0; k0 < K; k0 += 32){
        short8v afr[4];
        if (SPLIT && k0 >= 96){
            #pragma unroll
            for (int m=0;m<4;m++)
                afr[m] = *(const short8v*)(arow2 + (size_t)(m*16)*lda2 + (k0-96));
        } else {
            #pragma unroll
            for (int m=0;m<4;m++)
                afr[m] = *(const short8v*)(arow + (size_t)(m*16)*lda + k0);
        }
        #pragma unroll
        for (int n2=0;n2<4;n2++){
            short8v bfr = *(const short8v*)&Ws[(n2*16+lr)*WSTR + k0 + lk*8];
            #pragma unroll
            for (int m=0;m<4;m++)
                acc[m][n2] = __builtin_amdgcn_mfma_f32_16x16x32_bf16(afr[m], bfr, acc[m][n2], 0,0,0);
        }
    }
    #pragma unroll
    for (int m=0;m<4;m++){
        #pragma unroll
        for (int n2=0;n2<4;n2++){
            int gcol = bn + n2*16 + lr;
            if (gcol >= N) continue;
            #pragma unroll
            for (int rg=0; rg<4; rg++){
                int grow = bm + wm + m*16 + lk*4 + rg;
                float v = acc[m][n2][rg];
                if (MODE == GM_RES){
                    v += b2f(R[(size_t)grow*ldr + gcol]);
                    ((u16*)Cv)[(size_t)grow*ldc + gcol] = f2b(v);
                } else if (MODE == GM_BN_RES){
                    float bnv = (v - bm_[gcol])*rsqrtf(bv[gcol]+1e-5f)*bg[gcol] + bb[gcol];
                    ((float*)Cv)[(size_t)grow*ldc + gcol] = bnv + b2f(R[(size_t)grow*ldr + gcol]);
                } else if (MODE == GM_GELU_BN){
                    float gl = gelu_exact(v);
                    v = (gl - bm_[gcol])*rsqrtf(bv[gcol]+1e-5f)*bg[gcol] + bb[gcol];
                    ((u16*)Cv)[(size_t)grow*ldc + gcol] = f2b(v);
                } else if (MODE == GM_BIAS_RELU){
                    ((u16*)Cv)[(size_t)grow*ldc + gcol] = f2b(fmaxf(v + bg[gcol], 0.f));
                } else {
                    ((u16*)Cv)[(size_t)grow*ldc + gcol] = f2b(v);
                }
            }
        }
    }
}

// ---------- gate stage 2: sigmoid(G1 @ w2 + b2) per pixel, G1 bf16 ----------
__global__ __launch_bounds__(256) void gate2_k(const u16* __restrict__ G1,
    const float* __restrict__ w2, const float* __restrict__ b2, float* __restrict__ gpix)
{
    int pix = blockIdx.x*256 + threadIdx.x;
    const short4v* g4 = (const short4v*)(G1 + (size_t)pix*96);
    const float4* w4 = (const float4*)w2;
    float s = b2[0];
    #pragma unroll
    for (int j=0;j<24;j++){
        short4v g = g4[j]; float4 w = w4[j];
        s += b2f((u16)g.x)*w.x + b2f((u16)g.y)*w.y + b2f((u16)g.z)*w.z + b2f((u16)g.w)*w.w;
    }
    gpix[pix] = 1.f/(1.f+expf(-s));
}

// ---------- deterministic mean of gpix -> dyn_k ----------
__global__ __launch_bounds__(1024) void gate_reduce_k(const float* __restrict__ gpix,
                                                      float* __restrict__ dynk)
{
    __shared__ float sm[16];
    float s = 0.f;
    for (int i=threadIdx.x; i<NPIX; i+=1024) s += gpix[i];
    #pragma unroll
    for (int off=32; off; off>>=1) s += __shfl_xor(s,off,64);
    int wid = threadIdx.x>>6, lane = threadIdx.x&63;
    if (lane==0) sm[wid]=s;
    __syncthreads();
    if (threadIdx.x==0){
        float tot=0.f; for (int i=0;i<16;i++) tot+=sm[i];
        *dynk = floorf(12.0f * (tot/(float)NPIX));
    }
}

// ---------- qkv depthwise 3x3 (288 ch), 4-col sweep, LDS weights, XCD-swizzled ----------
// output split into Q|K|V planes of 96 ch (planeStride elems apart)
#define QPOS(c8) ((c8)*8 + ((c8)>>2)*4)
#define QTAPSTRIDE 324
__global__ __launch_bounds__(256) void qkv_dw_k(const u16* __restrict__ in,
    const float* __restrict__ w, u16* __restrict__ out, size_t planeStride)
{
    __shared__ float wlds[9*QTAPSTRIDE];
    int t = threadIdx.x;
    for (int i=t; i<2592; i+=256){
        int tap = i/288, cc = i%288;
        wlds[tap*QTAPSTRIDE + QPOS(cc>>3) + (cc&7)] = w[cc*9+tap];
    }
    __syncthreads();
    int bid = blockIdx.x;
    int sb = (bid & 7)*(gridDim.x >> 3) + (bid >> 3);
    int idx = sb*256 + t;                  // over NB*HW/4*36 (col quads x 36 c8 groups)
    int c8 = idx % 36; int pq = idx / 36;
    int xg = pq & 31; int hy = (pq >> 5) & 127; int img = pq >> 12;
    int x0 = xg*4;
    int c0 = c8*8;
    int wofs = QPOS(c8);
    float acc[4][8] = {{0.f}};
    #pragma unroll
    for (int ky=0; ky<3; ky++){
        int hh = hy + ky - 1; if ((unsigned)hh >= HH) continue;
        float wr[3][8];
        #pragma unroll
        for (int kx=0; kx<3; kx++){
            floatx4 wa = *(const floatx4*)&wlds[(ky*3+kx)*QTAPSTRIDE + wofs];
            floatx4 wb = *(const floatx4*)&wlds[(ky*3+kx)*QTAPSTRIDE + wofs + 4];
            #pragma unroll
            for (int j=0;j<4;j++){ wr[kx][j]=wa[j]; wr[kx][4+j]=wb[j]; }
        }
        const u16* rowp = in + ((size_t)(img*HH+hh)*WW)*288 + c0;
        #pragma unroll
        for (int cc=0; cc<6; cc++){
            int cx = x0 - 1 + cc;
            if ((unsigned)cx >= WW) continue;
            short8v v = *(const short8v*)(rowp + (size_t)cx*288);
            float vf[8];
            #pragma unroll
            for (int j=0;j<8;j++) vf[j] = b2f((u16)v[j]);
            #pragma unroll
            for (int dx=0; dx<4; dx++){
                int kx = cc - dx;
                if (kx < 0 || kx >= 3) continue;   // compile-time folds per (cc,dx)
                #pragma unroll
                for (int j=0;j<8;j++) acc[dx][j] = fmaf(wr[kx][j], vf[j], acc[dx][j]);
            }
        }
    }
    size_t pix0 = (size_t)(img*HH+hy)*WW + x0;
    int sec = c0/96, qc0 = c0 - sec*96;
    u16* outp = out + (size_t)sec*planeStride + qc0;
    #pragma unroll
    for (int dx=0; dx<4; dx++){
        short8v o;
        #pragma unroll
        for (int j=0;j<8;j++) o[j] = (short)f2b(acc[dx][j]);
        *(short8v*)(outp + (pix0+dx)*96) = o;
    }
}

// ---------- Gram partials per (img,head,slice), Q/K planes, vectorized staging ----------
__global__ __launch_bounds__(256) void gram_k(const u16* __restrict__ Qp,
    const u16* __restrict__ Kp, float* __restrict__ part)
{
    int bh = blockIdx.x;        // NB*8: img*8+h
    int slice = blockIdx.y;     // 16 (1024 pixels each)
    int img = bh >> 3, h = bh & 7;
    const u16* Qb = Qp + (size_t)img*HW*96 + h*12;
    const u16* Kb = Kp + (size_t)img*HW*96 + h*12;
    __shared__ float qs[64][12];
    __shared__ float ks[64][12];
    int t = threadIdx.x;
    float acc = 0.f;
    int c = (t<144) ? t/12 : (t<156 ? t-144 : t-156);
    int d = (t<144) ? t%12 : 0;
    for (int st=0; st<16; st++){
        int pix0 = slice*1024 + st*64;
        __syncthreads();
        for (int i=t; i<384; i+=256){
            int p = i/6, j = i%6;
            const u16* src = (j<3) ? (Qb + (size_t)(pix0+p)*96 + j*4)
                                   : (Kb + (size_t)(pix0+p)*96 + (j-3)*4);
            short4v v = *(const short4v*)src;
            float f0=b2f((u16)v.x), f1=b2f((u16)v.y), f2=b2f((u16)v.z), f3=b2f((u16)v.w);
            if (j<3){ int jj=j*4;     qs[p][jj]=f0; qs[p][jj+1]=f1; qs[p][jj+2]=f2; qs[p][jj+3]=f3; }
            else    { int jj=(j-3)*4; ks[p][jj]=f0; ks[p][jj+1]=f1; ks[p][jj+2]=f2; ks[p][jj+3]=f3; }
        }
        __syncthreads();
        if (t<144){        for (int p=0;p<64;p++) acc = fmaf(qs[p][c], ks[p][d], acc); }
        else if (t<156){   for (int p=0;p<64;p++) acc = fmaf(qs[p][c], qs[p][c], acc); }
        else if (t<168){   for (int p=0;p<64;p++) acc = fmaf(ks[p][c], ks[p][c], acc); }
    }
    if (t<168) part[((size_t)bh*16 + slice)*168 + t] = acc;
}

__global__ __launch_bounds__(256) void gram_combine_k(const float* __restrict__ part,
                                                      float* __restrict__ gram, int n)
{
    int i = blockIdx.x*256 + threadIdx.x;
    if (i >= n) return;
    int bh = i/168, t = i%168;
    float s = 0.f;
    for (int sl=0; sl<16; sl++) s += part[((size_t)bh*16+sl)*168 + t];
    gram[i] = s;
}

// ---------- attn 12x12: normalize, temperature, top-k mask, softmax ----------
__global__ __launch_bounds__(256) void attn_k(const float* __restrict__ gram,
    const float* __restrict__ temp, const float* __restrict__ dynk_p,
    const float* __restrict__ a1, const float* __restrict__ a2,
    const float* __restrict__ a3, const float* __restrict__ a4,
    float* __restrict__ attnW)
{
    int bh = blockIdx.x;   // NB*8: img*8+h
    int h = bh & 7;
    __shared__ float av[12][12];
    __shared__ float mv[12][12];
    __shared__ float nq[12], nk[12];
    int t = threadIdx.x;
    if (t < 12) nq[t] = fmaxf(sqrtf(gram[bh*168+144+t]), 1e-12f);
    else if (t < 24) nk[t-12] = fmaxf(sqrtf(gram[bh*168+156+(t-12)]), 1e-12f);
    __syncthreads();
    if (t < 144){
        int c=t/12, d=t%12;
        av[c][d] = gram[bh*168+t] / (nq[c]*nk[d]) * temp[h];
    }
    __syncthreads();
    float dk = *dynk_p;
    if (t < 144){
        int c=t/12, d=t%12; float v = av[c][d];
        int r = 0;
        #pragma unroll
        for (int j=0;j<12;j++){
            float o = av[c][j];
            r += (o > v) ? 1 : ((o == v && j < d) ? 1 : 0);
        }
        mv[c][d] = ((float)r < dk) ? v : -INFINITY;
    }
    __syncthreads();
    if (t < 12){
        float mx = -INFINITY;
        for (int d2=0; d2<12; d2++) mx = fmaxf(mx, mv[t][d2]);
        float e[12]; float s = 0.f;
        for (int d2=0; d2<12; d2++){ e[d2] = expf(mv[t][d2]-mx); s += e[d2]; }
        float sc = (a1[0]+a2[0]+a3[0]+a4[0]) / s;
        for (int d2=0; d2<12; d2++) attnW[(size_t)bh*144 + t*12 + d2] = e[d2]*sc;
    }
}

// ---------- attn apply -> P96 bf16 (V plane input); thread = (pixel, head) ----------
__global__ __launch_bounds__(256) void attn_apply_k(const u16* __restrict__ Vp,
    const float* __restrict__ attnW, u16* __restrict__ P)
{
    int gid = blockIdx.x*256 + threadIdx.x;          // NB*HW*8
    int h = gid % 8; size_t pix = (size_t)(gid / 8);
    int img = (int)(pix >> 14);
    const u16* vp = Vp + pix*96 + h*12;
    float vf[12];
    #pragma unroll
    for (int j=0;j<3;j++){
        short4v v = *(const short4v*)(vp + j*4);
        vf[j*4+0]=b2f((u16)v.x); vf[j*4+1]=b2f((u16)v.y);
        vf[j*4+2]=b2f((u16)v.z); vf[j*4+3]=b2f((u16)v.w);
    }
    const float* awb = attnW + ((size_t)(img*8+h))*144;
    u16 o[12];
    #pragma unroll
    for (int cc=0; cc<12; cc++){
        const float4* ap = (const float4*)(awb + cc*12);   // 48B stride -> 16B aligned
        float4 a0 = ap[0], a1 = ap[1], a2 = ap[2];
        float s = a0.x*vf[0] + a0.y*vf[1] + a0.z*vf[2] + a0.w*vf[3]
                + a1.x*vf[4] + a1.y*vf[5] + a1.z*vf[6] + a1.w*vf[7]
                + a2.x*vf[8] + a2.y*vf[9] + a2.z*vf[10]+ a2.w*vf[11];
        o[cc] = f2b(s);
    }
    u16* op = P + pix*96 + h*12;
    *(short4v*)(op)   = *(short4v*)&o[0];
    *(short4v*)(op+4) = *(short4v*)&o[4];
    *(short4v*)(op+8) = *(short4v*)&o[8];
}

// ---------- FFN multi-scale depthwise, row-sweep per scale, XCD-swizzled ----------
template<int KS>
__global__ __launch_bounds__(256) void ffn_dw_g(const u16* __restrict__ V0,
    const float* __restrict__ wsrc, const float* __restrict__ bsrc, int cbase,
    const float* __restrict__ bn2g, const float* __restrict__ bn2b,
    const float* __restrict__ bn2m, const float* __restrict__ bn2v,
    u16* __restrict__ U)
{
    constexpr int PAD = KS/2;
    __shared__ float wlds[KS*KS*64];
    __shared__ float bng[64], bnb[64], bnm[64], bnvr[64];
    int t = threadIdx.x;
    for (int i=t; i<KS*KS*64; i+=256){
        int tap = i >> 6, cc = i & 63;
        wlds[tap*64 + cc] = wsrc[cc*KS*KS + tap];
    }
    if (t < 64){
        bng[t] = bn2g[cbase+t]; bnb[t] = bn2b[cbase+t];
        bnm[t] = bn2m[cbase+t]; bnvr[t] = rsqrtf(bn2v[cbase+t]+1e-5f);
    }
    __syncthreads();
    int ci = t & 7, seg = t >> 3;
    int bid = blockIdx.x;
    int rowid = (bid & 7)*(gridDim.x >> 3) + (bid >> 3);
    int img = rowid >> 7, hy = rowid & 127;
    int c0r = ci*8;
    int c0 = cbase + c0r;
    int x0 = seg*4;
    float acc[4][8];
    {
        floatx4 b0 = *(const floatx4*)(bsrc + c0r);
        floatx4 b1 = *(const floatx4*)(bsrc + c0r + 4);
        #pragma unroll
        for (int dx=0;dx<4;dx++){
            #pragma unroll
            for (int j=0;j<4;j++){ acc[dx][j]=b0[j]; acc[dx][4+j]=b1[j]; }
        }
    }
    #pragma unroll
    for (int ky=0; ky<KS; ky++){
        int hh = hy + ky - PAD;
        if ((unsigned)hh >= HH) continue;
        float wr[KS][8];
        #pragma unroll
        for (int kx=0; kx<KS; kx++){
            floatx4 wa = *(const floatx4*)&wlds[(ky*KS+kx)*64 + c0r];
            floatx4 wb = *(const floatx4*)&wlds[(ky*KS+kx)*64 + c0r + 4];
            #pragma unroll
            for (int j=0;j<4;j++){ wr[kx][j]=wa[j]; wr[kx][4+j]=wb[j]; }
        }
        const u16* rowp = V0 + ((size_t)(img*HH+hh)*WW)*256 + c0;
        #pragma unroll
        for (int cc=0; cc<4+2*PAD; cc++){
            int cx = x0 - PAD + cc;
            if ((unsigned)cx >= WW) continue;
            short8v v = *(const short8v*)(rowp + (size_t)cx*256);
            float vf[8];
            #pragma unroll
            for (int j=0;j<8;j++) vf[j] = b2f((u16)v[j]);
            #pragma unroll
            for (int dx=0; dx<4; dx++){
                int kx = cc - dx;
                if (kx < 0 || kx >= KS) continue;
                #pragma unroll
                for (int j=0;j<8;j++) acc[dx][j] = fmaf(wr[kx][j], vf[j], acc[dx][j]);
            }
        }
    }
    size_t rbase = (size_t)(img*HH+hy)*WW;
    #pragma unroll
    for (int dx=0; dx<4; dx++){
        size_t pix = rbase + x0 + dx;
        short8v vc = *(const short8v*)(V0 + pix*256 + c0);
        short8v o;
        #pragma unroll
        for (int j=0;j<8;j++){
            float v0c = b2f((u16)vc[j]);
            float u1 = acc[dx][j] + v0c;
            float gl = gelu_exact(u1);
            float bn = (gl - bnm[c0r+j])*bnvr[c0r+j]*bng[c0r+j] + bnb[c0r+j];
            o[j] = (short)f2b(bn*v0c);
        }
        *(short8v*)(U + pix*256 + c0) = o;
    }
}

extern "C" void kernel_launch(void* const* d_in, const int* in_sizes, int n_in,
                              void* d_out, int out_size, void* d_ws, size_t ws_size,
                              hipStream_t stream)
{
    const float* x     = (const float*)d_in[0];
    const float* pos_w = (const float*)d_in[1];
    const float* pos_b = (const float*)d_in[2];
    const float* ln1g  = (const float*)d_in[3];
    const float* ln1b  = (const float*)d_in[4];
    const float* temp  = (const float*)d_in[5];
    const float* qkvw  = (const float*)d_in[6];
    const float* qkvdw = (const float*)d_in[7];
    const float* projw = (const float*)d_in[8];
    const float* gw1   = (const float*)d_in[9];
    const float* gb1   = (const float*)d_in[10];
    const float* gw2   = (const float*)d_in[11];
    const float* gb2   = (const float*)d_in[12];
    const float* a1    = (const float*)d_in[13];
    const float* a2    = (const float*)d_in[14];
    const float* a3    = (const float*)d_in[15];
    const float* a4    = (const float*)d_in[16];
    const float* ln2g  = (const float*)d_in[17];
    const float* ln2b  = (const float*)d_in[18];
    const float* fc1w  = (const float*)d_in[19];
    const float* bn1g  = (const float*)d_in[20];
    const float* bn1b  = (const float*)d_in[21];
    const float* bn1m  = (const float*)d_in[22];
    const float* bn1v  = (const float*)d_in[23];
    const float* bn2g  = (const float*)d_in[24];
    const float* bn2b  = (const float*)d_in[25];
    const float* bn2m  = (const float*)d_in[26];
    const float* bn2v  = (const float*)d_in[27];
    const float* fc2w  = (const float*)d_in[28];
    const float* bn3g  = (const float*)d_in[29];
    const float* bn3b  = (const float*)d_in[30];
    const float* bn3m  = (const float*)d_in[31];
    const float* bn3v  = (const float*)d_in[32];
    const float* dw0w  = (const float*)d_in[33];
    const float* dw0b  = (const float*)d_in[34];
    const float* dw1w  = (const float*)d_in[35];
    const float* dw1b  = (const float*)d_in[36];
    const float* dw2w  = (const float*)d_in[37];
    const float* dw2b  = (const float*)d_in[38];
    const float* dw3w  = (const float*)d_in[39];
    const float* dw3b  = (const float*)d_in[40];

    float* OUT = (float*)d_out;      // final fp32 output (written once by fc2)

    // ---- fixed small buffers + bf16 residual stream A ----
    char* p = (char*)d_ws;
    float* gpix  = (float*)p;                 p += (size_t)NPIX*4;
    float* dynk  = (float*)p;                 p += 256;
    float* gpart = (float*)p;                 p += 64*16*168*4;
    float* gram  = (float*)p;                 p += 64*168*4;
    float* attnW = (float*)p;                 p += 64*144*4;
    float* wposT = (float*)p;                 p += 1728*4;
    u16*   wbf   = (u16*)p;                   p += (size_t)WTOT*2;
    u16*   Abf   = (u16*)p;                   p += (size_t)NPIX*192*2;   // 50.3 MB
    size_t fixedB = (size_t)(p - (char*)d_ws);

    // ---- choose chunk size from ws_size: per-image = Y(192)+B1(288)+B2(288) bf16 ----
    size_t perImg = (size_t)HW*2*(192+288+288);   // 25,165,824
    int CBr = 2;
    if (ws_size >= fixedB + 8*perImg) CBr = 8;
    else if (ws_size >= fixedB + 4*perImg) CBr = 4;
    int NCHUNKr = BB/CBr;
    size_t CHWr = (size_t)CBr*HW;

    u16* Ybf = (u16*)p;                   p += CHWr*192*2;
    u16* B1  = (u16*)p;                   p += CHWr*288*2;
    u16* B2  = (u16*)p;
    u16* qkvwb = wbf;
    u16* projwb= wbf + WQ;
    u16* gw1b  = wbf + WQ + WP;
    u16* fc1b  = wbf + WQ + WP + WG;
    u16* fc2b  = wbf + WQ + WP + WG + WF1;
    u16* G1bf  = B1;     // gate phase
    u16* QKVbf = B1;     // qkv out (288 interleaved)
    u16* QKVdbf= B2;     // qkv_dw out: Q|K|V planes of CHWr*96 each
    u16* P96   = B1;     // attn out (QKV dead)
    u16* Zbf   = B2;     // LN2 out (QKVd dead)
    u16* V0bf  = B1;     // fc1 out (P96 dead)
    u16* Ubf   = B2;     // ffn out (Z dead)

    wprep_k<<<(WTOT+255)/256, 256, 0, stream>>>(qkvw, projw, gw1, fc1w, fc2w,
                                                pos_w, wbf, wposT);
    pos_conv_k<<<NPIX/4, 192, 0, stream>>>(x, wposT, pos_b, Abf);

    // gate phase
    for (int c=0; c<NCHUNKr; c++){
        const u16* Ab = Abf + (size_t)c*CHWr*192;
        ln_k<<<CHWr/4, 256, 0, stream>>>(Ab, ln1g, ln1b, Ybf);
        dim3 g(CHWr/256, 2);
        gemm_bf16_k<GM_BIAS_RELU,192><<<g, 256, 0, stream>>>(Ybf, 192, nullptr, 0,
            gw1b, G1bf, 96, nullptr, 0, gb1, nullptr, nullptr, nullptr, 96);
        gate2_k<<<CHWr/256, 256, 0, stream>>>(G1bf, gw2, gb2, gpix + (size_t)c*CHWr);
    }
    gate_reduce_k<<<1, 1024, 0, stream>>>(gpix, dynk);

    // main phase
    for (int c=0; c<NCHUNKr; c++){
        u16* Ab = Abf + (size_t)c*CHWr*192;
        if (NCHUNKr > 1)   // single-chunk mode: Ybf from gate phase is still valid
            ln_k<<<CHWr/4, 256, 0, stream>>>(Ab, ln1g, ln1b, Ybf);
        {
            dim3 g(CHWr/256, 5);
            gemm_bf16_k<GM_NONE,96><<<g, 256, 0, stream>>>(Ybf, 192, nullptr, 0,
                qkvwb, QKVbf, 288, nullptr, 0, nullptr,nullptr,nullptr,nullptr, 288);
        }
        size_t pstr = CHWr*96;
        qkv_dw_k<<<CHWr/4*36/256, 256, 0, stream>>>(QKVbf, qkvdw, QKVdbf, pstr);
        { dim3 g(CBr*8, 16); gram_k<<<g, 256, 0, stream>>>(QKVdbf, QKVdbf + pstr, gpart); }
        gram_combine_k<<<(CBr*8*168+255)/256, 256, 0, stream>>>(gpart, gram, CBr*8*168);
        attn_k<<<CBr*8, 256, 0, stream>>>(gram, temp, dynk, a1,a2,a3,a4, attnW);
        attn_apply_k<<<CHWr*8/256, 256, 0, stream>>>(QKVdbf + 2*pstr, attnW, P96);
        {   // proj + residual: A += [P96 | Y[:,96:]] @ projw^T  (bf16 in-place)
            dim3 g(CHWr/256, 3);
            gemm_bf16_k<GM_RES,192,true><<<g, 256, 0, stream>>>(P96, 96, Ybf+96, 192,
                projwb, Ab, 192, Ab, 192, nullptr,nullptr,nullptr,nullptr, 192);
        }
        ln_k<<<CHWr/4, 256, 0, stream>>>(Ab, ln2g, ln2b, Zbf);
        {
            dim3 g(CHWr/256, 4);
            gemm_bf16_k<GM_GELU_BN,192><<<g, 256, 0, stream>>>(Zbf, 192, nullptr, 0,
                fc1b, V0bf, 256, nullptr, 0, bn1g,bn1b,bn1m,bn1v, 256);
        }
        int rows = (int)(CHWr/WW);
        ffn_dw_g<1><<<rows, 256, 0, stream>>>(V0bf, dw0w, dw0b, 0,
            bn2g,bn2b,bn2m,bn2v, Ubf);
        ffn_dw_g<3><<<rows, 256, 0, stream>>>(V0bf, dw1w, dw1b, 64,
            bn2g,bn2b,bn2m,bn2v, Ubf);
        ffn_dw_g<5><<<rows, 256, 0, stream>>>(V0bf, dw2w, dw2b, 128,
            bn2g,bn2b,bn2m,bn2v, Ubf);
        ffn_dw_g<7><<<rows, 256, 0, stream>>>(V0bf, dw3w, dw3b, 192,
            bn2g,bn2b,bn2m,bn2v, Ubf);
        {   // fc2 + bn3 + residual -> fp32 OUT
            dim3 g(CHWr/256, 3);
            gemm_bf16_k<GM_BN_RES,256><<<g, 256, 0, stream>>>(Ubf, 256, nullptr, 0,
                fc2b, OUT + (size_t)c*CHWr*192, 192, Ab, 192, bn3g,bn3b,bn3m,bn3v, 192);
        }
    }
}